// Round 8
// baseline (280.163 us; speedup 1.0000x reference)
//
#include <hip/hip_runtime.h>
#include <hip/hip_bf16.h>

// UniTeacherEncoder v8: v7 with __launch_bounds__ REMOVED from k_attn.
// Evidence chain: (256,4)->VGPR 64, 940MB scratch traffic; (256,3)->VGPR 84,
// 350MB scratch. The min-waves target makes LLVM spill toward higher occupancy.
// Default allocator (no bounds) doesn't spill below ~450 VGPR (m08) -> clean.

namespace {

constexpr int kN  = 1024;
constexpr int kC  = 128;
constexpr int kG  = 8;
constexpr int kDH = 64;
constexpr int kND = 256;

constexpr int   kNT    = 16384;
constexpr float kRLO   = -2.0625f;   // rel in [-2.032, 2.032] guaranteed (|off|<=4)
constexpr float kRSPAN = 4.125f;

// workspace layout (float offsets)
constexpr size_t W_LNKV = 0;          // 2048 x 128 f32
constexpr size_t W_LNQ1 = 262144;
constexpr size_t W_LNQ2 = 524288;
constexpr size_t W_QT   = 786432;     // bf16 [32 bg][64 d][1024 r]
constexpr size_t W_KT   = 1835008;    // bf16 [32 bg][64 d][256 j]
constexpr size_t W_V    = 2097152;    // bf16 [32 bg][256 j][64 d]
constexpr size_t W_VGS  = 2359296;    // f32 [32][256]
constexpr size_t W_AO   = 2367488;    // f32 [32 bg][1024][64]
constexpr size_t W_FUS  = 4988928;    // f32 2048 x 128
constexpr size_t W_TAB  = 5251072;    // f32 2 x 16385
constexpr size_t W_MOUT = 5283844;    // 4 x 128
constexpr size_t W_PART = 5284356;    // 4 x 64 x 128
constexpr size_t W_OWT1 = 5317124;    // 512 x 128
constexpr size_t W_OWT2 = 5382660;
constexpr size_t W_FWT  = 5448196;    // 256 x 128

} // namespace

__device__ __forceinline__ float wave_sum(float v) {
#pragma unroll
  for (int o = 32; o > 0; o >>= 1) v += __shfl_xor(v, o, 64);
  return v;
}
__device__ __forceinline__ float bf_lo(unsigned int u) {
  return __uint_as_float(u << 16);
}
__device__ __forceinline__ float bf_hi(unsigned int u) {
  return __uint_as_float(u & 0xffff0000u);
}
__device__ __forceinline__ unsigned int cvtpk_bf16(float lo, float hi) {
  unsigned int r;
  asm volatile("v_cvt_pk_bf16_f32 %0, %1, %2" : "=v"(r) : "v"(lo), "v"(hi));
  return r;
}

// ---------------- k_prep: transposes + LN x3 + CPB table + mout ----------------
__global__ void k_prep(const float* __restrict__ ow, const float* __restrict__ fw,
                       float* __restrict__ owT1, float* __restrict__ owT2,
                       float* __restrict__ fwT,
                       const float* __restrict__ x1_0, const float* __restrict__ x1_1,
                       const float* __restrict__ x2, float* __restrict__ lnq1,
                       float* __restrict__ lnq2, float* __restrict__ lnkv,
                       const float* __restrict__ ng, const float* __restrict__ nb,
                       const float* __restrict__ cw1, const float* __restrict__ cb1,
                       const float* __restrict__ cw2, const float* __restrict__ cb2,
                       const float* __restrict__ cw3, const float* __restrict__ cb3,
                       float* __restrict__ tab,
                       const float* __restrict__ tfng, const float* __restrict__ tfnb,
                       const float* __restrict__ inw, const float* __restrict__ inb,
                       const float* __restrict__ tow, const float* __restrict__ tob,
                       float* __restrict__ mout) {
  int bx = blockIdx.x;
  int t = threadIdx.x;
  if (bx < 160) {
    const float* src; float* dst; int R, C, tile;
    if (bx < 64)       { src = ow;          dst = owT1; R = 128; C = 512; tile = bx; }
    else if (bx < 128) { src = ow + 65536;  dst = owT2; R = 128; C = 512; tile = bx - 64; }
    else               { src = fw;          dst = fwT;  R = 128; C = 256; tile = bx - 128; }
    int tpr = C >> 5;
    int ti = tile / tpr, tj = tile - ti * tpr;
    __shared__ float tl[32][33];
    int x = t & 31, ys = t >> 5;
#pragma unroll
    for (int p = 0; p < 4; ++p) {
      int y = ys + p * 8;
      tl[y][x] = src[(size_t)(ti * 32 + y) * C + tj * 32 + x];
    }
    __syncthreads();
#pragma unroll
    for (int p = 0; p < 4; ++p) {
      int y = ys + p * 8;
      dst[(size_t)(tj * 32 + y) * R + ti * 32 + x] = tl[x][y];
    }
  } else if (bx < 1696) {
    int w = t >> 6, lane = t & 63;
    int gr = (bx - 160) * 4 + w;
    int sel = gr >> 11, row = gr & 2047;
    const float* in = (sel == 0) ? x1_0 : (sel == 1) ? x1_1 : x2;
    float* out = (sel == 0) ? lnq1 : (sel == 1) ? lnq2 : lnkv;
    const float* xr = in + (size_t)row * kC;
    float xa = xr[lane], xb = xr[lane + 64];
    float m = wave_sum(xa + xb) * (1.f / kC);
    float da = xa - m, db = xb - m;
    float v = wave_sum(da * da + db * db) * (1.f / kC);
    float r = rsqrtf(v + 1e-5f);
    float* orow = out + (size_t)row * kC;
    orow[lane]      = da * r * ng[lane] + nb[lane];
    orow[lane + 64] = db * r * ng[lane + 64] + nb[lane + 64];
  } else if (bx < 1826) {
    int rel = bx - 1696;
    int idx = rel / 65, bb = rel - idx * 65;
    int tt = bb * 256 + t;
    if (tt <= kNT) {
      float rel_ = kRLO + (kRSPAN / (float)kNT) * (float)tt;
      float u = (rel_ >= 0.f ? 1.f : -1.f) * log1pf(fabsf(rel_));
      const float* W1 = cw1 + idx * 32; const float* B1 = cb1 + idx * 32;
      const float* W2 = cw2 + idx * 1024; const float* B2 = cb2 + idx * 32;
      const float* W3 = cw3 + idx * 32; const float* B3 = cb3 + idx;
      float h1[32];
#pragma unroll
      for (int m = 0; m < 32; ++m) h1[m] = fmaxf(0.f, u * W1[m] + B1[m]);
      float o = B3[0];
      for (int m = 0; m < 32; ++m) {
        float a = B2[m];
#pragma unroll
        for (int k = 0; k < 32; ++k) a += h1[k] * W2[k * 32 + m];
        o += fmaxf(a, 0.f) * W3[m];
      }
      tab[(size_t)idx * (kNT + 1) + tt] = o;
    }
  } else {
    int rel = bx - 1826;
    int i = rel >> 1, b = rel & 1;
    bool act = t < 128;
    __shared__ float red[2];
    __shared__ float s1[128];
    __shared__ float s2[128];
    const float* xs = (i ? x1_1 : x1_0) + (size_t)b * kN * kC;
    float x = act ? xs[t] : 0.f;
    float s = wave_sum(x);
    if (act && (t & 63) == 0) red[t >> 6] = s;
    __syncthreads();
    float m1 = (red[0] + red[1]) * (1.f / kC);
    __syncthreads();
    float d1 = x - m1;
    float ss = wave_sum(act ? d1 * d1 : 0.f);
    if (act && (t & 63) == 0) red[t >> 6] = ss;
    __syncthreads();
    float v1 = (red[0] + red[1]) * (1.f / kC);
    __syncthreads();
    float t0 = act ? d1 * rsqrtf(v1 + 1e-5f) * ng[t] + nb[t] : 0.f;
    s = wave_sum(t0);
    if (act && (t & 63) == 0) red[t >> 6] = s;
    __syncthreads();
    float m2 = (red[0] + red[1]) * (1.f / kC);
    __syncthreads();
    float d2 = t0 - m2;
    ss = wave_sum(act ? d2 * d2 : 0.f);
    if (act && (t & 63) == 0) red[t >> 6] = ss;
    __syncthreads();
    float v2 = (red[0] + red[1]) * (1.f / kC);
    if (act) s1[t] = d2 * rsqrtf(v2 + 1e-5f) * tfng[i * kC + t] + tfnb[i * kC + t];
    __syncthreads();
    if (act) {
      float a0 = 0.f;
      const float* wr = inw + (size_t)i * 384 * kC + (size_t)(256 + t) * kC;
      for (int c = 0; c < 128; ++c) a0 += s1[c] * wr[c];
      s2[t] = inb[i * 384 + 256 + t] + a0;
    }
    __syncthreads();
    if (act) {
      float a0 = 0.f;
      const float* wr2 = tow + (size_t)i * kC * kC + (size_t)t * kC;
      for (int c = 0; c < 128; ++c) a0 += s2[c] * wr2[c];
      mout[rel * kC + t] = tob[i * kC + t] + a0;
    }
  }
}

// ---------------- k_qoff: qproj ([0,512)) + offsets ([512,2560)) ----------------
__global__ void k_qoff(const float* __restrict__ lnq1, const float* __restrict__ lnq2,
                       const float* __restrict__ qw, const float* __restrict__ o1w,
                       const float* __restrict__ o1b, const float* __restrict__ o2w,
                       __hip_bfloat16* __restrict__ qt, float* __restrict__ vgs) {
  int bx = blockIdx.x;
  if (bx < 512) {
    int bg = bx >> 4, r0 = (bx & 15) * 64;
    int str = bg >> 4, b = (bg >> 3) & 1, g = bg & 7;
    int rl = threadIdx.x & 63, dq = threadIdx.x >> 6;
    const float* lnq = str ? lnq2 : lnq1;
    const float* xr = lnq + ((size_t)(b * kN + r0 + rl)) * kC + g * 16;
    float4 x0 = *(const float4*)(xr + 0);
    float4 x1 = *(const float4*)(xr + 4);
    float4 x2 = *(const float4*)(xr + 8);
    float4 x3 = *(const float4*)(xr + 12);
    const float* wqb = qw + (size_t)str * 8192 + (size_t)g * 1024;
#pragma unroll 4
    for (int dd = 0; dd < 16; ++dd) {
      int d = dq * 16 + dd;
      const float* wq = wqb + d * 16;
      float4 w0 = *(const float4*)(wq + 0);
      float4 w1 = *(const float4*)(wq + 4);
      float4 w2 = *(const float4*)(wq + 8);
      float4 w3 = *(const float4*)(wq + 12);
      float q = x0.x * w0.x + x0.y * w0.y + x0.z * w0.z + x0.w * w0.w
              + x1.x * w1.x + x1.y * w1.y + x1.z * w1.z + x1.w * w1.w
              + x2.x * w2.x + x2.y * w2.y + x2.z * w2.z + x2.w * w2.w
              + x3.x * w3.x + x3.y * w3.y + x3.z * w3.z + x3.w * w3.w;
      qt[((size_t)bg * 64 + d) * 1024 + r0 + rl] = __float2bfloat16(q);
    }
  } else {
    int bxo = bx - 512;
    int w = threadIdx.x >> 6, lane = threadIdx.x & 63;
    int bg = bxo >> 6, j = ((bxo & 63) << 2) + w;
    int str = bg >> 4, b = (bg >> 3) & 1, g = bg & 7;
    const float* lnq = str ? lnq2 : lnq1;
    __shared__ float xr[4][96];
    int base = j * 4 - 1;
#pragma unroll
    for (int rep = 0; rep < 2; ++rep) {
      int idx = lane + rep * 64;
      if (idx < 96) {
        int r = idx >> 4, c = idx & 15, n = base + r;
        xr[w][idx] = (n >= 0 && n < kN)
                         ? lnq[((size_t)(b * kN + n)) * kC + g * 16 + c] : 0.f;
      }
    }
    const float* wq = qw + (size_t)str * 8192 + (size_t)(g * kDH + lane) * 16;
    float acc = o1b[str * 64 + lane];
#pragma unroll
    for (int k2 = 0; k2 < 6; ++k2) {
      float qv = 0.f;
#pragma unroll
      for (int c = 0; c < 16; ++c) qv += xr[w][k2 * 16 + c] * wq[c];
      acc += qv * o1w[str * 384 + lane * 6 + k2];
    }
    float ge = 0.5f * acc * (1.f + erff(acc * 0.70710678118654752440f));
    float s = wave_sum(ge * o2w[str * 64 + lane]);
    if (lane == 0)
      vgs[bg * kND + j] = 2.f * ((float)j + tanhf(s) * 4.0f) / 255.f - 1.f;
  }
}

// ---------------- grid_sample + k/v projections ----------------
__global__ void k_sample_kv(const float* __restrict__ lnkv, const float* __restrict__ vgs,
                            const float* __restrict__ kw, const float* __restrict__ vw,
                            __hip_bfloat16* __restrict__ ktout,
                            __hip_bfloat16* __restrict__ vout) {
  int w = threadIdx.x >> 6, lane = threadIdx.x & 63;
  int bg = blockIdx.x >> 6, j = ((blockIdx.x & 63) << 2) + w;
  int str = bg >> 4, b = (bg >> 3) & 1, g = bg & 7;
  __shared__ float sc[4][16];
  if (lane < 16) {
    float gr = vgs[bg * kND + j];
    float x = ((gr + 1.f) * 1024.f - 1.f) * 0.5f;
    float x0f = floorf(x);
    float w1 = x - x0f;
    int x0 = (int)x0f, x1 = x0 + 1;
    const float* src = lnkv + (size_t)b * kN * kC + g * 16 + lane;
    float v0 = (x0 >= 0 && x0 < 1024) ? src[(size_t)x0 * kC] : 0.f;
    float v1 = (x1 >= 0 && x1 < 1024) ? src[(size_t)x1 * kC] : 0.f;
    sc[w][lane] = v0 * (1.f - w1) + v1 * w1;
  }
  const float* kwr = kw + (size_t)str * 8192 + (size_t)(g * kDH + lane) * 16;
  const float* vwr = vw + (size_t)str * 8192 + (size_t)(g * kDH + lane) * 16;
  float ka = 0.f, va = 0.f;
#pragma unroll
  for (int c = 0; c < 16; ++c) { ka += sc[w][c] * kwr[c]; va += sc[w][c] * vwr[c]; }
  ktout[((size_t)bg * 64 + lane) * 256 + j] = __float2bfloat16(ka);
  vout[((size_t)bg * 256 + j) * 64 + lane] = __float2bfloat16(va);
}

// ---------------- flash-tile attention, 32-row tiles, NO launch_bounds ----------------
__global__ void
k_attn(const __hip_bfloat16* __restrict__ qt_g, const __hip_bfloat16* __restrict__ kt_g,
       const __hip_bfloat16* __restrict__ v_g, const float* __restrict__ vgs,
       const float* __restrict__ tab, float* __restrict__ aout,
       float* __restrict__ attout) {
  int bg = blockIdx.x >> 5, tile = blockIdx.x & 31;
  int i0 = tile * 32;
  int str = bg >> 4;
  int t = threadIdx.x;
  int tr = t >> 5, tc = t & 31;

  __shared__ __hip_bfloat16 qt[64 * 32];   // [k][r]
  __shared__ __hip_bfloat16 stg[4096];     // K chunk [16][256] / V chunk [64][64]
  __shared__ __hip_bfloat16 P[32 * 260];

  const float* tabs = tab + str * (kNT + 1);

  // stage qt (4 KB): one float4 (8 bf16) per thread
  {
    int e = t * 8, d = e >> 5, r = e & 31;
    *(float4*)&qt[e] = *(const float4*)(qt_g + ((size_t)bg * 64 + d) * 1024 + i0 + r);
  }

  float4 accA[4], accB[4];
#pragma unroll
  for (int rr = 0; rr < 4; ++rr) { accA[rr] = {0,0,0,0}; accB[rr] = {0,0,0,0}; }

  // QK over 4 d-chunks of 16
  for (int ch = 0; ch < 4; ++ch) {
    __syncthreads();
#pragma unroll
    for (int it = 0; it < 2; ++it) {
      int e = t * 8 + it * 2048;
      int d = e >> 8, j = e & 255;
      *(float4*)&stg[e] =
          *(const float4*)(kt_g + ((size_t)bg * 64 + ch * 16 + d) * 256 + j);
    }
    __syncthreads();
#pragma unroll
    for (int k = 0; k < 16; ++k) {
      uint2 aq = *(const uint2*)&qt[(ch * 16 + k) * 32 + tr * 4];
      float ar[4] = {bf_lo(aq.x), bf_hi(aq.x), bf_lo(aq.y), bf_hi(aq.y)};
      uint2 b0 = *(const uint2*)&stg[k * 256 + tc * 4];
      uint2 b1 = *(const uint2*)&stg[k * 256 + 128 + tc * 4];
      float4 bA = {bf_lo(b0.x), bf_hi(b0.x), bf_lo(b0.y), bf_hi(b0.y)};
      float4 bB = {bf_lo(b1.x), bf_hi(b1.x), bf_lo(b1.y), bf_hi(b1.y)};
#pragma unroll
      for (int rr = 0; rr < 4; ++rr) {
        accA[rr].x += ar[rr] * bA.x; accA[rr].y += ar[rr] * bA.y;
        accA[rr].z += ar[rr] * bA.z; accA[rr].w += ar[rr] * bA.w;
        accB[rr].x += ar[rr] * bB.x; accB[rr].y += ar[rr] * bB.y;
        accB[rr].z += ar[rr] * bB.z; accB[rr].w += ar[rr] * bB.w;
      }
    }
  }

  // bias + softmax (rows spread over the 32 tc lanes)
  float4 vgA = *(const float4*)&vgs[bg * 256 + tc * 4];
  float4 vgB = *(const float4*)&vgs[bg * 256 + 128 + tc * 4];
  float* aoutb = aout + (size_t)str * 4194304 + (size_t)(bg & 15) * 262144;
#pragma unroll
  for (int rr = 0; rr < 4; ++rr) {
    int i = i0 + tr * 4 + rr;
    float seq = 2.f * (float)i / 1023.f - 1.f;
    float s[8];
    {
      const float* va = (const float*)&vgA;
      const float* vb = (const float*)&vgB;
      float* pa = (float*)&accA[rr];
      float* pb = (float*)&accB[rr];
#pragma unroll
      for (int c = 0; c < 4; ++c) {
        float rel = seq - va[c];
        float ft = (rel - kRLO) * ((float)kNT / kRSPAN);
        ft = fminf(fmaxf(ft, 0.f), 16383.999f);
        int ix = (int)ft; float fw = ft - (float)ix;
        s[c] = pa[c] * 0.125f + tabs[ix] * (1.f - fw) + tabs[ix + 1] * fw;
        rel = seq - vb[c];
        ft = (rel - kRLO) * ((float)kNT / kRSPAN);
        ft = fminf(fmaxf(ft, 0.f), 16383.999f);
        ix = (int)ft; fw = ft - (float)ix;
        s[4 + c] = pb[c] * 0.125f + tabs[ix] * (1.f - fw) + tabs[ix + 1] * fw;
      }
    }
    float m = fmaxf(fmaxf(fmaxf(s[0], s[1]), fmaxf(s[2], s[3])),
                    fmaxf(fmaxf(s[4], s[5]), fmaxf(s[6], s[7])));
#pragma unroll
    for (int mk = 1; mk <= 16; mk <<= 1) m = fmaxf(m, __shfl_xor(m, mk, 64));
    float e[8], sum = 0.f;
#pragma unroll
    for (int c = 0; c < 8; ++c) { e[c] = expf(s[c] - m); sum += e[c]; }
#pragma unroll
    for (int mk = 1; mk <= 16; mk <<= 1) sum += __shfl_xor(sum, mk, 64);
    float inv = 1.f / sum;
#pragma unroll
    for (int c = 0; c < 8; ++c) e[c] *= inv;
    float* arow = aoutb + (size_t)i * 256;
    *(float4*)&arow[tc * 4]       = {e[0], e[1], e[2], e[3]};
    *(float4*)&arow[128 + tc * 4] = {e[4], e[5], e[6], e[7]};
    uint2 pl = {cvtpk_bf16(e[0], e[1]), cvtpk_bf16(e[2], e[3])};
    uint2 ph = {cvtpk_bf16(e[4], e[5]), cvtpk_bf16(e[6], e[7])};
    *(uint2*)&P[(tr * 4 + rr) * 260 + tc * 4]       = pl;
    *(uint2*)&P[(tr * 4 + rr) * 260 + 128 + tc * 4] = ph;
  }

  // PV: thread (rg = t>>4 -> rows rg*2..+1, dg = t&15 -> d dg*4..+3)
  int rg = t >> 4, dg = t & 15;
  float4 acc[2] = {{0,0,0,0},{0,0,0,0}};
  for (int ch = 0; ch < 4; ++ch) {
    __syncthreads();
#pragma unroll
    for (int it = 0; it < 2; ++it) {
      int e = t * 8 + it * 2048;
      int j = e >> 6, d = e & 63;
      *(float4*)&stg[e] =
          *(const float4*)(v_g + ((size_t)bg * 256 + ch * 64 + j) * 64 + d);
    }
    __syncthreads();
#pragma unroll 4
    for (int jq = 0; jq < 16; ++jq) {
      int jl = jq * 4;
      int jg = ch * 64 + jl;
      uint2 p0 = *(const uint2*)&P[(rg * 2 + 0) * 260 + jg];
      uint2 p1 = *(const uint2*)&P[(rg * 2 + 1) * 260 + jg];
      float a0[4] = {bf_lo(p0.x), bf_hi(p0.x), bf_lo(p0.y), bf_hi(p0.y)};
      float a1[4] = {bf_lo(p1.x), bf_hi(p1.x), bf_lo(p1.y), bf_hi(p1.y)};
#pragma unroll
      for (int jj = 0; jj < 4; ++jj) {
        uint2 vv = *(const uint2*)&stg[(jl + jj) * 64 + dg * 4];
        float4 v4 = {bf_lo(vv.x), bf_hi(vv.x), bf_lo(vv.y), bf_hi(vv.y)};
        acc[0].x += a0[jj] * v4.x; acc[0].y += a0[jj] * v4.y;
        acc[0].z += a0[jj] * v4.z; acc[0].w += a0[jj] * v4.w;
        acc[1].x += a1[jj] * v4.x; acc[1].y += a1[jj] * v4.y;
        acc[1].z += a1[jj] * v4.z; acc[1].w += a1[jj] * v4.w;
      }
    }
  }
#pragma unroll
  for (int rr = 0; rr < 2; ++rr)
    *(float4*)&attout[((size_t)bg * 1024 + i0 + rg * 2 + rr) * 64 + dg * 4] = acc[rr];
}

// ---------------- oproj (both streams) + residual + fuse ----------------
__global__ void k_oproj_fuse(const float* __restrict__ ao, const float* __restrict__ owT1,
                             const float* __restrict__ owT2, const float* __restrict__ ob,
                             const float* __restrict__ x1_0, const float* __restrict__ x1_1,
                             const float* __restrict__ fwT, const float* __restrict__ fb,
                             float* __restrict__ fused) {
  int tok0 = blockIdx.x * 8;
  int t = threadIdx.x;
  int o = t & 127, th = t >> 7;
  __shared__ float s[8 * 512];
  __shared__ float xoL[2][8 * 128];
  for (int strm = 0; strm < 2; ++strm) {
    __syncthreads();
#pragma unroll
    for (int k = 0; k < 16; ++k) {
      int fi = t + k * 256;
      int tok = fi >> 9, c = fi & 511;
      int tg = tok0 + tok;
      int b = tg >> 10, n = tg & 1023;
      s[fi] = ao[((size_t)(strm * 16 + b * 8 + (c >> 6)) * 1024 + n) * 64 + (c & 63)];
    }
    __syncthreads();
    const float* owT = strm ? owT2 : owT1;
    const float* x1 = strm ? x1_1 : x1_0;
    float acc0 = 0.f, acc1 = 0.f, acc2 = 0.f, acc3 = 0.f;
    for (int c = 0; c < 512; c += 4) {
      float wa = owT[(c + 0) * kC + o];
      float wb = owT[(c + 1) * kC + o];
      float wc = owT[(c + 2) * kC + o];
      float wd = owT[(c + 3) * kC + o];
      const float4 sa = *(const float4*)&s[(th + 0) * 512 + c];
      const float4 sb = *(const float4*)&s[(th + 2) * 512 + c];
      const float4 sc4 = *(const float4*)&s[(th + 4) * 512 + c];
      const float4 sd = *(const float4*)&s[(th + 6) * 512 + c];
      acc0 += sa.x * wa + sa.y * wb + sa.z * wc + sa.w * wd;
      acc1 += sb.x * wa + sb.y * wb + sb.z * wc + sb.w * wd;
      acc2 += sc4.x * wa + sc4.y * wb + sc4.z * wc + sc4.w * wd;
      acc3 += sd.x * wa + sd.y * wb + sd.z * wc + sd.w * wd;
    }
    float bias = ob[strm * 128 + o];
    float accs[4] = {acc0, acc1, acc2, acc3};
#pragma unroll
    for (int k = 0; k < 4; ++k) {
      int tok = th + k * 2;
      int tg = tok0 + tok;
      xoL[strm][tok * 128 + o] = x1[(size_t)tg * kC + o] + accs[k] + bias;
    }
  }
  __syncthreads();
  float fa[4] = {0.f, 0.f, 0.f, 0.f};
  for (int c = 0; c < 128; ++c) {
    float w0 = fwT[c * kC + o];
    float w1 = fwT[(128 + c) * kC + o];
#pragma unroll
    for (int k = 0; k < 4; ++k) {
      int tok = th + k * 2;
      fa[k] += xoL[0][tok * 128 + c] * w0 + xoL[1][tok * 128 + c] * w1;
    }
  }
#pragma unroll
  for (int k = 0; k < 4; ++k)
    fused[(size_t)(tok0 + th + k * 2) * kC + o] = fa[k] + fb[o];
}

// ---------------- double-LN + mout, wave per token, chunk partials ----------------
__global__ void k_meanz(const float* __restrict__ fused, const float* __restrict__ ng,
                        const float* __restrict__ nb, const float* __restrict__ tfng,
                        const float* __restrict__ tfnb, const float* __restrict__ mout,
                        float* __restrict__ partial) {
  int chunk = blockIdx.x, b = blockIdx.y, i = blockIdx.z;
  int w = threadIdx.x >> 6, lane = threadIdx.x & 63;
  int c = lane, c2 = lane + 64;
  float moa = mout[(i * 2 + b) * kC + c], mob = mout[(i * 2 + b) * kC + c2];
  float g1a = ng[c], b1a = nb[c], g1b = ng[c2], b1b = nb[c2];
  float g2a = tfng[i * kC + c], b2a = tfnb[i * kC + c];
  float g2b = tfng[i * kC + c2], b2b = tfnb[i * kC + c2];
  float acca = 0.f, accb = 0.f;
#pragma unroll
  for (int it = 0; it < 4; ++it) {
    int tok = chunk * 16 + it * 4 + w;
    const float* xr = fused + ((size_t)(b * kN + tok)) * kC;
    float xa = xr[c], xb = xr[c2];
    float m1 = wave_sum(xa + xb) * (1.f / kC);
    float da = xa - m1, db = xb - m1;
    float v1 = wave_sum(da * da + db * db) * (1.f / kC);
    float r1 = rsqrtf(v1 + 1e-5f);
    float za = da * r1 * g1a + b1a + moa;
    float zb = db * r1 * g1b + b1b + mob;
    float m2 = wave_sum(za + zb) * (1.f / kC);
    float ea = za - m2, eb = zb - m2;
    float v2 = wave_sum(ea * ea + eb * eb) * (1.f / kC);
    float r2 = rsqrtf(v2 + 1e-5f);
    acca += ea * r2 * g2a + b2a;
    accb += eb * r2 * g2b + b2b;
  }
  __shared__ float red[4][128];
  red[w][c] = acca; red[w][c2] = accb;
  __syncthreads();
  if (w == 0) {
    float pa = red[0][c] + red[1][c] + red[2][c] + red[3][c];
    float pb = red[0][c2] + red[1][c2] + red[2][c2] + red[3][c2];
    float* pr = partial + ((size_t)(i * 2 + b) * 64 + chunk) * kC;
    pr[c] = pa; pr[c2] = pb;
  }
}

__global__ void k_final(const float* __restrict__ partial, const float* __restrict__ pw,
                        const float* __restrict__ pb, float* __restrict__ out) {
  int ib = blockIdx.x;
  int i = ib >> 1, t = threadIdx.x;
  int c = t & 127, half = t >> 7;
  float a = 0.f;
  for (int ch = half * 32; ch < half * 32 + 32; ++ch)
    a += partial[((size_t)ib * 64 + ch) * kC + c];
  __shared__ float s[256];
  s[half * 128 + c] = a;
  __syncthreads();
  if (t < 128) s[t] = (s[t] + s[128 + t]) * (1.f / (float)kN);
  __syncthreads();
  if (t < 128) {
    float a0 = 0.f;
    const float* wr = pw + (size_t)i * kC * kC + (size_t)t * kC;
    for (int cc = 0; cc < 128; ++cc) a0 += s[cc] * wr[cc];
    out[ib * 128 + t] = tanhf(pb[i * kC + t] + a0);
  }
}

extern "C" void kernel_launch(void* const* d_in, const int* in_sizes, int n_in,
                              void* d_out, int out_size, void* d_ws, size_t ws_size,
                              hipStream_t stream) {
  const float* x1_0   = (const float*)d_in[0];
  const float* x1_1   = (const float*)d_in[1];
  const float* x2     = (const float*)d_in[2];
  const float* norm_g = (const float*)d_in[3];
  const float* norm_b = (const float*)d_in[4];
  const float* d_qw   = (const float*)d_in[5];
  const float* d_kw   = (const float*)d_in[6];
  const float* d_vw   = (const float*)d_in[7];
  const float* d_ow   = (const float*)d_in[8];
  const float* d_ob   = (const float*)d_in[9];
  const float* d_o1w  = (const float*)d_in[10];
  const float* d_o1b  = (const float*)d_in[11];
  const float* d_o2w  = (const float*)d_in[12];
  const float* c_w1   = (const float*)d_in[13];
  const float* c_b1   = (const float*)d_in[14];
  const float* c_w2   = (const float*)d_in[15];
  const float* c_b2   = (const float*)d_in[16];
  const float* c_w3   = (const float*)d_in[17];
  const float* c_b3   = (const float*)d_in[18];
  const float* fus_w  = (const float*)d_in[19];
  const float* fus_b  = (const float*)d_in[20];
  const float* tf_ng  = (const float*)d_in[21];
  const float* tf_nb  = (const float*)d_in[22];
  const float* tf_inw = (const float*)d_in[23];
  const float* tf_inb = (const float*)d_in[24];
  const float* tf_ow  = (const float*)d_in[25];
  const float* tf_ob  = (const float*)d_in[26];
  const float* tf_pw  = (const float*)d_in[27];
  const float* tf_pb  = (const float*)d_in[28];

  float* ws = (float*)d_ws;
  float* out = (float*)d_out;
  float* lnkv = ws + W_LNKV;
  float* lnq1 = ws + W_LNQ1; float* lnq2 = ws + W_LNQ2;
  __hip_bfloat16* qtb = (__hip_bfloat16*)(ws + W_QT);
  __hip_bfloat16* ktb = (__hip_bfloat16*)(ws + W_KT);
  __hip_bfloat16* vb  = (__hip_bfloat16*)(ws + W_V);
  float* vgsw = ws + W_VGS;
  float* ao = ws + W_AO;
  float* fused = ws + W_FUS; float* tab = ws + W_TAB;
  float* moutp = ws + W_MOUT; float* partp = ws + W_PART;
  float* owT1 = ws + W_OWT1; float* owT2 = ws + W_OWT2;
  float* fwT = ws + W_FWT;

  // output: f1(256) | f2(256) | a1(2*8*1024*256) | a2(same), all f32
  float* aoutb = out + 512;

  k_prep<<<1830, 256, 0, stream>>>(d_ow, fus_w, owT1, owT2, fwT,
                                   x1_0, x1_1, x2, lnq1, lnq2, lnkv, norm_g, norm_b,
                                   c_w1, c_b1, c_w2, c_b2, c_w3, c_b3, tab,
                                   tf_ng, tf_nb, tf_inw, tf_inb, tf_ow, tf_ob, moutp);
  k_qoff<<<2560, 256, 0, stream>>>(lnq1, lnq2, d_qw, d_o1w, d_o1b, d_o2w, qtb, vgsw);
  k_sample_kv<<<2048, 256, 0, stream>>>(lnkv, vgsw, d_kw, d_vw, ktb, vb);
  k_attn<<<1024, 256, 0, stream>>>(qtb, ktb, vb, vgsw, tab, aoutb, ao);
  k_oproj_fuse<<<256, 256, 0, stream>>>(ao, owT1, owT2, d_ob, x1_0, x1_1, fwT,
                                        fus_b, fused);
  k_meanz<<<dim3(64, 2, 2), 256, 0, stream>>>(fused, norm_g, norm_b, tf_ng, tf_nb,
                                              moutp, partp);
  k_final<<<4, 256, 0, stream>>>(partp, tf_pw, tf_pb, out);

  (void)in_sizes; (void)n_in; (void)out_size; (void)ws_size;
}

// Round 9
// 153.745 us; speedup vs baseline: 1.8223x; 1.8223x over previous
//
#include <hip/hip_runtime.h>
#include <hip/hip_bf16.h>

// UniTeacherEncoder v9: k_attn with __launch_bounds__(256,2) (the ONLY config
// measured spill-free: v5 (256,2)->VGPR128/0 scratch; (256,4)/(256,3)/none ->
// VGPR 64/84/64 with 280-940MB scratch traffic) + fully scalarized register
// arrays (no address-taken locals, rule-#20 insurance).

namespace {

constexpr int kN  = 1024;
constexpr int kC  = 128;
constexpr int kG  = 8;
constexpr int kDH = 64;
constexpr int kND = 256;

constexpr int   kNT    = 16384;
constexpr float kRLO   = -2.0625f;   // rel in [-2.032, 2.032] guaranteed (|off|<=4)
constexpr float kRSPAN = 4.125f;

// workspace layout (float offsets)
constexpr size_t W_LNKV = 0;          // 2048 x 128 f32
constexpr size_t W_LNQ1 = 262144;
constexpr size_t W_LNQ2 = 524288;
constexpr size_t W_QT   = 786432;     // bf16 [32 bg][64 d][1024 r]
constexpr size_t W_KT   = 1835008;    // bf16 [32 bg][64 d][256 j]
constexpr size_t W_V    = 2097152;    // bf16 [32 bg][256 j][64 d]
constexpr size_t W_VGS  = 2359296;    // f32 [32][256]
constexpr size_t W_AO   = 2367488;    // f32 [32 bg][1024][64]
constexpr size_t W_FUS  = 4988928;    // f32 2048 x 128
constexpr size_t W_TAB  = 5251072;    // f32 2 x 16385
constexpr size_t W_MOUT = 5283844;    // 4 x 128
constexpr size_t W_PART = 5284356;    // 4 x 64 x 128
constexpr size_t W_OWT1 = 5317124;    // 512 x 128
constexpr size_t W_OWT2 = 5382660;
constexpr size_t W_FWT  = 5448196;    // 256 x 128

} // namespace

__device__ __forceinline__ float wave_sum(float v) {
#pragma unroll
  for (int o = 32; o > 0; o >>= 1) v += __shfl_xor(v, o, 64);
  return v;
}
__device__ __forceinline__ float bf_lo(unsigned int u) {
  return __uint_as_float(u << 16);
}
__device__ __forceinline__ float bf_hi(unsigned int u) {
  return __uint_as_float(u & 0xffff0000u);
}
__device__ __forceinline__ unsigned int cvtpk_bf16(float lo, float hi) {
  unsigned int r;
  asm volatile("v_cvt_pk_bf16_f32 %0, %1, %2" : "=v"(r) : "v"(lo), "v"(hi));
  return r;
}
__device__ __forceinline__ float cpb_bias(const float* __restrict__ tabs,
                                          float seq, float vg) {
  float rel = seq - vg;
  float ft = (rel - kRLO) * ((float)kNT / kRSPAN);
  ft = fminf(fmaxf(ft, 0.f), 16383.999f);
  int ix = (int)ft;
  float fw = ft - (float)ix;
  return tabs[ix] * (1.f - fw) + tabs[ix + 1] * fw;
}

// ---------------- k_prep: transposes + LN x3 + CPB table + mout ----------------
__global__ void k_prep(const float* __restrict__ ow, const float* __restrict__ fw,
                       float* __restrict__ owT1, float* __restrict__ owT2,
                       float* __restrict__ fwT,
                       const float* __restrict__ x1_0, const float* __restrict__ x1_1,
                       const float* __restrict__ x2, float* __restrict__ lnq1,
                       float* __restrict__ lnq2, float* __restrict__ lnkv,
                       const float* __restrict__ ng, const float* __restrict__ nb,
                       const float* __restrict__ cw1, const float* __restrict__ cb1,
                       const float* __restrict__ cw2, const float* __restrict__ cb2,
                       const float* __restrict__ cw3, const float* __restrict__ cb3,
                       float* __restrict__ tab,
                       const float* __restrict__ tfng, const float* __restrict__ tfnb,
                       const float* __restrict__ inw, const float* __restrict__ inb,
                       const float* __restrict__ tow, const float* __restrict__ tob,
                       float* __restrict__ mout) {
  int bx = blockIdx.x;
  int t = threadIdx.x;
  if (bx < 160) {
    const float* src; float* dst; int R, C, tile;
    if (bx < 64)       { src = ow;          dst = owT1; R = 128; C = 512; tile = bx; }
    else if (bx < 128) { src = ow + 65536;  dst = owT2; R = 128; C = 512; tile = bx - 64; }
    else               { src = fw;          dst = fwT;  R = 128; C = 256; tile = bx - 128; }
    int tpr = C >> 5;
    int ti = tile / tpr, tj = tile - ti * tpr;
    __shared__ float tl[32][33];
    int x = t & 31, ys = t >> 5;
#pragma unroll
    for (int p = 0; p < 4; ++p) {
      int y = ys + p * 8;
      tl[y][x] = src[(size_t)(ti * 32 + y) * C + tj * 32 + x];
    }
    __syncthreads();
#pragma unroll
    for (int p = 0; p < 4; ++p) {
      int y = ys + p * 8;
      dst[(size_t)(tj * 32 + y) * R + ti * 32 + x] = tl[x][y];
    }
  } else if (bx < 1696) {
    int w = t >> 6, lane = t & 63;
    int gr = (bx - 160) * 4 + w;
    int sel = gr >> 11, row = gr & 2047;
    const float* in = (sel == 0) ? x1_0 : (sel == 1) ? x1_1 : x2;
    float* out = (sel == 0) ? lnq1 : (sel == 1) ? lnq2 : lnkv;
    const float* xr = in + (size_t)row * kC;
    float xa = xr[lane], xb = xr[lane + 64];
    float m = wave_sum(xa + xb) * (1.f / kC);
    float da = xa - m, db = xb - m;
    float v = wave_sum(da * da + db * db) * (1.f / kC);
    float r = rsqrtf(v + 1e-5f);
    float* orow = out + (size_t)row * kC;
    orow[lane]      = da * r * ng[lane] + nb[lane];
    orow[lane + 64] = db * r * ng[lane + 64] + nb[lane + 64];
  } else if (bx < 1826) {
    int rel = bx - 1696;
    int idx = rel / 65, bb = rel - idx * 65;
    int tt = bb * 256 + t;
    if (tt <= kNT) {
      float rel_ = kRLO + (kRSPAN / (float)kNT) * (float)tt;
      float u = (rel_ >= 0.f ? 1.f : -1.f) * log1pf(fabsf(rel_));
      const float* W1 = cw1 + idx * 32; const float* B1 = cb1 + idx * 32;
      const float* W2 = cw2 + idx * 1024; const float* B2 = cb2 + idx * 32;
      const float* W3 = cw3 + idx * 32; const float* B3 = cb3 + idx;
      float h1[32];
#pragma unroll
      for (int m = 0; m < 32; ++m) h1[m] = fmaxf(0.f, u * W1[m] + B1[m]);
      float o = B3[0];
      for (int m = 0; m < 32; ++m) {
        float a = B2[m];
#pragma unroll
        for (int k = 0; k < 32; ++k) a += h1[k] * W2[k * 32 + m];
        o += fmaxf(a, 0.f) * W3[m];
      }
      tab[(size_t)idx * (kNT + 1) + tt] = o;
    }
  } else {
    int rel = bx - 1826;
    int i = rel >> 1, b = rel & 1;
    bool act = t < 128;
    __shared__ float red[2];
    __shared__ float s1[128];
    __shared__ float s2[128];
    const float* xs = (i ? x1_1 : x1_0) + (size_t)b * kN * kC;
    float x = act ? xs[t] : 0.f;
    float s = wave_sum(x);
    if (act && (t & 63) == 0) red[t >> 6] = s;
    __syncthreads();
    float m1 = (red[0] + red[1]) * (1.f / kC);
    __syncthreads();
    float d1 = x - m1;
    float ss = wave_sum(act ? d1 * d1 : 0.f);
    if (act && (t & 63) == 0) red[t >> 6] = ss;
    __syncthreads();
    float v1 = (red[0] + red[1]) * (1.f / kC);
    __syncthreads();
    float t0 = act ? d1 * rsqrtf(v1 + 1e-5f) * ng[t] + nb[t] : 0.f;
    s = wave_sum(t0);
    if (act && (t & 63) == 0) red[t >> 6] = s;
    __syncthreads();
    float m2 = (red[0] + red[1]) * (1.f / kC);
    __syncthreads();
    float d2 = t0 - m2;
    ss = wave_sum(act ? d2 * d2 : 0.f);
    if (act && (t & 63) == 0) red[t >> 6] = ss;
    __syncthreads();
    float v2 = (red[0] + red[1]) * (1.f / kC);
    if (act) s1[t] = d2 * rsqrtf(v2 + 1e-5f) * tfng[i * kC + t] + tfnb[i * kC + t];
    __syncthreads();
    if (act) {
      float a0 = 0.f;
      const float* wr = inw + (size_t)i * 384 * kC + (size_t)(256 + t) * kC;
      for (int c = 0; c < 128; ++c) a0 += s1[c] * wr[c];
      s2[t] = inb[i * 384 + 256 + t] + a0;
    }
    __syncthreads();
    if (act) {
      float a0 = 0.f;
      const float* wr2 = tow + (size_t)i * kC * kC + (size_t)t * kC;
      for (int c = 0; c < 128; ++c) a0 += s2[c] * wr2[c];
      mout[rel * kC + t] = tob[i * kC + t] + a0;
    }
  }
}

// ---------------- k_qoff: qproj ([0,512)) + offsets ([512,2560)) ----------------
__global__ void k_qoff(const float* __restrict__ lnq1, const float* __restrict__ lnq2,
                       const float* __restrict__ qw, const float* __restrict__ o1w,
                       const float* __restrict__ o1b, const float* __restrict__ o2w,
                       __hip_bfloat16* __restrict__ qt, float* __restrict__ vgs) {
  int bx = blockIdx.x;
  if (bx < 512) {
    int bg = bx >> 4, r0 = (bx & 15) * 64;
    int str = bg >> 4, b = (bg >> 3) & 1, g = bg & 7;
    int rl = threadIdx.x & 63, dq = threadIdx.x >> 6;
    const float* lnq = str ? lnq2 : lnq1;
    const float* xr = lnq + ((size_t)(b * kN + r0 + rl)) * kC + g * 16;
    float4 x0 = *(const float4*)(xr + 0);
    float4 x1 = *(const float4*)(xr + 4);
    float4 x2 = *(const float4*)(xr + 8);
    float4 x3 = *(const float4*)(xr + 12);
    const float* wqb = qw + (size_t)str * 8192 + (size_t)g * 1024;
#pragma unroll 4
    for (int dd = 0; dd < 16; ++dd) {
      int d = dq * 16 + dd;
      const float* wq = wqb + d * 16;
      float4 w0 = *(const float4*)(wq + 0);
      float4 w1 = *(const float4*)(wq + 4);
      float4 w2 = *(const float4*)(wq + 8);
      float4 w3 = *(const float4*)(wq + 12);
      float q = x0.x * w0.x + x0.y * w0.y + x0.z * w0.z + x0.w * w0.w
              + x1.x * w1.x + x1.y * w1.y + x1.z * w1.z + x1.w * w1.w
              + x2.x * w2.x + x2.y * w2.y + x2.z * w2.z + x2.w * w2.w
              + x3.x * w3.x + x3.y * w3.y + x3.z * w3.z + x3.w * w3.w;
      qt[((size_t)bg * 64 + d) * 1024 + r0 + rl] = __float2bfloat16(q);
    }
  } else {
    int bxo = bx - 512;
    int w = threadIdx.x >> 6, lane = threadIdx.x & 63;
    int bg = bxo >> 6, j = ((bxo & 63) << 2) + w;
    int str = bg >> 4, b = (bg >> 3) & 1, g = bg & 7;
    const float* lnq = str ? lnq2 : lnq1;
    __shared__ float xr[4][96];
    int base = j * 4 - 1;
#pragma unroll
    for (int rep = 0; rep < 2; ++rep) {
      int idx = lane + rep * 64;
      if (idx < 96) {
        int r = idx >> 4, c = idx & 15, n = base + r;
        xr[w][idx] = (n >= 0 && n < kN)
                         ? lnq[((size_t)(b * kN + n)) * kC + g * 16 + c] : 0.f;
      }
    }
    const float* wq = qw + (size_t)str * 8192 + (size_t)(g * kDH + lane) * 16;
    float acc = o1b[str * 64 + lane];
#pragma unroll
    for (int k2 = 0; k2 < 6; ++k2) {
      float qv = 0.f;
#pragma unroll
      for (int c = 0; c < 16; ++c) qv += xr[w][k2 * 16 + c] * wq[c];
      acc += qv * o1w[str * 384 + lane * 6 + k2];
    }
    float ge = 0.5f * acc * (1.f + erff(acc * 0.70710678118654752440f));
    float s = wave_sum(ge * o2w[str * 64 + lane]);
    if (lane == 0)
      vgs[bg * kND + j] = 2.f * ((float)j + tanhf(s) * 4.0f) / 255.f - 1.f;
  }
}

// ---------------- grid_sample + k/v projections ----------------
__global__ void k_sample_kv(const float* __restrict__ lnkv, const float* __restrict__ vgs,
                            const float* __restrict__ kw, const float* __restrict__ vw,
                            __hip_bfloat16* __restrict__ ktout,
                            __hip_bfloat16* __restrict__ vout) {
  int w = threadIdx.x >> 6, lane = threadIdx.x & 63;
  int bg = blockIdx.x >> 6, j = ((blockIdx.x & 63) << 2) + w;
  int str = bg >> 4, b = (bg >> 3) & 1, g = bg & 7;
  __shared__ float sc[4][16];
  if (lane < 16) {
    float gr = vgs[bg * kND + j];
    float x = ((gr + 1.f) * 1024.f - 1.f) * 0.5f;
    float x0f = floorf(x);
    float w1 = x - x0f;
    int x0 = (int)x0f, x1 = x0 + 1;
    const float* src = lnkv + (size_t)b * kN * kC + g * 16 + lane;
    float v0 = (x0 >= 0 && x0 < 1024) ? src[(size_t)x0 * kC] : 0.f;
    float v1 = (x1 >= 0 && x1 < 1024) ? src[(size_t)x1 * kC] : 0.f;
    sc[w][lane] = v0 * (1.f - w1) + v1 * w1;
  }
  const float* kwr = kw + (size_t)str * 8192 + (size_t)(g * kDH + lane) * 16;
  const float* vwr = vw + (size_t)str * 8192 + (size_t)(g * kDH + lane) * 16;
  float ka = 0.f, va = 0.f;
#pragma unroll
  for (int c = 0; c < 16; ++c) { ka += sc[w][c] * kwr[c]; va += sc[w][c] * vwr[c]; }
  ktout[((size_t)bg * 64 + lane) * 256 + j] = __float2bfloat16(ka);
  vout[((size_t)bg * 256 + j) * 64 + lane] = __float2bfloat16(va);
}

// ---------------- flash-tile attention, 32-row tiles, (256,2), scalarized ----------------
#define SOFTMAX_ROW(RR, PA, PB)                                                     \
  {                                                                                 \
    int i = i0 + tr * 4 + RR;                                                       \
    float seq = 2.f * (float)i / 1023.f - 1.f;                                      \
    float s0 = PA.x * 0.125f + cpb_bias(tabs, seq, vgA.x);                          \
    float s1 = PA.y * 0.125f + cpb_bias(tabs, seq, vgA.y);                          \
    float s2 = PA.z * 0.125f + cpb_bias(tabs, seq, vgA.z);                          \
    float s3 = PA.w * 0.125f + cpb_bias(tabs, seq, vgA.w);                          \
    float s4 = PB.x * 0.125f + cpb_bias(tabs, seq, vgB.x);                          \
    float s5 = PB.y * 0.125f + cpb_bias(tabs, seq, vgB.y);                          \
    float s6 = PB.z * 0.125f + cpb_bias(tabs, seq, vgB.z);                          \
    float s7 = PB.w * 0.125f + cpb_bias(tabs, seq, vgB.w);                          \
    float m = fmaxf(fmaxf(fmaxf(s0, s1), fmaxf(s2, s3)),                            \
                    fmaxf(fmaxf(s4, s5), fmaxf(s6, s7)));                           \
    m = fmaxf(m, __shfl_xor(m, 1, 64));                                             \
    m = fmaxf(m, __shfl_xor(m, 2, 64));                                             \
    m = fmaxf(m, __shfl_xor(m, 4, 64));                                             \
    m = fmaxf(m, __shfl_xor(m, 8, 64));                                             \
    m = fmaxf(m, __shfl_xor(m, 16, 64));                                            \
    float e0 = expf(s0 - m), e1 = expf(s1 - m), e2 = expf(s2 - m),                  \
          e3 = expf(s3 - m), e4 = expf(s4 - m), e5 = expf(s5 - m),                  \
          e6 = expf(s6 - m), e7 = expf(s7 - m);                                     \
    float sum = e0 + e1 + e2 + e3 + e4 + e5 + e6 + e7;                              \
    sum += __shfl_xor(sum, 1, 64);                                                  \
    sum += __shfl_xor(sum, 2, 64);                                                  \
    sum += __shfl_xor(sum, 4, 64);                                                  \
    sum += __shfl_xor(sum, 8, 64);                                                  \
    sum += __shfl_xor(sum, 16, 64);                                                 \
    float inv = 1.f / sum;                                                          \
    e0 *= inv; e1 *= inv; e2 *= inv; e3 *= inv;                                     \
    e4 *= inv; e5 *= inv; e6 *= inv; e7 *= inv;                                     \
    float* arow = aoutb + (size_t)i * 256;                                          \
    float4 oA = {e0, e1, e2, e3};                                                   \
    float4 oB = {e4, e5, e6, e7};                                                   \
    *(float4*)&arow[tc * 4] = oA;                                                   \
    *(float4*)&arow[128 + tc * 4] = oB;                                             \
    uint2 pl = {cvtpk_bf16(e0, e1), cvtpk_bf16(e2, e3)};                            \
    uint2 ph = {cvtpk_bf16(e4, e5), cvtpk_bf16(e6, e7)};                            \
    *(uint2*)&P[(tr * 4 + RR) * 260 + tc * 4] = pl;                                 \
    *(uint2*)&P[(tr * 4 + RR) * 260 + 128 + tc * 4] = ph;                           \
  }

__global__ void __launch_bounds__(256, 2)
k_attn(const __hip_bfloat16* __restrict__ qt_g, const __hip_bfloat16* __restrict__ kt_g,
       const __hip_bfloat16* __restrict__ v_g, const float* __restrict__ vgs,
       const float* __restrict__ tab, float* __restrict__ aout,
       float* __restrict__ attout) {
  int bg = blockIdx.x >> 5, tile = blockIdx.x & 31;
  int i0 = tile * 32;
  int str = bg >> 4;
  int t = threadIdx.x;
  int tr = t >> 5, tc = t & 31;

  __shared__ __hip_bfloat16 qt[64 * 32];   // [k][r]
  __shared__ __hip_bfloat16 stg[4096];     // K chunk [16][256] / V chunk [64][64]
  __shared__ __hip_bfloat16 P[32 * 260];

  const float* tabs = tab + str * (kNT + 1);

  // stage qt (4 KB): one float4 (8 bf16) per thread
  {
    int e = t * 8, d = e >> 5, r = e & 31;
    *(float4*)&qt[e] = *(const float4*)(qt_g + ((size_t)bg * 64 + d) * 1024 + i0 + r);
  }

  float4 accA0 = {0,0,0,0}, accA1 = {0,0,0,0}, accA2 = {0,0,0,0}, accA3 = {0,0,0,0};
  float4 accB0 = {0,0,0,0}, accB1 = {0,0,0,0}, accB2 = {0,0,0,0}, accB3 = {0,0,0,0};

  // QK over 4 d-chunks of 16
  for (int ch = 0; ch < 4; ++ch) {
    __syncthreads();
#pragma unroll
    for (int it = 0; it < 2; ++it) {
      int e = t * 8 + it * 2048;
      int d = e >> 8, j = e & 255;
      *(float4*)&stg[e] =
          *(const float4*)(kt_g + ((size_t)bg * 64 + ch * 16 + d) * 256 + j);
    }
    __syncthreads();
#pragma unroll
    for (int k = 0; k < 16; ++k) {
      uint2 aq = *(const uint2*)&qt[(ch * 16 + k) * 32 + tr * 4];
      float ar0 = bf_lo(aq.x), ar1 = bf_hi(aq.x), ar2 = bf_lo(aq.y), ar3 = bf_hi(aq.y);
      uint2 b0 = *(const uint2*)&stg[k * 256 + tc * 4];
      uint2 b1 = *(const uint2*)&stg[k * 256 + 128 + tc * 4];
      float bA0 = bf_lo(b0.x), bA1 = bf_hi(b0.x), bA2 = bf_lo(b0.y), bA3 = bf_hi(b0.y);
      float bB0 = bf_lo(b1.x), bB1 = bf_hi(b1.x), bB2 = bf_lo(b1.y), bB3 = bf_hi(b1.y);
      accA0.x += ar0 * bA0; accA0.y += ar0 * bA1; accA0.z += ar0 * bA2; accA0.w += ar0 * bA3;
      accA1.x += ar1 * bA0; accA1.y += ar1 * bA1; accA1.z += ar1 * bA2; accA1.w += ar1 * bA3;
      accA2.x += ar2 * bA0; accA2.y += ar2 * bA1; accA2.z += ar2 * bA2; accA2.w += ar2 * bA3;
      accA3.x += ar3 * bA0; accA3.y += ar3 * bA1; accA3.z += ar3 * bA2; accA3.w += ar3 * bA3;
      accB0.x += ar0 * bB0; accB0.y += ar0 * bB1; accB0.z += ar0 * bB2; accB0.w += ar0 * bB3;
      accB1.x += ar1 * bB0; accB1.y += ar1 * bB1; accB1.z += ar1 * bB2; accB1.w += ar1 * bB3;
      accB2.x += ar2 * bB0; accB2.y += ar2 * bB1; accB2.z += ar2 * bB2; accB2.w += ar2 * bB3;
      accB3.x += ar3 * bB0; accB3.y += ar3 * bB1; accB3.z += ar3 * bB2; accB3.w += ar3 * bB3;
    }
  }

  // bias + softmax (rows spread over the 32 tc lanes), fully scalarized
  float4 vgA = *(const float4*)&vgs[bg * 256 + tc * 4];
  float4 vgB = *(const float4*)&vgs[bg * 256 + 128 + tc * 4];
  float* aoutb = aout + (size_t)str * 4194304 + (size_t)(bg & 15) * 262144;
  SOFTMAX_ROW(0, accA0, accB0)
  SOFTMAX_ROW(1, accA1, accB1)
  SOFTMAX_ROW(2, accA2, accB2)
  SOFTMAX_ROW(3, accA3, accB3)

  // PV: thread (rg = t>>4 -> rows rg*2..+1, dg = t&15 -> d dg*4..+3)
  int rg = t >> 4, dg = t & 15;
  float4 acc0 = {0,0,0,0}, acc1 = {0,0,0,0};
  for (int ch = 0; ch < 4; ++ch) {
    __syncthreads();
#pragma unroll
    for (int it = 0; it < 2; ++it) {
      int e = t * 8 + it * 2048;
      int j = e >> 6, d = e & 63;
      *(float4*)&stg[e] =
          *(const float4*)(v_g + ((size_t)bg * 256 + ch * 64 + j) * 64 + d);
    }
    __syncthreads();
#pragma unroll 4
    for (int jq = 0; jq < 16; ++jq) {
      int jl = jq * 4;
      int jg = ch * 64 + jl;
      uint2 p0 = *(const uint2*)&P[(rg * 2 + 0) * 260 + jg];
      uint2 p1 = *(const uint2*)&P[(rg * 2 + 1) * 260 + jg];
      float p00 = bf_lo(p0.x), p01 = bf_hi(p0.x), p02 = bf_lo(p0.y), p03 = bf_hi(p0.y);
      float p10 = bf_lo(p1.x), p11 = bf_hi(p1.x), p12 = bf_lo(p1.y), p13 = bf_hi(p1.y);
      uint2 u0 = *(const uint2*)&stg[(jl + 0) * 64 + dg * 4];
      uint2 u1 = *(const uint2*)&stg[(jl + 1) * 64 + dg * 4];
      uint2 u2 = *(const uint2*)&stg[(jl + 2) * 64 + dg * 4];
      uint2 u3 = *(const uint2*)&stg[(jl + 3) * 64 + dg * 4];
      float4 v0 = {bf_lo(u0.x), bf_hi(u0.x), bf_lo(u0.y), bf_hi(u0.y)};
      float4 v1 = {bf_lo(u1.x), bf_hi(u1.x), bf_lo(u1.y), bf_hi(u1.y)};
      float4 v2 = {bf_lo(u2.x), bf_hi(u2.x), bf_lo(u2.y), bf_hi(u2.y)};
      float4 v3 = {bf_lo(u3.x), bf_hi(u3.x), bf_lo(u3.y), bf_hi(u3.y)};
      acc0.x += p00 * v0.x + p01 * v1.x + p02 * v2.x + p03 * v3.x;
      acc0.y += p00 * v0.y + p01 * v1.y + p02 * v2.y + p03 * v3.y;
      acc0.z += p00 * v0.z + p01 * v1.z + p02 * v2.z + p03 * v3.z;
      acc0.w += p00 * v0.w + p01 * v1.w + p02 * v2.w + p03 * v3.w;
      acc1.x += p10 * v0.x + p11 * v1.x + p12 * v2.x + p13 * v3.x;
      acc1.y += p10 * v0.y + p11 * v1.y + p12 * v2.y + p13 * v3.y;
      acc1.z += p10 * v0.z + p11 * v1.z + p12 * v2.z + p13 * v3.z;
      acc1.w += p10 * v0.w + p11 * v1.w + p12 * v2.w + p13 * v3.w;
    }
  }
  *(float4*)&attout[((size_t)bg * 1024 + i0 + rg * 2 + 0) * 64 + dg * 4] = acc0;
  *(float4*)&attout[((size_t)bg * 1024 + i0 + rg * 2 + 1) * 64 + dg * 4] = acc1;
}

// ---------------- oproj (both streams) + residual + fuse ----------------
__global__ void k_oproj_fuse(const float* __restrict__ ao, const float* __restrict__ owT1,
                             const float* __restrict__ owT2, const float* __restrict__ ob,
                             const float* __restrict__ x1_0, const float* __restrict__ x1_1,
                             const float* __restrict__ fwT, const float* __restrict__ fb,
                             float* __restrict__ fused) {
  int tok0 = blockIdx.x * 8;
  int t = threadIdx.x;
  int o = t & 127, th = t >> 7;
  __shared__ float s[8 * 512];
  __shared__ float xoL[2][8 * 128];
  for (int strm = 0; strm < 2; ++strm) {
    __syncthreads();
#pragma unroll
    for (int k = 0; k < 16; ++k) {
      int fi = t + k * 256;
      int tok = fi >> 9, c = fi & 511;
      int tg = tok0 + tok;
      int b = tg >> 10, n = tg & 1023;
      s[fi] = ao[((size_t)(strm * 16 + b * 8 + (c >> 6)) * 1024 + n) * 64 + (c & 63)];
    }
    __syncthreads();
    const float* owT = strm ? owT2 : owT1;
    const float* x1 = strm ? x1_1 : x1_0;
    float acc0 = 0.f, acc1 = 0.f, acc2 = 0.f, acc3 = 0.f;
    for (int c = 0; c < 512; c += 4) {
      float wa = owT[(c + 0) * kC + o];
      float wb = owT[(c + 1) * kC + o];
      float wc = owT[(c + 2) * kC + o];
      float wd = owT[(c + 3) * kC + o];
      const float4 sa = *(const float4*)&s[(th + 0) * 512 + c];
      const float4 sb = *(const float4*)&s[(th + 2) * 512 + c];
      const float4 sc4 = *(const float4*)&s[(th + 4) * 512 + c];
      const float4 sd = *(const float4*)&s[(th + 6) * 512 + c];
      acc0 += sa.x * wa + sa.y * wb + sa.z * wc + sa.w * wd;
      acc1 += sb.x * wa + sb.y * wb + sb.z * wc + sb.w * wd;
      acc2 += sc4.x * wa + sc4.y * wb + sc4.z * wc + sc4.w * wd;
      acc3 += sd.x * wa + sd.y * wb + sd.z * wc + sd.w * wd;
    }
    float bias = ob[strm * 128 + o];
    float accs[4] = {acc0, acc1, acc2, acc3};
#pragma unroll
    for (int k = 0; k < 4; ++k) {
      int tok = th + k * 2;
      int tg = tok0 + tok;
      xoL[strm][tok * 128 + o] = x1[(size_t)tg * kC + o] + accs[k] + bias;
    }
  }
  __syncthreads();
  float fa0 = 0.f, fa1 = 0.f, fa2 = 0.f, fa3 = 0.f;
  for (int c = 0; c < 128; ++c) {
    float w0 = fwT[c * kC + o];
    float w1 = fwT[(128 + c) * kC + o];
    fa0 += xoL[0][(th + 0) * 128 + c] * w0 + xoL[1][(th + 0) * 128 + c] * w1;
    fa1 += xoL[0][(th + 2) * 128 + c] * w0 + xoL[1][(th + 2) * 128 + c] * w1;
    fa2 += xoL[0][(th + 4) * 128 + c] * w0 + xoL[1][(th + 4) * 128 + c] * w1;
    fa3 += xoL[0][(th + 6) * 128 + c] * w0 + xoL[1][(th + 6) * 128 + c] * w1;
  }
  float bias = fb[o];
  fused[(size_t)(tok0 + th + 0) * kC + o] = fa0 + bias;
  fused[(size_t)(tok0 + th + 2) * kC + o] = fa1 + bias;
  fused[(size_t)(tok0 + th + 4) * kC + o] = fa2 + bias;
  fused[(size_t)(tok0 + th + 6) * kC + o] = fa3 + bias;
}

// ---------------- double-LN + mout, wave per token, chunk partials ----------------
__global__ void k_meanz(const float* __restrict__ fused, const float* __restrict__ ng,
                        const float* __restrict__ nb, const float* __restrict__ tfng,
                        const float* __restrict__ tfnb, const float* __restrict__ mout,
                        float* __restrict__ partial) {
  int chunk = blockIdx.x, b = blockIdx.y, i = blockIdx.z;
  int w = threadIdx.x >> 6, lane = threadIdx.x & 63;
  int c = lane, c2 = lane + 64;
  float moa = mout[(i * 2 + b) * kC + c], mob = mout[(i * 2 + b) * kC + c2];
  float g1a = ng[c], b1a = nb[c], g1b = ng[c2], b1b = nb[c2];
  float g2a = tfng[i * kC + c], b2a = tfnb[i * kC + c];
  float g2b = tfng[i * kC + c2], b2b = tfnb[i * kC + c2];
  float acca = 0.f, accb = 0.f;
#pragma unroll
  for (int it = 0; it < 4; ++it) {
    int tok = chunk * 16 + it * 4 + w;
    const float* xr = fused + ((size_t)(b * kN + tok)) * kC;
    float xa = xr[c], xb = xr[c2];
    float m1 = wave_sum(xa + xb) * (1.f / kC);
    float da = xa - m1, db = xb - m1;
    float v1 = wave_sum(da * da + db * db) * (1.f / kC);
    float r1 = rsqrtf(v1 + 1e-5f);
    float za = da * r1 * g1a + b1a + moa;
    float zb = db * r1 * g1b + b1b + mob;
    float m2 = wave_sum(za + zb) * (1.f / kC);
    float ea = za - m2, eb = zb - m2;
    float v2 = wave_sum(ea * ea + eb * eb) * (1.f / kC);
    float r2 = rsqrtf(v2 + 1e-5f);
    acca += ea * r2 * g2a + b2a;
    accb += eb * r2 * g2b + b2b;
  }
  __shared__ float red[4][128];
  red[w][c] = acca; red[w][c2] = accb;
  __syncthreads();
  if (w == 0) {
    float pa = red[0][c] + red[1][c] + red[2][c] + red[3][c];
    float pb = red[0][c2] + red[1][c2] + red[2][c2] + red[3][c2];
    float* pr = partial + ((size_t)(i * 2 + b) * 64 + chunk) * kC;
    pr[c] = pa; pr[c2] = pb;
  }
}

__global__ void k_final(const float* __restrict__ partial, const float* __restrict__ pw,
                        const float* __restrict__ pb, float* __restrict__ out) {
  int ib = blockIdx.x;
  int i = ib >> 1, t = threadIdx.x;
  int c = t & 127, half = t >> 7;
  float a = 0.f;
  for (int ch = half * 32; ch < half * 32 + 32; ++ch)
    a += partial[((size_t)ib * 64 + ch) * kC + c];
  __shared__ float s[256];
  s[half * 128 + c] = a;
  __syncthreads();
  if (t < 128) s[t] = (s[t] + s[128 + t]) * (1.f / (float)kN);
  __syncthreads();
  if (t < 128) {
    float a0 = 0.f;
    const float* wr = pw + (size_t)i * kC * kC + (size_t)t * kC;
    for (int cc = 0; cc < 128; ++cc) a0 += s[cc] * wr[cc];
    out[ib * 128 + t] = tanhf(pb[i * kC + t] + a0);
  }
}

extern "C" void kernel_launch(void* const* d_in, const int* in_sizes, int n_in,
                              void* d_out, int out_size, void* d_ws, size_t ws_size,
                              hipStream_t stream) {
  const float* x1_0   = (const float*)d_in[0];
  const float* x1_1   = (const float*)d_in[1];
  const float* x2     = (const float*)d_in[2];
  const float* norm_g = (const float*)d_in[3];
  const float* norm_b = (const float*)d_in[4];
  const float* d_qw   = (const float*)d_in[5];
  const float* d_kw   = (const float*)d_in[6];
  const float* d_vw   = (const float*)d_in[7];
  const float* d_ow   = (const float*)d_in[8];
  const float* d_ob   = (const float*)d_in[9];
  const float* d_o1w  = (const float*)d_in[10];
  const float* d_o1b  = (const float*)d_in[11];
  const float* d_o2w  = (const float*)d_in[12];
  const float* c_w1   = (const float*)d_in[13];
  const float* c_b1   = (const float*)d_in[14];
  const float* c_w2   = (const float*)d_in[15];
  const float* c_b2   = (const float*)d_in[16];
  const float* c_w3   = (const float*)d_in[17];
  const float* c_b3   = (const float*)d_in[18];
  const float* fus_w  = (const float*)d_in[19];
  const float* fus_b  = (const float*)d_in[20];
  const float* tf_ng  = (const float*)d_in[21];
  const float* tf_nb  = (const float*)d_in[22];
  const float* tf_inw = (const float*)d_in[23];
  const float* tf_inb = (const float*)d_in[24];
  const float* tf_ow  = (const float*)d_in[25];
  const float* tf_ob  = (const float*)d_in[26];
  const float* tf_pw  = (const float*)d_in[27];
  const float* tf_pb  = (const float*)d_in[28];

  float* ws = (float*)d_ws;
  float* out = (float*)d_out;
  float* lnkv = ws + W_LNKV;
  float* lnq1 = ws + W_LNQ1; float* lnq2 = ws + W_LNQ2;
  __hip_bfloat16* qtb = (__hip_bfloat16*)(ws + W_QT);
  __hip_bfloat16* ktb = (__hip_bfloat16*)(ws + W_KT);
  __hip_bfloat16* vb  = (__hip_bfloat16*)(ws + W_V);
  float* vgsw = ws + W_VGS;
  float* ao = ws + W_AO;
  float* fused = ws + W_FUS; float* tab = ws + W_TAB;
  float* moutp = ws + W_MOUT; float* partp = ws + W_PART;
  float* owT1 = ws + W_OWT1; float* owT2 = ws + W_OWT2;
  float* fwT = ws + W_FWT;

  // output: f1(256) | f2(256) | a1(2*8*1024*256) | a2(same), all f32
  float* aoutb = out + 512;

  k_prep<<<1830, 256, 0, stream>>>(d_ow, fus_w, owT1, owT2, fwT,
                                   x1_0, x1_1, x2, lnq1, lnq2, lnkv, norm_g, norm_b,
                                   c_w1, c_b1, c_w2, c_b2, c_w3, c_b3, tab,
                                   tf_ng, tf_nb, tf_inw, tf_inb, tf_ow, tf_ob, moutp);
  k_qoff<<<2560, 256, 0, stream>>>(lnq1, lnq2, d_qw, d_o1w, d_o1b, d_o2w, qtb, vgsw);
  k_sample_kv<<<2048, 256, 0, stream>>>(lnkv, vgsw, d_kw, d_vw, ktb, vb);
  k_attn<<<1024, 256, 0, stream>>>(qtb, ktb, vb, vgsw, tab, aoutb, ao);
  k_oproj_fuse<<<256, 256, 0, stream>>>(ao, owT1, owT2, d_ob, x1_0, x1_1, fwT,
                                        fus_b, fused);
  k_meanz<<<dim3(64, 2, 2), 256, 0, stream>>>(fused, norm_g, norm_b, tf_ng, tf_nb,
                                              moutp, partp);
  k_final<<<4, 256, 0, stream>>>(partp, tf_pw, tf_pb, out);

  (void)in_sizes; (void)n_in; (void)out_size; (void)ws_size;
}

// Round 10
// 119.660 us; speedup vs baseline: 2.3413x; 1.2849x over previous
//
#include <hip/hip_runtime.h>
#include <hip/hip_bf16.h>

// UniTeacherEncoder v10: MFMA attention (mfma_f32_16x16x32_bf16).
// Operand staging: Q row-major [r][d], K row-major [j][d], V transposed [d][j]
// so every MFMA fragment is one contiguous 16B ds_read_b128.
// C/D layout (HW-verified m89/m91): col=lane&15, row=(lane>>4)*4+reg.
// A: row=lane&15, k=(lane>>4)*8+i.  B: col=lane&15, k=(lane>>4)*8+i.
// k_attn keeps __launch_bounds__(256,2) — the only spill-free allocator config
// measured on this compiler (v5..v9 evidence).

namespace {

constexpr int kN  = 1024;
constexpr int kC  = 128;
constexpr int kG  = 8;
constexpr int kDH = 64;
constexpr int kND = 256;

constexpr int   kNT    = 16384;
constexpr float kRLO   = -2.0625f;   // rel in [-2.032, 2.032] guaranteed (|off|<=4)
constexpr float kRSPAN = 4.125f;

// workspace layout (float offsets)
constexpr size_t W_LNKV = 0;          // 2048 x 128 f32
constexpr size_t W_LNQ1 = 262144;
constexpr size_t W_LNQ2 = 524288;
constexpr size_t W_Q    = 786432;     // bf16 [32 bg][1024 r][64 d] row-major
constexpr size_t W_K    = 1835008;    // bf16 [32 bg][256 j][64 d] row-major
constexpr size_t W_VT   = 2097152;    // bf16 [32 bg][64 d][256 j] (transposed V)
constexpr size_t W_VGS  = 2359296;    // f32 [32][256]
constexpr size_t W_AO   = 2367488;    // f32 [32 bg][1024][64]
constexpr size_t W_FUS  = 4988928;    // f32 2048 x 128
constexpr size_t W_TAB  = 5251072;    // f32 2 x 16385
constexpr size_t W_MOUT = 5283844;    // 4 x 128
constexpr size_t W_PART = 5284356;    // 4 x 64 x 128
constexpr size_t W_OWT1 = 5317124;    // 512 x 128
constexpr size_t W_OWT2 = 5382660;
constexpr size_t W_FWT  = 5448196;    // 256 x 128

} // namespace

typedef __attribute__((ext_vector_type(8))) short short8;
typedef __attribute__((ext_vector_type(4))) float floatx4;

__device__ __forceinline__ float wave_sum(float v) {
#pragma unroll
  for (int o = 32; o > 0; o >>= 1) v += __shfl_xor(v, o, 64);
  return v;
}
__device__ __forceinline__ float cpb_bias(const float* __restrict__ tabs,
                                          float seq, float vg) {
  float rel = seq - vg;
  float ft = (rel - kRLO) * ((float)kNT / kRSPAN);
  ft = fminf(fmaxf(ft, 0.f), 16383.999f);
  int ix = (int)ft;
  float fw = ft - (float)ix;
  return tabs[ix] * (1.f - fw) + tabs[ix + 1] * fw;
}

// ---------------- k_prep: transposes + LN x3 + CPB table + mout ----------------
__global__ void k_prep(const float* __restrict__ ow, const float* __restrict__ fw,
                       float* __restrict__ owT1, float* __restrict__ owT2,
                       float* __restrict__ fwT,
                       const float* __restrict__ x1_0, const float* __restrict__ x1_1,
                       const float* __restrict__ x2, float* __restrict__ lnq1,
                       float* __restrict__ lnq2, float* __restrict__ lnkv,
                       const float* __restrict__ ng, const float* __restrict__ nb,
                       const float* __restrict__ cw1, const float* __restrict__ cb1,
                       const float* __restrict__ cw2, const float* __restrict__ cb2,
                       const float* __restrict__ cw3, const float* __restrict__ cb3,
                       float* __restrict__ tab,
                       const float* __restrict__ tfng, const float* __restrict__ tfnb,
                       const float* __restrict__ inw, const float* __restrict__ inb,
                       const float* __restrict__ tow, const float* __restrict__ tob,
                       float* __restrict__ mout) {
  int bx = blockIdx.x;
  int t = threadIdx.x;
  if (bx < 160) {
    const float* src; float* dst; int R, C, tile;
    if (bx < 64)       { src = ow;          dst = owT1; R = 128; C = 512; tile = bx; }
    else if (bx < 128) { src = ow + 65536;  dst = owT2; R = 128; C = 512; tile = bx - 64; }
    else               { src = fw;          dst = fwT;  R = 128; C = 256; tile = bx - 128; }
    int tpr = C >> 5;
    int ti = tile / tpr, tj = tile - ti * tpr;
    __shared__ float tl[32][33];
    int x = t & 31, ys = t >> 5;
#pragma unroll
    for (int p = 0; p < 4; ++p) {
      int y = ys + p * 8;
      tl[y][x] = src[(size_t)(ti * 32 + y) * C + tj * 32 + x];
    }
    __syncthreads();
#pragma unroll
    for (int p = 0; p < 4; ++p) {
      int y = ys + p * 8;
      dst[(size_t)(tj * 32 + y) * R + ti * 32 + x] = tl[x][y];
    }
  } else if (bx < 1696) {
    int w = t >> 6, lane = t & 63;
    int gr = (bx - 160) * 4 + w;
    int sel = gr >> 11, row = gr & 2047;
    const float* in = (sel == 0) ? x1_0 : (sel == 1) ? x1_1 : x2;
    float* out = (sel == 0) ? lnq1 : (sel == 1) ? lnq2 : lnkv;
    const float* xr = in + (size_t)row * kC;
    float xa = xr[lane], xb = xr[lane + 64];
    float m = wave_sum(xa + xb) * (1.f / kC);
    float da = xa - m, db = xb - m;
    float v = wave_sum(da * da + db * db) * (1.f / kC);
    float r = rsqrtf(v + 1e-5f);
    float* orow = out + (size_t)row * kC;
    orow[lane]      = da * r * ng[lane] + nb[lane];
    orow[lane + 64] = db * r * ng[lane + 64] + nb[lane + 64];
  } else if (bx < 1826) {
    int rel = bx - 1696;
    int idx = rel / 65, bb = rel - idx * 65;
    int tt = bb * 256 + t;
    if (tt <= kNT) {
      float rel_ = kRLO + (kRSPAN / (float)kNT) * (float)tt;
      float u = (rel_ >= 0.f ? 1.f : -1.f) * log1pf(fabsf(rel_));
      const float* W1 = cw1 + idx * 32; const float* B1 = cb1 + idx * 32;
      const float* W2 = cw2 + idx * 1024; const float* B2 = cb2 + idx * 32;
      const float* W3 = cw3 + idx * 32; const float* B3 = cb3 + idx;
      float h1[32];
#pragma unroll
      for (int m = 0; m < 32; ++m) h1[m] = fmaxf(0.f, u * W1[m] + B1[m]);
      float o = B3[0];
      for (int m = 0; m < 32; ++m) {
        float a = B2[m];
#pragma unroll
        for (int k = 0; k < 32; ++k) a += h1[k] * W2[k * 32 + m];
        o += fmaxf(a, 0.f) * W3[m];
      }
      tab[(size_t)idx * (kNT + 1) + tt] = o;
    }
  } else {
    int rel = bx - 1826;
    int i = rel >> 1, b = rel & 1;
    bool act = t < 128;
    __shared__ float red[2];
    __shared__ float s1[128];
    __shared__ float s2[128];
    const float* xs = (i ? x1_1 : x1_0) + (size_t)b * kN * kC;
    float x = act ? xs[t] : 0.f;
    float s = wave_sum(x);
    if (act && (t & 63) == 0) red[t >> 6] = s;
    __syncthreads();
    float m1 = (red[0] + red[1]) * (1.f / kC);
    __syncthreads();
    float d1 = x - m1;
    float ss = wave_sum(act ? d1 * d1 : 0.f);
    if (act && (t & 63) == 0) red[t >> 6] = ss;
    __syncthreads();
    float v1 = (red[0] + red[1]) * (1.f / kC);
    __syncthreads();
    float t0 = act ? d1 * rsqrtf(v1 + 1e-5f) * ng[t] + nb[t] : 0.f;
    s = wave_sum(t0);
    if (act && (t & 63) == 0) red[t >> 6] = s;
    __syncthreads();
    float m2 = (red[0] + red[1]) * (1.f / kC);
    __syncthreads();
    float d2 = t0 - m2;
    ss = wave_sum(act ? d2 * d2 : 0.f);
    if (act && (t & 63) == 0) red[t >> 6] = ss;
    __syncthreads();
    float v2 = (red[0] + red[1]) * (1.f / kC);
    if (act) s1[t] = d2 * rsqrtf(v2 + 1e-5f) * tfng[i * kC + t] + tfnb[i * kC + t];
    __syncthreads();
    if (act) {
      float a0 = 0.f;
      const float* wr = inw + (size_t)i * 384 * kC + (size_t)(256 + t) * kC;
      for (int c = 0; c < 128; ++c) a0 += s1[c] * wr[c];
      s2[t] = inb[i * 384 + 256 + t] + a0;
    }
    __syncthreads();
    if (act) {
      float a0 = 0.f;
      const float* wr2 = tow + (size_t)i * kC * kC + (size_t)t * kC;
      for (int c = 0; c < 128; ++c) a0 += s2[c] * wr2[c];
      mout[rel * kC + t] = tob[i * kC + t] + a0;
    }
  }
}

// ---------------- k_qoff: qproj ([0,512)) + offsets ([512,2560)) ----------------
// qproj writes Q ROW-major bf16 [bg][r][d] (16 consecutive bf16 per thread).
__global__ void k_qoff(const float* __restrict__ lnq1, const float* __restrict__ lnq2,
                       const float* __restrict__ qw, const float* __restrict__ o1w,
                       const float* __restrict__ o1b, const float* __restrict__ o2w,
                       __hip_bfloat16* __restrict__ qout, float* __restrict__ vgs) {
  int bx = blockIdx.x;
  if (bx < 512) {
    int bg = bx >> 4, r0 = (bx & 15) * 64;
    int str = bg >> 4, b = (bg >> 3) & 1, g = bg & 7;
    int rl = threadIdx.x & 63, dq = threadIdx.x >> 6;
    const float* lnq = str ? lnq2 : lnq1;
    const float* xr = lnq + ((size_t)(b * kN + r0 + rl)) * kC + g * 16;
    float4 x0 = *(const float4*)(xr + 0);
    float4 x1 = *(const float4*)(xr + 4);
    float4 x2 = *(const float4*)(xr + 8);
    float4 x3 = *(const float4*)(xr + 12);
    const float* wqb = qw + (size_t)str * 8192 + (size_t)g * 1024;
    __hip_bfloat16* qrow = qout + ((size_t)bg * 1024 + r0 + rl) * 64 + dq * 16;
#pragma unroll 4
    for (int dd = 0; dd < 16; ++dd) {
      int d = dq * 16 + dd;
      const float* wq = wqb + d * 16;
      float4 w0 = *(const float4*)(wq + 0);
      float4 w1 = *(const float4*)(wq + 4);
      float4 w2 = *(const float4*)(wq + 8);
      float4 w3 = *(const float4*)(wq + 12);
      float q = x0.x * w0.x + x0.y * w0.y + x0.z * w0.z + x0.w * w0.w
              + x1.x * w1.x + x1.y * w1.y + x1.z * w1.z + x1.w * w1.w
              + x2.x * w2.x + x2.y * w2.y + x2.z * w2.z + x2.w * w2.w
              + x3.x * w3.x + x3.y * w3.y + x3.z * w3.z + x3.w * w3.w;
      qrow[dd] = __float2bfloat16(q);
    }
  } else {
    int bxo = bx - 512;
    int w = threadIdx.x >> 6, lane = threadIdx.x & 63;
    int bg = bxo >> 6, j = ((bxo & 63) << 2) + w;
    int str = bg >> 4, b = (bg >> 3) & 1, g = bg & 7;
    const float* lnq = str ? lnq2 : lnq1;
    __shared__ float xr[4][96];
    int base = j * 4 - 1;
#pragma unroll
    for (int rep = 0; rep < 2; ++rep) {
      int idx = lane + rep * 64;
      if (idx < 96) {
        int r = idx >> 4, c = idx & 15, n = base + r;
        xr[w][idx] = (n >= 0 && n < kN)
                         ? lnq[((size_t)(b * kN + n)) * kC + g * 16 + c] : 0.f;
      }
    }
    const float* wq = qw + (size_t)str * 8192 + (size_t)(g * kDH + lane) * 16;
    float acc = o1b[str * 64 + lane];
#pragma unroll
    for (int k2 = 0; k2 < 6; ++k2) {
      float qv = 0.f;
#pragma unroll
      for (int c = 0; c < 16; ++c) qv += xr[w][k2 * 16 + c] * wq[c];
      acc += qv * o1w[str * 384 + lane * 6 + k2];
    }
    float ge = 0.5f * acc * (1.f + erff(acc * 0.70710678118654752440f));
    float s = wave_sum(ge * o2w[str * 64 + lane]);
    if (lane == 0)
      vgs[bg * kND + j] = 2.f * ((float)j + tanhf(s) * 4.0f) / 255.f - 1.f;
  }
}

// ---------------- grid_sample + k/v projections ----------------
// K row-major [bg][j][d]; V transposed [bg][d][j].
__global__ void k_sample_kv(const float* __restrict__ lnkv, const float* __restrict__ vgs,
                            const float* __restrict__ kw, const float* __restrict__ vw,
                            __hip_bfloat16* __restrict__ kout,
                            __hip_bfloat16* __restrict__ vtout) {
  int w = threadIdx.x >> 6, lane = threadIdx.x & 63;
  int bg = blockIdx.x >> 6, j = ((blockIdx.x & 63) << 2) + w;
  int str = bg >> 4, b = (bg >> 3) & 1, g = bg & 7;
  __shared__ float sc[4][16];
  if (lane < 16) {
    float gr = vgs[bg * kND + j];
    float x = ((gr + 1.f) * 1024.f - 1.f) * 0.5f;
    float x0f = floorf(x);
    float w1 = x - x0f;
    int x0 = (int)x0f, x1 = x0 + 1;
    const float* src = lnkv + (size_t)b * kN * kC + g * 16 + lane;
    float v0 = (x0 >= 0 && x0 < 1024) ? src[(size_t)x0 * kC] : 0.f;
    float v1 = (x1 >= 0 && x1 < 1024) ? src[(size_t)x1 * kC] : 0.f;
    sc[w][lane] = v0 * (1.f - w1) + v1 * w1;
  }
  const float* kwr = kw + (size_t)str * 8192 + (size_t)(g * kDH + lane) * 16;
  const float* vwr = vw + (size_t)str * 8192 + (size_t)(g * kDH + lane) * 16;
  float ka = 0.f, va = 0.f;
#pragma unroll
  for (int c = 0; c < 16; ++c) { ka += sc[w][c] * kwr[c]; va += sc[w][c] * vwr[c]; }
  kout[((size_t)bg * 256 + j) * 64 + lane] = __float2bfloat16(ka);      // K[j][d]
  vtout[((size_t)bg * 64 + lane) * 256 + j] = __float2bfloat16(va);     // Vt[d][j]
}

// ---------------- MFMA flash attention: block = (bg, 64-row tile) ----------------
__global__ void __launch_bounds__(256, 2)
k_attn(const __hip_bfloat16* __restrict__ q_g, const __hip_bfloat16* __restrict__ k_g,
       const __hip_bfloat16* __restrict__ vt_g, const float* __restrict__ vgs,
       const float* __restrict__ tab, float* __restrict__ aout,
       float* __restrict__ attout) {
  int bg = blockIdx.x >> 4, tile = blockIdx.x & 15;
  int str = bg >> 4;
  int i0 = tile * 64;
  int t = threadIdx.x;
  int w = t >> 6, l = t & 63;
  int lr = l & 15, lg = l >> 4;   // fragment lane-row/col and k-group

  __shared__ __align__(16) __hip_bfloat16 Qs[64 * 72];    // Q tile [r][72]
  __shared__ __align__(16) __hip_bfloat16 Ss[64 * 72];    // K / Vt chunk staging
  __shared__ __align__(16) __hip_bfloat16 Ps[64 * 272];   // P tile [r][272]

  const float* tabs = tab + str * (kNT + 1);

  // stage Q tile (wave-local rows: wave w stages rows it later reads)
  {
    int r = t >> 2, c0 = (t & 3) * 16;
    const __hip_bfloat16* src = q_g + ((size_t)bg * 1024 + i0 + r) * 64 + c0;
    *(float4*)&Qs[r * 72 + c0]     = *(const float4*)src;
    *(float4*)&Qs[r * 72 + c0 + 8] = *(const float4*)(src + 8);
  }
  short8 a0 = *(const short8*)&Qs[(w * 16 + lr) * 72 + lg * 8];
  short8 a1 = *(const short8*)&Qs[(w * 16 + lr) * 72 + 32 + lg * 8];

  floatx4 acc[16];
#pragma unroll
  for (int f = 0; f < 16; ++f) acc[f] = {0.f, 0.f, 0.f, 0.f};

  // ---- QK^T over 4 j-chunks of 64 ----
#pragma unroll
  for (int jc = 0; jc < 4; ++jc) {
    __syncthreads();
    {
      int r = t >> 2, c0 = (t & 3) * 16;
      const __hip_bfloat16* src = k_g + ((size_t)bg * 256 + jc * 64 + r) * 64 + c0;
      *(float4*)&Ss[r * 72 + c0]     = *(const float4*)src;
      *(float4*)&Ss[r * 72 + c0 + 8] = *(const float4*)(src + 8);
    }
    __syncthreads();
#pragma unroll
    for (int ct = 0; ct < 4; ++ct) {
      short8 b0 = *(const short8*)&Ss[(ct * 16 + lr) * 72 + lg * 8];
      short8 b1 = *(const short8*)&Ss[(ct * 16 + lr) * 72 + 32 + lg * 8];
      acc[jc * 4 + ct] =
          __builtin_amdgcn_mfma_f32_16x16x32_bf16(a0, b0, acc[jc * 4 + ct], 0, 0, 0);
      acc[jc * 4 + ct] =
          __builtin_amdgcn_mfma_f32_16x16x32_bf16(a1, b1, acc[jc * 4 + ct], 0, 0, 0);
    }
  }

  // ---- bias + softmax; write attn f32 + P bf16 ----
  float vgl[16];
#pragma unroll
  for (int f = 0; f < 16; ++f) vgl[f] = vgs[bg * 256 + f * 16 + lr];
  float* aoutb = aout + (size_t)str * 4194304 + (size_t)(bg & 15) * 262144;
#pragma unroll
  for (int reg = 0; reg < 4; ++reg) {
    int row = w * 16 + lg * 4 + reg;
    int i = i0 + row;
    float seq = 2.f * (float)i / 1023.f - 1.f;
    float sv[16];
#pragma unroll
    for (int f = 0; f < 16; ++f)
      sv[f] = acc[f][reg] * 0.125f + cpb_bias(tabs, seq, vgl[f]);
    float m = sv[0];
#pragma unroll
    for (int f = 1; f < 16; ++f) m = fmaxf(m, sv[f]);
    m = fmaxf(m, __shfl_xor(m, 1, 64));
    m = fmaxf(m, __shfl_xor(m, 2, 64));
    m = fmaxf(m, __shfl_xor(m, 4, 64));
    m = fmaxf(m, __shfl_xor(m, 8, 64));
    float ev[16], sum = 0.f;
#pragma unroll
    for (int f = 0; f < 16; ++f) { ev[f] = expf(sv[f] - m); sum += ev[f]; }
    sum += __shfl_xor(sum, 1, 64);
    sum += __shfl_xor(sum, 2, 64);
    sum += __shfl_xor(sum, 4, 64);
    sum += __shfl_xor(sum, 8, 64);
    float inv = 1.f / sum;
    float* arow = aoutb + (size_t)i * 256;
#pragma unroll
    for (int f = 0; f < 16; ++f) {
      float p = ev[f] * inv;
      arow[f * 16 + lr] = p;
      Ps[row * 272 + f * 16 + lr] = __float2bfloat16(p);
    }
  }

  // ---- PV over 4 j-chunks of 64 (P reads are wave-local; no extra barrier) ----
  floatx4 oacc[4];
#pragma unroll
  for (int dt = 0; dt < 4; ++dt) oacc[dt] = {0.f, 0.f, 0.f, 0.f};
#pragma unroll
  for (int jc = 0; jc < 4; ++jc) {
    __syncthreads();
    {
      int r = t >> 2, c0 = (t & 3) * 16;
      const __hip_bfloat16* src = vt_g + ((size_t)bg * 64 + r) * 256 + jc * 64 + c0;
      *(float4*)&Ss[r * 72 + c0]     = *(const float4*)src;
      *(float4*)&Ss[r * 72 + c0 + 8] = *(const float4*)(src + 8);
    }
    __syncthreads();
    short8 pa0 = *(const short8*)&Ps[(w * 16 + lr) * 272 + jc * 64 + lg * 8];
    short8 pa1 = *(const short8*)&Ps[(w * 16 + lr) * 272 + jc * 64 + 32 + lg * 8];
#pragma unroll
    for (int dt = 0; dt < 4; ++dt) {
      short8 b0 = *(const short8*)&Ss[(dt * 16 + lr) * 72 + lg * 8];
      short8 b1 = *(const short8*)&Ss[(dt * 16 + lr) * 72 + 32 + lg * 8];
      oacc[dt] = __builtin_amdgcn_mfma_f32_16x16x32_bf16(pa0, b0, oacc[dt], 0, 0, 0);
      oacc[dt] = __builtin_amdgcn_mfma_f32_16x16x32_bf16(pa1, b1, oacc[dt], 0, 0, 0);
    }
  }
#pragma unroll
  for (int dt = 0; dt < 4; ++dt)
#pragma unroll
    for (int reg = 0; reg < 4; ++reg) {
      int row = w * 16 + lg * 4 + reg;
      attout[((size_t)bg * 1024 + i0 + row) * 64 + dt * 16 + lr] = oacc[dt][reg];
    }
}

// ---------------- oproj (both streams) + residual + fuse ----------------
__global__ void k_oproj_fuse(const float* __restrict__ ao, const float* __restrict__ owT1,
                             const float* __restrict__ owT2, const float* __restrict__ ob,
                             const float* __restrict__ x1_0, const float* __restrict__ x1_1,
                             const float* __restrict__ fwT, const float* __restrict__ fb,
                             float* __restrict__ fused) {
  int tok0 = blockIdx.x * 8;
  int t = threadIdx.x;
  int o = t & 127, th = t >> 7;
  __shared__ float s[8 * 512];
  __shared__ float xoL[2][8 * 128];
  for (int strm = 0; strm < 2; ++strm) {
    __syncthreads();
#pragma unroll
    for (int k = 0; k < 16; ++k) {
      int fi = t + k * 256;
      int tok = fi >> 9, c = fi & 511;
      int tg = tok0 + tok;
      int b = tg >> 10, n = tg & 1023;
      s[fi] = ao[((size_t)(strm * 16 + b * 8 + (c >> 6)) * 1024 + n) * 64 + (c & 63)];
    }
    __syncthreads();
    const float* owT = strm ? owT2 : owT1;
    const float* x1 = strm ? x1_1 : x1_0;
    float acc0 = 0.f, acc1 = 0.f, acc2 = 0.f, acc3 = 0.f;
    for (int c = 0; c < 512; c += 4) {
      float wa = owT[(c + 0) * kC + o];
      float wb = owT[(c + 1) * kC + o];
      float wc = owT[(c + 2) * kC + o];
      float wd = owT[(c + 3) * kC + o];
      const float4 sa = *(const float4*)&s[(th + 0) * 512 + c];
      const float4 sb = *(const float4*)&s[(th + 2) * 512 + c];
      const float4 sc4 = *(const float4*)&s[(th + 4) * 512 + c];
      const float4 sd = *(const float4*)&s[(th + 6) * 512 + c];
      acc0 += sa.x * wa + sa.y * wb + sa.z * wc + sa.w * wd;
      acc1 += sb.x * wa + sb.y * wb + sb.z * wc + sb.w * wd;
      acc2 += sc4.x * wa + sc4.y * wb + sc4.z * wc + sc4.w * wd;
      acc3 += sd.x * wa + sd.y * wb + sd.z * wc + sd.w * wd;
    }
    float bias = ob[strm * 128 + o];
    float accs[4] = {acc0, acc1, acc2, acc3};
#pragma unroll
    for (int k = 0; k < 4; ++k) {
      int tok = th + k * 2;
      int tg = tok0 + tok;
      xoL[strm][tok * 128 + o] = x1[(size_t)tg * kC + o] + accs[k] + bias;
    }
  }
  __syncthreads();
  float fa0 = 0.f, fa1 = 0.f, fa2 = 0.f, fa3 = 0.f;
  for (int c = 0; c < 128; ++c) {
    float w0 = fwT[c * kC + o];
    float w1 = fwT[(128 + c) * kC + o];
    fa0 += xoL[0][(th + 0) * 128 + c] * w0 + xoL[1][(th + 0) * 128 + c] * w1;
    fa1 += xoL[0][(th + 2) * 128 + c] * w0 + xoL[1][(th + 2) * 128 + c] * w1;
    fa2 += xoL[0][(th + 4) * 128 + c] * w0 + xoL[1][(th + 4) * 128 + c] * w1;
    fa3 += xoL[0][(th + 6) * 128 + c] * w0 + xoL[1][(th + 6) * 128 + c] * w1;
  }
  float bias = fb[o];
  fused[(size_t)(tok0 + th + 0) * kC + o] = fa0 + bias;
  fused[(size_t)(tok0 + th + 2) * kC + o] = fa1 + bias;
  fused[(size_t)(tok0 + th + 4) * kC + o] = fa2 + bias;
  fused[(size_t)(tok0 + th + 6) * kC + o] = fa3 + bias;
}

// ---------------- double-LN + mout, wave per token, chunk partials ----------------
__global__ void k_meanz(const float* __restrict__ fused, const float* __restrict__ ng,
                        const float* __restrict__ nb, const float* __restrict__ tfng,
                        const float* __restrict__ tfnb, const float* __restrict__ mout,
                        float* __restrict__ partial) {
  int chunk = blockIdx.x, b = blockIdx.y, i = blockIdx.z;
  int w = threadIdx.x >> 6, lane = threadIdx.x & 63;
  int c = lane, c2 = lane + 64;
  float moa = mout[(i * 2 + b) * kC + c], mob = mout[(i * 2 + b) * kC + c2];
  float g1a = ng[c], b1a = nb[c], g1b = ng[c2], b1b = nb[c2];
  float g2a = tfng[i * kC + c], b2a = tfnb[i * kC + c];
  float g2b = tfng[i * kC + c2], b2b = tfnb[i * kC + c2];
  float acca = 0.f, accb = 0.f;
#pragma unroll
  for (int it = 0; it < 4; ++it) {
    int tok = chunk * 16 + it * 4 + w;
    const float* xr = fused + ((size_t)(b * kN + tok)) * kC;
    float xa = xr[c], xb = xr[c2];
    float m1 = wave_sum(xa + xb) * (1.f / kC);
    float da = xa - m1, db = xb - m1;
    float v1 = wave_sum(da * da + db * db) * (1.f / kC);
    float r1 = rsqrtf(v1 + 1e-5f);
    float za = da * r1 * g1a + b1a + moa;
    float zb = db * r1 * g1b + b1b + mob;
    float m2 = wave_sum(za + zb) * (1.f / kC);
    float ea = za - m2, eb = zb - m2;
    float v2 = wave_sum(ea * ea + eb * eb) * (1.f / kC);
    float r2 = rsqrtf(v2 + 1e-5f);
    acca += ea * r2 * g2a + b2a;
    accb += eb * r2 * g2b + b2b;
  }
  __shared__ float red[4][128];
  red[w][c] = acca; red[w][c2] = accb;
  __syncthreads();
  if (w == 0) {
    float pa = red[0][c] + red[1][c] + red[2][c] + red[3][c];
    float pb = red[0][c2] + red[1][c2] + red[2][c2] + red[3][c2];
    float* pr = partial + ((size_t)(i * 2 + b) * 64 + chunk) * kC;
    pr[c] = pa; pr[c2] = pb;
  }
}

__global__ void k_final(const float* __restrict__ partial, const float* __restrict__ pw,
                        const float* __restrict__ pb, float* __restrict__ out) {
  int ib = blockIdx.x;
  int i = ib >> 1, t = threadIdx.x;
  int c = t & 127, half = t >> 7;
  float a = 0.f;
  for (int ch = half * 32; ch < half * 32 + 32; ++ch)
    a += partial[((size_t)ib * 64 + ch) * kC + c];
  __shared__ float s[256];
  s[half * 128 + c] = a;
  __syncthreads();
  if (t < 128) s[t] = (s[t] + s[128 + t]) * (1.f / (float)kN);
  __syncthreads();
  if (t < 128) {
    float a0 = 0.f;
    const float* wr = pw + (size_t)i * kC * kC + (size_t)t * kC;
    for (int cc = 0; cc < 128; ++cc) a0 += s[cc] * wr[cc];
    out[ib * 128 + t] = tanhf(pb[i * kC + t] + a0);
  }
}

extern "C" void kernel_launch(void* const* d_in, const int* in_sizes, int n_in,
                              void* d_out, int out_size, void* d_ws, size_t ws_size,
                              hipStream_t stream) {
  const float* x1_0   = (const float*)d_in[0];
  const float* x1_1   = (const float*)d_in[1];
  const float* x2     = (const float*)d_in[2];
  const float* norm_g = (const float*)d_in[3];
  const float* norm_b = (const float*)d_in[4];
  const float* d_qw   = (const float*)d_in[5];
  const float* d_kw   = (const float*)d_in[6];
  const float* d_vw   = (const float*)d_in[7];
  const float* d_ow   = (const float*)d_in[8];
  const float* d_ob   = (const float*)d_in[9];
  const float* d_o1w  = (const float*)d_in[10];
  const float* d_o1b  = (const float*)d_in[11];
  const float* d_o2w  = (const float*)d_in[12];
  const float* c_w1   = (const float*)d_in[13];
  const float* c_b1   = (const float*)d_in[14];
  const float* c_w2   = (const float*)d_in[15];
  const float* c_b2   = (const float*)d_in[16];
  const float* c_w3   = (const float*)d_in[17];
  const float* c_b3   = (const float*)d_in[18];
  const float* fus_w  = (const float*)d_in[19];
  const float* fus_b  = (const float*)d_in[20];
  const float* tf_ng  = (const float*)d_in[21];
  const float* tf_nb  = (const float*)d_in[22];
  const float* tf_inw = (const float*)d_in[23];
  const float* tf_inb = (const float*)d_in[24];
  const float* tf_ow  = (const float*)d_in[25];
  const float* tf_ob  = (const float*)d_in[26];
  const float* tf_pw  = (const float*)d_in[27];
  const float* tf_pb  = (const float*)d_in[28];

  float* ws = (float*)d_ws;
  float* out = (float*)d_out;
  float* lnkv = ws + W_LNKV;
  float* lnq1 = ws + W_LNQ1; float* lnq2 = ws + W_LNQ2;
  __hip_bfloat16* qb  = (__hip_bfloat16*)(ws + W_Q);
  __hip_bfloat16* kb  = (__hip_bfloat16*)(ws + W_K);
  __hip_bfloat16* vtb = (__hip_bfloat16*)(ws + W_VT);
  float* vgsw = ws + W_VGS;
  float* ao = ws + W_AO;
  float* fused = ws + W_FUS; float* tab = ws + W_TAB;
  float* moutp = ws + W_MOUT; float* partp = ws + W_PART;
  float* owT1 = ws + W_OWT1; float* owT2 = ws + W_OWT2;
  float* fwT = ws + W_FWT;

  // output: f1(256) | f2(256) | a1(2*8*1024*256) | a2(same), all f32
  float* aoutb = out + 512;

  k_prep<<<1830, 256, 0, stream>>>(d_ow, fus_w, owT1, owT2, fwT,
                                   x1_0, x1_1, x2, lnq1, lnq2, lnkv, norm_g, norm_b,
                                   c_w1, c_b1, c_w2, c_b2, c_w3, c_b3, tab,
                                   tf_ng, tf_nb, tf_inw, tf_inb, tf_ow, tf_ob, moutp);
  k_qoff<<<2560, 256, 0, stream>>>(lnq1, lnq2, d_qw, d_o1w, d_o1b, d_o2w, qb, vgsw);
  k_sample_kv<<<2048, 256, 0, stream>>>(lnkv, vgsw, d_kw, d_vw, kb, vtb);
  k_attn<<<512, 256, 0, stream>>>(qb, kb, vtb, vgsw, tab, aoutb, ao);
  k_oproj_fuse<<<256, 256, 0, stream>>>(ao, owT1, owT2, d_ob, x1_0, x1_1, fwT,
                                        fus_b, fused);
  k_meanz<<<dim3(64, 2, 2), 256, 0, stream>>>(fused, norm_g, norm_b, tf_ng, tf_nb,
                                              moutp, partp);
  k_final<<<4, 256, 0, stream>>>(partp, tf_pw, tf_pb, out);

  (void)in_sizes; (void)n_in; (void)out_size; (void)ws_size;
}

// Round 11
// 92.603 us; speedup vs baseline: 3.0254x; 1.2922x over previous
//
#include <hip/hip_runtime.h>
#include <hip/hip_bf16.h>

// UniTeacherEncoder v11: MFMA attention + MFMA oproj/fuse.
// Fragment convention HW-verified by v10's passing k_attn:
//   A: row=lane&15, k=(lane>>4)*8+i   (16B contiguous k)
//   B: col=lane&15, k=(lane>>4)*8+i   (16B contiguous k)
//   C/D: col=lane&15, row=(lane>>4)*4+reg
// k_attn emits PV result bf16 in oproj A-layout [str][tok][c=512].
// Weights for MFMA B stay in ORIGINAL [o][c] row-major layout (bf16 copy).
// __launch_bounds__(256,2) everywhere hot — only spill-free allocator config.

namespace {

constexpr int kN  = 1024;
constexpr int kC  = 128;
constexpr int kG  = 8;
constexpr int kDH = 64;
constexpr int kND = 256;

constexpr int   kNT    = 16384;
constexpr float kRLO   = -2.0625f;   // rel in [-2.032, 2.032] guaranteed (|off|<=4)
constexpr float kRSPAN = 4.125f;

// workspace layout (float offsets)
constexpr size_t W_LNKV = 0;          // 2048 x 128 f32
constexpr size_t W_LNQ1 = 262144;
constexpr size_t W_LNQ2 = 524288;
constexpr size_t W_Q    = 786432;     // bf16 [32 bg][1024 r][64 d] row-major
constexpr size_t W_K    = 1835008;    // bf16 [32 bg][256 j][64 d] row-major
constexpr size_t W_VT   = 2097152;    // bf16 [32 bg][64 d][256 j] (transposed V)
constexpr size_t W_VGS  = 2359296;    // f32 [32][256]
constexpr size_t W_AO   = 2367488;    // bf16 [2 str][2048 tok][512 c]
constexpr size_t W_FUS  = 4988928;    // f32 2048 x 128
constexpr size_t W_TAB  = 5251072;    // f32 2 x 16385
constexpr size_t W_MOUT = 5283844;    // 4 x 128
constexpr size_t W_PART = 5284356;    // 4 x 64 x 128
constexpr size_t W_OWB  = 5317124;    // bf16 2x128x512 (131072 bf16 = 65536 f)
constexpr size_t W_FWB  = 5382660;    // bf16 128x256  (32768 bf16 = 16384 f)

} // namespace

typedef __attribute__((ext_vector_type(8))) short short8;
typedef __attribute__((ext_vector_type(4))) float floatx4;

__device__ __forceinline__ float wave_sum(float v) {
#pragma unroll
  for (int o = 32; o > 0; o >>= 1) v += __shfl_xor(v, o, 64);
  return v;
}
__device__ __forceinline__ float cpb_bias(const float* __restrict__ tabs,
                                          float seq, float vg) {
  float rel = seq - vg;
  float ft = (rel - kRLO) * ((float)kNT / kRSPAN);
  ft = fminf(fmaxf(ft, 0.f), 16383.999f);
  int ix = (int)ft;
  float fw = ft - (float)ix;
  return tabs[ix] * (1.f - fw) + tabs[ix + 1] * fw;
}

// ---------------- k_prep: weight bf16 cvt + LN x3 + CPB table + mout ----------------
// blocks [0,640): f32->bf16 copy of ow (131072) and fw (32768)
// blocks [640,2176): LN of x1_0 / x1_1 / x2 (wave per token)
// blocks [2176,2306): CPB table
// blocks [2306,2310): mout
__global__ void k_prep(const float* __restrict__ ow, const float* __restrict__ fw,
                       __hip_bfloat16* __restrict__ owb, __hip_bfloat16* __restrict__ fwb,
                       const float* __restrict__ x1_0, const float* __restrict__ x1_1,
                       const float* __restrict__ x2, float* __restrict__ lnq1,
                       float* __restrict__ lnq2, float* __restrict__ lnkv,
                       const float* __restrict__ ng, const float* __restrict__ nb,
                       const float* __restrict__ cw1, const float* __restrict__ cb1,
                       const float* __restrict__ cw2, const float* __restrict__ cb2,
                       const float* __restrict__ cw3, const float* __restrict__ cb3,
                       float* __restrict__ tab,
                       const float* __restrict__ tfng, const float* __restrict__ tfnb,
                       const float* __restrict__ inw, const float* __restrict__ inb,
                       const float* __restrict__ tow, const float* __restrict__ tob,
                       float* __restrict__ mout) {
  int bx = blockIdx.x;
  int t = threadIdx.x;
  if (bx < 640) {
    int id = bx * 256 + t;
    if (id < 131072) owb[id] = __float2bfloat16(ow[id]);
    else fwb[id - 131072] = __float2bfloat16(fw[id - 131072]);
  } else if (bx < 2176) {
    int w = t >> 6, lane = t & 63;
    int gr = (bx - 640) * 4 + w;
    int sel = gr >> 11, row = gr & 2047;
    const float* in = (sel == 0) ? x1_0 : (sel == 1) ? x1_1 : x2;
    float* out = (sel == 0) ? lnq1 : (sel == 1) ? lnq2 : lnkv;
    const float* xr = in + (size_t)row * kC;
    float xa = xr[lane], xb = xr[lane + 64];
    float m = wave_sum(xa + xb) * (1.f / kC);
    float da = xa - m, db = xb - m;
    float v = wave_sum(da * da + db * db) * (1.f / kC);
    float r = rsqrtf(v + 1e-5f);
    float* orow = out + (size_t)row * kC;
    orow[lane]      = da * r * ng[lane] + nb[lane];
    orow[lane + 64] = db * r * ng[lane + 64] + nb[lane + 64];
  } else if (bx < 2306) {
    int rel = bx - 2176;
    int idx = rel / 65, bb = rel - idx * 65;
    int tt = bb * 256 + t;
    if (tt <= kNT) {
      float rel_ = kRLO + (kRSPAN / (float)kNT) * (float)tt;
      float u = (rel_ >= 0.f ? 1.f : -1.f) * log1pf(fabsf(rel_));
      const float* W1 = cw1 + idx * 32; const float* B1 = cb1 + idx * 32;
      const float* W2 = cw2 + idx * 1024; const float* B2 = cb2 + idx * 32;
      const float* W3 = cw3 + idx * 32; const float* B3 = cb3 + idx;
      float h1[32];
#pragma unroll
      for (int m = 0; m < 32; ++m) h1[m] = fmaxf(0.f, u * W1[m] + B1[m]);
      float o = B3[0];
      for (int m = 0; m < 32; ++m) {
        float a = B2[m];
#pragma unroll
        for (int k = 0; k < 32; ++k) a += h1[k] * W2[k * 32 + m];
        o += fmaxf(a, 0.f) * W3[m];
      }
      tab[(size_t)idx * (kNT + 1) + tt] = o;
    }
  } else {
    int rel = bx - 2306;
    int i = rel >> 1, b = rel & 1;
    bool act = t < 128;
    __shared__ float red[2];
    __shared__ float s1[128];
    __shared__ float s2[128];
    const float* xs = (i ? x1_1 : x1_0) + (size_t)b * kN * kC;
    float x = act ? xs[t] : 0.f;
    float s = wave_sum(x);
    if (act && (t & 63) == 0) red[t >> 6] = s;
    __syncthreads();
    float m1 = (red[0] + red[1]) * (1.f / kC);
    __syncthreads();
    float d1 = x - m1;
    float ss = wave_sum(act ? d1 * d1 : 0.f);
    if (act && (t & 63) == 0) red[t >> 6] = ss;
    __syncthreads();
    float v1 = (red[0] + red[1]) * (1.f / kC);
    __syncthreads();
    float t0 = act ? d1 * rsqrtf(v1 + 1e-5f) * ng[t] + nb[t] : 0.f;
    s = wave_sum(t0);
    if (act && (t & 63) == 0) red[t >> 6] = s;
    __syncthreads();
    float m2 = (red[0] + red[1]) * (1.f / kC);
    __syncthreads();
    float d2 = t0 - m2;
    ss = wave_sum(act ? d2 * d2 : 0.f);
    if (act && (t & 63) == 0) red[t >> 6] = ss;
    __syncthreads();
    float v2 = (red[0] + red[1]) * (1.f / kC);
    if (act) s1[t] = d2 * rsqrtf(v2 + 1e-5f) * tfng[i * kC + t] + tfnb[i * kC + t];
    __syncthreads();
    if (act) {
      float a0 = 0.f;
      const float* wr = inw + (size_t)i * 384 * kC + (size_t)(256 + t) * kC;
      for (int c = 0; c < 128; ++c) a0 += s1[c] * wr[c];
      s2[t] = inb[i * 384 + 256 + t] + a0;
    }
    __syncthreads();
    if (act) {
      float a0 = 0.f;
      const float* wr2 = tow + (size_t)i * kC * kC + (size_t)t * kC;
      for (int c = 0; c < 128; ++c) a0 += s2[c] * wr2[c];
      mout[rel * kC + t] = tob[i * kC + t] + a0;
    }
  }
}

// ---------------- k_qoff: qproj ([0,512)) + offsets ([512,2560)) ----------------
__global__ void k_qoff(const float* __restrict__ lnq1, const float* __restrict__ lnq2,
                       const float* __restrict__ qw, const float* __restrict__ o1w,
                       const float* __restrict__ o1b, const float* __restrict__ o2w,
                       __hip_bfloat16* __restrict__ qout, float* __restrict__ vgs) {
  int bx = blockIdx.x;
  if (bx < 512) {
    int bg = bx >> 4, r0 = (bx & 15) * 64;
    int str = bg >> 4, b = (bg >> 3) & 1, g = bg & 7;
    int rl = threadIdx.x & 63, dq = threadIdx.x >> 6;
    const float* lnq = str ? lnq2 : lnq1;
    const float* xr = lnq + ((size_t)(b * kN + r0 + rl)) * kC + g * 16;
    float4 x0 = *(const float4*)(xr + 0);
    float4 x1 = *(const float4*)(xr + 4);
    float4 x2 = *(const float4*)(xr + 8);
    float4 x3 = *(const float4*)(xr + 12);
    const float* wqb = qw + (size_t)str * 8192 + (size_t)g * 1024;
    __hip_bfloat16* qrow = qout + ((size_t)bg * 1024 + r0 + rl) * 64 + dq * 16;
#pragma unroll 4
    for (int dd = 0; dd < 16; ++dd) {
      int d = dq * 16 + dd;
      const float* wq = wqb + d * 16;
      float4 w0 = *(const float4*)(wq + 0);
      float4 w1 = *(const float4*)(wq + 4);
      float4 w2 = *(const float4*)(wq + 8);
      float4 w3 = *(const float4*)(wq + 12);
      float q = x0.x * w0.x + x0.y * w0.y + x0.z * w0.z + x0.w * w0.w
              + x1.x * w1.x + x1.y * w1.y + x1.z * w1.z + x1.w * w1.w
              + x2.x * w2.x + x2.y * w2.y + x2.z * w2.z + x2.w * w2.w
              + x3.x * w3.x + x3.y * w3.y + x3.z * w3.z + x3.w * w3.w;
      qrow[dd] = __float2bfloat16(q);
    }
  } else {
    int bxo = bx - 512;
    int w = threadIdx.x >> 6, lane = threadIdx.x & 63;
    int bg = bxo >> 6, j = ((bxo & 63) << 2) + w;
    int str = bg >> 4, b = (bg >> 3) & 1, g = bg & 7;
    const float* lnq = str ? lnq2 : lnq1;
    __shared__ float xr[4][96];
    int base = j * 4 - 1;
#pragma unroll
    for (int rep = 0; rep < 2; ++rep) {
      int idx = lane + rep * 64;
      if (idx < 96) {
        int r = idx >> 4, c = idx & 15, n = base + r;
        xr[w][idx] = (n >= 0 && n < kN)
                         ? lnq[((size_t)(b * kN + n)) * kC + g * 16 + c] : 0.f;
      }
    }
    const float* wq = qw + (size_t)str * 8192 + (size_t)(g * kDH + lane) * 16;
    float acc = o1b[str * 64 + lane];
#pragma unroll
    for (int k2 = 0; k2 < 6; ++k2) {
      float qv = 0.f;
#pragma unroll
      for (int c = 0; c < 16; ++c) qv += xr[w][k2 * 16 + c] * wq[c];
      acc += qv * o1w[str * 384 + lane * 6 + k2];
    }
    float ge = 0.5f * acc * (1.f + erff(acc * 0.70710678118654752440f));
    float s = wave_sum(ge * o2w[str * 64 + lane]);
    if (lane == 0)
      vgs[bg * kND + j] = 2.f * ((float)j + tanhf(s) * 4.0f) / 255.f - 1.f;
  }
}

// ---------------- grid_sample + k/v projections ----------------
__global__ void k_sample_kv(const float* __restrict__ lnkv, const float* __restrict__ vgs,
                            const float* __restrict__ kw, const float* __restrict__ vw,
                            __hip_bfloat16* __restrict__ kout,
                            __hip_bfloat16* __restrict__ vtout) {
  int w = threadIdx.x >> 6, lane = threadIdx.x & 63;
  int bg = blockIdx.x >> 6, j = ((blockIdx.x & 63) << 2) + w;
  int str = bg >> 4, b = (bg >> 3) & 1, g = bg & 7;
  __shared__ float sc[4][16];
  if (lane < 16) {
    float gr = vgs[bg * kND + j];
    float x = ((gr + 1.f) * 1024.f - 1.f) * 0.5f;
    float x0f = floorf(x);
    float w1 = x - x0f;
    int x0 = (int)x0f, x1 = x0 + 1;
    const float* src = lnkv + (size_t)b * kN * kC + g * 16 + lane;
    float v0 = (x0 >= 0 && x0 < 1024) ? src[(size_t)x0 * kC] : 0.f;
    float v1 = (x1 >= 0 && x1 < 1024) ? src[(size_t)x1 * kC] : 0.f;
    sc[w][lane] = v0 * (1.f - w1) + v1 * w1;
  }
  const float* kwr = kw + (size_t)str * 8192 + (size_t)(g * kDH + lane) * 16;
  const float* vwr = vw + (size_t)str * 8192 + (size_t)(g * kDH + lane) * 16;
  float ka = 0.f, va = 0.f;
#pragma unroll
  for (int c = 0; c < 16; ++c) { ka += sc[w][c] * kwr[c]; va += sc[w][c] * vwr[c]; }
  kout[((size_t)bg * 256 + j) * 64 + lane] = __float2bfloat16(ka);      // K[j][d]
  vtout[((size_t)bg * 64 + lane) * 256 + j] = __float2bfloat16(va);     // Vt[d][j]
}

// ---------------- MFMA flash attention: block = (bg, 64-row tile) ----------------
__global__ void __launch_bounds__(256, 2)
k_attn(const __hip_bfloat16* __restrict__ q_g, const __hip_bfloat16* __restrict__ k_g,
       const __hip_bfloat16* __restrict__ vt_g, const float* __restrict__ vgs,
       const float* __restrict__ tab, float* __restrict__ aout,
       __hip_bfloat16* __restrict__ attout) {
  int bg = blockIdx.x >> 4, tile = blockIdx.x & 15;
  int str = bg >> 4;
  int i0 = tile * 64;
  int t = threadIdx.x;
  int w = t >> 6, l = t & 63;
  int lr = l & 15, lg = l >> 4;

  __shared__ __align__(16) __hip_bfloat16 Qs[64 * 72];
  __shared__ __align__(16) __hip_bfloat16 Ss[64 * 72];
  __shared__ __align__(16) __hip_bfloat16 Ps[64 * 272];

  const float* tabs = tab + str * (kNT + 1);

  {
    int r = t >> 2, c0 = (t & 3) * 16;
    const __hip_bfloat16* src = q_g + ((size_t)bg * 1024 + i0 + r) * 64 + c0;
    *(float4*)&Qs[r * 72 + c0]     = *(const float4*)src;
    *(float4*)&Qs[r * 72 + c0 + 8] = *(const float4*)(src + 8);
  }
  short8 a0 = *(const short8*)&Qs[(w * 16 + lr) * 72 + lg * 8];
  short8 a1 = *(const short8*)&Qs[(w * 16 + lr) * 72 + 32 + lg * 8];

  floatx4 acc[16];
#pragma unroll
  for (int f = 0; f < 16; ++f) acc[f] = {0.f, 0.f, 0.f, 0.f};

#pragma unroll
  for (int jc = 0; jc < 4; ++jc) {
    __syncthreads();
    {
      int r = t >> 2, c0 = (t & 3) * 16;
      const __hip_bfloat16* src = k_g + ((size_t)bg * 256 + jc * 64 + r) * 64 + c0;
      *(float4*)&Ss[r * 72 + c0]     = *(const float4*)src;
      *(float4*)&Ss[r * 72 + c0 + 8] = *(const float4*)(src + 8);
    }
    __syncthreads();
#pragma unroll
    for (int ct = 0; ct < 4; ++ct) {
      short8 b0 = *(const short8*)&Ss[(ct * 16 + lr) * 72 + lg * 8];
      short8 b1 = *(const short8*)&Ss[(ct * 16 + lr) * 72 + 32 + lg * 8];
      acc[jc * 4 + ct] =
          __builtin_amdgcn_mfma_f32_16x16x32_bf16(a0, b0, acc[jc * 4 + ct], 0, 0, 0);
      acc[jc * 4 + ct] =
          __builtin_amdgcn_mfma_f32_16x16x32_bf16(a1, b1, acc[jc * 4 + ct], 0, 0, 0);
    }
  }

  float vgl[16];
#pragma unroll
  for (int f = 0; f < 16; ++f) vgl[f] = vgs[bg * 256 + f * 16 + lr];
  float* aoutb = aout + (size_t)str * 4194304 + (size_t)(bg & 15) * 262144;
#pragma unroll
  for (int reg = 0; reg < 4; ++reg) {
    int row = w * 16 + lg * 4 + reg;
    int i = i0 + row;
    float seq = 2.f * (float)i / 1023.f - 1.f;
    float sv[16];
#pragma unroll
    for (int f = 0; f < 16; ++f)
      sv[f] = acc[f][reg] * 0.125f + cpb_bias(tabs, seq, vgl[f]);
    float m = sv[0];
#pragma unroll
    for (int f = 1; f < 16; ++f) m = fmaxf(m, sv[f]);
    m = fmaxf(m, __shfl_xor(m, 1, 64));
    m = fmaxf(m, __shfl_xor(m, 2, 64));
    m = fmaxf(m, __shfl_xor(m, 4, 64));
    m = fmaxf(m, __shfl_xor(m, 8, 64));
    float ev[16], sum = 0.f;
#pragma unroll
    for (int f = 0; f < 16; ++f) { ev[f] = expf(sv[f] - m); sum += ev[f]; }
    sum += __shfl_xor(sum, 1, 64);
    sum += __shfl_xor(sum, 2, 64);
    sum += __shfl_xor(sum, 4, 64);
    sum += __shfl_xor(sum, 8, 64);
    float inv = 1.f / sum;
    float* arow = aoutb + (size_t)i * 256;
#pragma unroll
    for (int f = 0; f < 16; ++f) {
      float p = ev[f] * inv;
      arow[f * 16 + lr] = p;
      Ps[row * 272 + f * 16 + lr] = __float2bfloat16(p);
    }
  }

  floatx4 oacc[4];
#pragma unroll
  for (int dt = 0; dt < 4; ++dt) oacc[dt] = {0.f, 0.f, 0.f, 0.f};
#pragma unroll
  for (int jc = 0; jc < 4; ++jc) {
    __syncthreads();
    {
      int r = t >> 2, c0 = (t & 3) * 16;
      const __hip_bfloat16* src = vt_g + ((size_t)bg * 64 + r) * 256 + jc * 64 + c0;
      *(float4*)&Ss[r * 72 + c0]     = *(const float4*)src;
      *(float4*)&Ss[r * 72 + c0 + 8] = *(const float4*)(src + 8);
    }
    __syncthreads();
    short8 pa0 = *(const short8*)&Ps[(w * 16 + lr) * 272 + jc * 64 + lg * 8];
    short8 pa1 = *(const short8*)&Ps[(w * 16 + lr) * 272 + jc * 64 + 32 + lg * 8];
#pragma unroll
    for (int dt = 0; dt < 4; ++dt) {
      short8 b0 = *(const short8*)&Ss[(dt * 16 + lr) * 72 + lg * 8];
      short8 b1 = *(const short8*)&Ss[(dt * 16 + lr) * 72 + 32 + lg * 8];
      oacc[dt] = __builtin_amdgcn_mfma_f32_16x16x32_bf16(pa0, b0, oacc[dt], 0, 0, 0);
      oacc[dt] = __builtin_amdgcn_mfma_f32_16x16x32_bf16(pa1, b1, oacc[dt], 0, 0, 0);
    }
  }
  // store PV result bf16 in oproj A-layout: [str][b*1024+i][g*64 + d]
  {
    int b = (bg >> 3) & 1, g = bg & 7;
    __hip_bfloat16* ab = attout + ((size_t)(str * 2 + b) * 1024) * 512 + (size_t)g * 64;
#pragma unroll
    for (int dt = 0; dt < 4; ++dt)
#pragma unroll
      for (int reg = 0; reg < 4; ++reg) {
        int row = w * 16 + lg * 4 + reg;
        ab[(size_t)(i0 + row) * 512 + dt * 16 + lr] = __float2bfloat16(oacc[dt][reg]);
      }
  }
}

// ---------------- MFMA oproj (both streams) + residual + fuse ----------------
// Block = 16 tokens, 4 waves; wave w owns o-tiles {2w, 2w+1}. 128 blocks.
__global__ void __launch_bounds__(256, 2)
k_oproj_fuse(const __hip_bfloat16* __restrict__ aog, const __hip_bfloat16* __restrict__ owb,
             const float* __restrict__ ob,
             const float* __restrict__ x1_0, const float* __restrict__ x1_1,
             const __hip_bfloat16* __restrict__ fwb, const float* __restrict__ fb,
             float* __restrict__ fused) {
  int tok0 = blockIdx.x * 16;
  int t = threadIdx.x;
  int w = t >> 6, l = t & 63;
  int lr = l & 15, lg = l >> 4;
  int nt0 = w * 2;

  __shared__ __align__(16) __hip_bfloat16 xos[16 * 280];  // stride 280: 16B-aligned, ~2-way banks

  for (int s = 0; s < 2; ++s) {
    const __hip_bfloat16* arow = aog + ((size_t)(s * 2048 + tok0 + lr)) * 512 + lg * 8;
    const __hip_bfloat16* wb0 = owb + (size_t)s * 65536 + (size_t)((nt0 + 0) * 16 + lr) * 512 + lg * 8;
    const __hip_bfloat16* wb1 = owb + (size_t)s * 65536 + (size_t)((nt0 + 1) * 16 + lr) * 512 + lg * 8;
    floatx4 acc0 = {0.f, 0.f, 0.f, 0.f}, acc1 = {0.f, 0.f, 0.f, 0.f};
#pragma unroll
    for (int ks = 0; ks < 16; ++ks) {
      short8 a  = *(const short8*)(arow + ks * 32);
      short8 b0 = *(const short8*)(wb0 + ks * 32);
      short8 b1 = *(const short8*)(wb1 + ks * 32);
      acc0 = __builtin_amdgcn_mfma_f32_16x16x32_bf16(a, b0, acc0, 0, 0, 0);
      acc1 = __builtin_amdgcn_mfma_f32_16x16x32_bf16(a, b1, acc1, 0, 0, 0);
    }
    const float* x1 = s ? x1_1 : x1_0;
    float bias0 = ob[s * 128 + nt0 * 16 + lr];
    float bias1 = ob[s * 128 + (nt0 + 1) * 16 + lr];
#pragma unroll
    for (int reg = 0; reg < 4; ++reg) {
      int row = lg * 4 + reg;
      size_t xi = (size_t)(tok0 + row) * 128;
      xos[row * 280 + s * 128 + nt0 * 16 + lr] =
          __float2bfloat16(acc0[reg] + x1[xi + nt0 * 16 + lr] + bias0);
      xos[row * 280 + s * 128 + (nt0 + 1) * 16 + lr] =
          __float2bfloat16(acc1[reg] + x1[xi + (nt0 + 1) * 16 + lr] + bias1);
    }
  }
  __syncthreads();

  floatx4 f0 = {0.f, 0.f, 0.f, 0.f}, f1 = {0.f, 0.f, 0.f, 0.f};
  const __hip_bfloat16* fb0 = fwb + (size_t)((nt0 + 0) * 16 + lr) * 256 + lg * 8;
  const __hip_bfloat16* fb1 = fwb + (size_t)((nt0 + 1) * 16 + lr) * 256 + lg * 8;
#pragma unroll
  for (int ks = 0; ks < 8; ++ks) {
    short8 a  = *(const short8*)&xos[lr * 280 + ks * 32 + lg * 8];
    short8 b0 = *(const short8*)(fb0 + ks * 32);
    short8 b1 = *(const short8*)(fb1 + ks * 32);
    f0 = __builtin_amdgcn_mfma_f32_16x16x32_bf16(a, b0, f0, 0, 0, 0);
    f1 = __builtin_amdgcn_mfma_f32_16x16x32_bf16(a, b1, f1, 0, 0, 0);
  }
  float fbias0 = fb[nt0 * 16 + lr], fbias1 = fb[(nt0 + 1) * 16 + lr];
#pragma unroll
  for (int reg = 0; reg < 4; ++reg) {
    int row = lg * 4 + reg;
    fused[(size_t)(tok0 + row) * 128 + nt0 * 16 + lr]       = f0[reg] + fbias0;
    fused[(size_t)(tok0 + row) * 128 + (nt0 + 1) * 16 + lr] = f1[reg] + fbias1;
  }
}

// ---------------- double-LN + mout, wave per token, chunk partials ----------------
__global__ void k_meanz(const float* __restrict__ fused, const float* __restrict__ ng,
                        const float* __restrict__ nb, const float* __restrict__ tfng,
                        const float* __restrict__ tfnb, const float* __restrict__ mout,
                        float* __restrict__ partial) {
  int chunk = blockIdx.x, b = blockIdx.y, i = blockIdx.z;
  int w = threadIdx.x >> 6, lane = threadIdx.x & 63;
  int c = lane, c2 = lane + 64;
  float moa = mout[(i * 2 + b) * kC + c], mob = mout[(i * 2 + b) * kC + c2];
  float g1a = ng[c], b1a = nb[c], g1b = ng[c2], b1b = nb[c2];
  float g2a = tfng[i * kC + c], b2a = tfnb[i * kC + c];
  float g2b = tfng[i * kC + c2], b2b = tfnb[i * kC + c2];
  float acca = 0.f, accb = 0.f;
#pragma unroll
  for (int it = 0; it < 4; ++it) {
    int tok = chunk * 16 + it * 4 + w;
    const float* xr = fused + ((size_t)(b * kN + tok)) * kC;
    float xa = xr[c], xb = xr[c2];
    float m1 = wave_sum(xa + xb) * (1.f / kC);
    float da = xa - m1, db = xb - m1;
    float v1 = wave_sum(da * da + db * db) * (1.f / kC);
    float r1 = rsqrtf(v1 + 1e-5f);
    float za = da * r1 * g1a + b1a + moa;
    float zb = db * r1 * g1b + b1b + mob;
    float m2 = wave_sum(za + zb) * (1.f / kC);
    float ea = za - m2, eb = zb - m2;
    float v2 = wave_sum(ea * ea + eb * eb) * (1.f / kC);
    float r2 = rsqrtf(v2 + 1e-5f);
    acca += ea * r2 * g2a + b2a;
    accb += eb * r2 * g2b + b2b;
  }
  __shared__ float red[4][128];
  red[w][c] = acca; red[w][c2] = accb;
  __syncthreads();
  if (w == 0) {
    float pa = red[0][c] + red[1][c] + red[2][c] + red[3][c];
    float pb = red[0][c2] + red[1][c2] + red[2][c2] + red[3][c2];
    float* pr = partial + ((size_t)(i * 2 + b) * 64 + chunk) * kC;
    pr[c] = pa; pr[c2] = pb;
  }
}

__global__ void k_final(const float* __restrict__ partial, const float* __restrict__ pw,
                        const float* __restrict__ pb, float* __restrict__ out) {
  int ib = blockIdx.x;
  int i = ib >> 1, t = threadIdx.x;
  int c = t & 127, half = t >> 7;
  float a = 0.f;
  for (int ch = half * 32; ch < half * 32 + 32; ++ch)
    a += partial[((size_t)ib * 64 + ch) * kC + c];
  __shared__ float s[256];
  s[half * 128 + c] = a;
  __syncthreads();
  if (t < 128) s[t] = (s[t] + s[128 + t]) * (1.f / (float)kN);
  __syncthreads();
  if (t < 128) {
    float a0 = 0.f;
    const float* wr = pw + (size_t)i * kC * kC + (size_t)t * kC;
    for (int cc = 0; cc < 128; ++cc) a0 += s[cc] * wr[cc];
    out[ib * 128 + t] = tanhf(pb[i * kC + t] + a0);
  }
}

extern "C" void kernel_launch(void* const* d_in, const int* in_sizes, int n_in,
                              void* d_out, int out_size, void* d_ws, size_t ws_size,
                              hipStream_t stream) {
  const float* x1_0   = (const float*)d_in[0];
  const float* x1_1   = (const float*)d_in[1];
  const float* x2     = (const float*)d_in[2];
  const float* norm_g = (const float*)d_in[3];
  const float* norm_b = (const float*)d_in[4];
  const float* d_qw   = (const float*)d_in[5];
  const float* d_kw   = (const float*)d_in[6];
  const float* d_vw   = (const float*)d_in[7];
  const float* d_ow   = (const float*)d_in[8];
  const float* d_ob   = (const float*)d_in[9];
  const float* d_o1w  = (const float*)d_in[10];
  const float* d_o1b  = (const float*)d_in[11];
  const float* d_o2w  = (const float*)d_in[12];
  const float* c_w1   = (const float*)d_in[13];
  const float* c_b1   = (const float*)d_in[14];
  const float* c_w2   = (const float*)d_in[15];
  const float* c_b2   = (const float*)d_in[16];
  const float* c_w3   = (const float*)d_in[17];
  const float* c_b3   = (const float*)d_in[18];
  const float* fus_w  = (const float*)d_in[19];
  const float* fus_b  = (const float*)d_in[20];
  const float* tf_ng  = (const float*)d_in[21];
  const float* tf_nb  = (const float*)d_in[22];
  const float* tf_inw = (const float*)d_in[23];
  const float* tf_inb = (const float*)d_in[24];
  const float* tf_ow  = (const float*)d_in[25];
  const float* tf_ob  = (const float*)d_in[26];
  const float* tf_pw  = (const float*)d_in[27];
  const float* tf_pb  = (const float*)d_in[28];

  float* ws = (float*)d_ws;
  float* out = (float*)d_out;
  float* lnkv = ws + W_LNKV;
  float* lnq1 = ws + W_LNQ1; float* lnq2 = ws + W_LNQ2;
  __hip_bfloat16* qb  = (__hip_bfloat16*)(ws + W_Q);
  __hip_bfloat16* kb  = (__hip_bfloat16*)(ws + W_K);
  __hip_bfloat16* vtb = (__hip_bfloat16*)(ws + W_VT);
  float* vgsw = ws + W_VGS;
  __hip_bfloat16* aob = (__hip_bfloat16*)(ws + W_AO);
  float* fused = ws + W_FUS; float* tab = ws + W_TAB;
  float* moutp = ws + W_MOUT; float* partp = ws + W_PART;
  __hip_bfloat16* owb = (__hip_bfloat16*)(ws + W_OWB);
  __hip_bfloat16* fwb = (__hip_bfloat16*)(ws + W_FWB);

  // output: f1(256) | f2(256) | a1(2*8*1024*256) | a2(same), all f32
  float* aoutb = out + 512;

  k_prep<<<2310, 256, 0, stream>>>(d_ow, fus_w, owb, fwb,
                                   x1_0, x1_1, x2, lnq1, lnq2, lnkv, norm_g, norm_b,
                                   c_w1, c_b1, c_w2, c_b2, c_w3, c_b3, tab,
                                   tf_ng, tf_nb, tf_inw, tf_inb, tf_ow, tf_ob, moutp);
  k_qoff<<<2560, 256, 0, stream>>>(lnq1, lnq2, d_qw, d_o1w, d_o1b, d_o2w, qb, vgsw);
  k_sample_kv<<<2048, 256, 0, stream>>>(lnkv, vgsw, d_kw, d_vw, kb, vtb);
  k_attn<<<512, 256, 0, stream>>>(qb, kb, vtb, vgsw, tab, aoutb, aob);
  k_oproj_fuse<<<128, 256, 0, stream>>>(aob, owb, d_ob, x1_0, x1_1, fwb, fus_b, fused);
  k_meanz<<<dim3(64, 2, 2), 256, 0, stream>>>(fused, norm_g, norm_b, tf_ng, tf_nb,
                                              moutp, partp);
  k_final<<<4, 256, 0, stream>>>(partp, tf_pw, tf_pb, out);

  (void)in_sizes; (void)n_in; (void)out_size; (void)ws_size;
}

// Round 12
// 88.611 us; speedup vs baseline: 3.1617x; 1.0451x over previous
//
#include <hip/hip_runtime.h>
#include <hip/hip_bf16.h>

// UniTeacherEncoder v12: MFMA attn with LDS-resident 2048-entry CPB table
// (Qs region reused after Q fragments load), Ps stride 264, 3 blocks/CU;
// meanz merged into oproj_fuse (fused stays in LDS). 6 launches.
// Fragment convention HW-verified (v10/v11 pass):
//   A: row=lane&15, k=(lane>>4)*8+i ; B: col=lane&15, k=(lane>>4)*8+i
//   C/D: col=lane&15, row=(lane>>4)*4+reg
// __launch_bounds__(256,2) on hot kernels (only spill-free allocator config).

namespace {

constexpr int kN  = 1024;
constexpr int kC  = 128;
constexpr int kG  = 8;
constexpr int kDH = 64;
constexpr int kND = 256;

constexpr int   kNT    = 2048;      // CPB table intervals (PWL, slope-changes ~1e-4 -> err ~5e-8)
constexpr float kRLO   = -2.0625f;  // rel in [-2.032, 2.032] guaranteed (|off|<=4)
constexpr float kRSPAN = 4.125f;

// workspace layout (float offsets)
constexpr size_t W_LNKV = 0;          // 2048 x 128 f32
constexpr size_t W_LNQ1 = 262144;
constexpr size_t W_LNQ2 = 524288;
constexpr size_t W_Q    = 786432;     // bf16 [32 bg][1024 r][64 d] row-major
constexpr size_t W_K    = 1835008;    // bf16 [32 bg][256 j][64 d] row-major
constexpr size_t W_VT   = 2097152;    // bf16 [32 bg][64 d][256 j] (transposed V)
constexpr size_t W_VGS  = 2359296;    // f32 [32][256]
constexpr size_t W_AO   = 2367488;    // bf16 [2 str][2048 tok][512 c]
constexpr size_t W_TAB  = 5251072;    // f32 2 x 2049
constexpr size_t W_MOUT = 5283844;    // 4 x 128
constexpr size_t W_PART = 5284356;    // 4 x 64 x 128
constexpr size_t W_OWB  = 5317124;    // bf16 2x128x512
constexpr size_t W_FWB  = 5382660;    // bf16 128x256

} // namespace

typedef __attribute__((ext_vector_type(8))) short short8;
typedef __attribute__((ext_vector_type(4))) float floatx4;

__device__ __forceinline__ float wave_sum(float v) {
#pragma unroll
  for (int o = 32; o > 0; o >>= 1) v += __shfl_xor(v, o, 64);
  return v;
}
__device__ __forceinline__ float cpb_lds(const float* __restrict__ tabL,
                                         float seq, float vg) {
  float rel = seq - vg;
  float ft = (rel - kRLO) * ((float)kNT / kRSPAN);
  ft = fminf(fmaxf(ft, 0.f), (float)kNT - 0.001f);
  int ix = (int)ft;
  float fw = ft - (float)ix;
  return tabL[ix] * (1.f - fw) + tabL[ix + 1] * fw;
}

// ---------------- k_prep: weight bf16 cvt + LN x3 + CPB table + mout ----------------
// blocks [0,640): f32->bf16 copy of ow/fw
// blocks [640,2176): LN of x1_0 / x1_1 / x2 (wave per token)
// blocks [2176,2194): CPB table (9 blocks per idx, 2049 entries)
// blocks [2194,2198): mout
__global__ void k_prep(const float* __restrict__ ow, const float* __restrict__ fw,
                       __hip_bfloat16* __restrict__ owb, __hip_bfloat16* __restrict__ fwb,
                       const float* __restrict__ x1_0, const float* __restrict__ x1_1,
                       const float* __restrict__ x2, float* __restrict__ lnq1,
                       float* __restrict__ lnq2, float* __restrict__ lnkv,
                       const float* __restrict__ ng, const float* __restrict__ nb,
                       const float* __restrict__ cw1, const float* __restrict__ cb1,
                       const float* __restrict__ cw2, const float* __restrict__ cb2,
                       const float* __restrict__ cw3, const float* __restrict__ cb3,
                       float* __restrict__ tab,
                       const float* __restrict__ tfng, const float* __restrict__ tfnb,
                       const float* __restrict__ inw, const float* __restrict__ inb,
                       const float* __restrict__ tow, const float* __restrict__ tob,
                       float* __restrict__ mout) {
  int bx = blockIdx.x;
  int t = threadIdx.x;
  if (bx < 640) {
    int id = bx * 256 + t;
    if (id < 131072) owb[id] = __float2bfloat16(ow[id]);
    else fwb[id - 131072] = __float2bfloat16(fw[id - 131072]);
  } else if (bx < 2176) {
    int w = t >> 6, lane = t & 63;
    int gr = (bx - 640) * 4 + w;
    int sel = gr >> 11, row = gr & 2047;
    const float* in = (sel == 0) ? x1_0 : (sel == 1) ? x1_1 : x2;
    float* out = (sel == 0) ? lnq1 : (sel == 1) ? lnq2 : lnkv;
    const float* xr = in + (size_t)row * kC;
    float xa = xr[lane], xb = xr[lane + 64];
    float m = wave_sum(xa + xb) * (1.f / kC);
    float da = xa - m, db = xb - m;
    float v = wave_sum(da * da + db * db) * (1.f / kC);
    float r = rsqrtf(v + 1e-5f);
    float* orow = out + (size_t)row * kC;
    orow[lane]      = da * r * ng[lane] + nb[lane];
    orow[lane + 64] = db * r * ng[lane + 64] + nb[lane + 64];
  } else if (bx < 2194) {
    int rel = bx - 2176;
    int idx = rel / 9, bb = rel - idx * 9;
    int tt = bb * 256 + t;
    if (tt <= kNT) {
      float rel_ = kRLO + (kRSPAN / (float)kNT) * (float)tt;
      float u = (rel_ >= 0.f ? 1.f : -1.f) * log1pf(fabsf(rel_));
      const float* W1 = cw1 + idx * 32; const float* B1 = cb1 + idx * 32;
      const float* W2 = cw2 + idx * 1024; const float* B2 = cb2 + idx * 32;
      const float* W3 = cw3 + idx * 32; const float* B3 = cb3 + idx;
      float h1[32];
#pragma unroll
      for (int m = 0; m < 32; ++m) h1[m] = fmaxf(0.f, u * W1[m] + B1[m]);
      float o = B3[0];
      for (int m = 0; m < 32; ++m) {
        float a = B2[m];
#pragma unroll
        for (int k = 0; k < 32; ++k) a += h1[k] * W2[k * 32 + m];
        o += fmaxf(a, 0.f) * W3[m];
      }
      tab[(size_t)idx * (kNT + 1) + tt] = o;
    }
  } else {
    int rel = bx - 2194;
    int i = rel >> 1, b = rel & 1;
    bool act = t < 128;
    __shared__ float red[2];
    __shared__ float s1[128];
    __shared__ float s2[128];
    const float* xs = (i ? x1_1 : x1_0) + (size_t)b * kN * kC;
    float x = act ? xs[t] : 0.f;
    float s = wave_sum(x);
    if (act && (t & 63) == 0) red[t >> 6] = s;
    __syncthreads();
    float m1 = (red[0] + red[1]) * (1.f / kC);
    __syncthreads();
    float d1 = x - m1;
    float ss = wave_sum(act ? d1 * d1 : 0.f);
    if (act && (t & 63) == 0) red[t >> 6] = ss;
    __syncthreads();
    float v1 = (red[0] + red[1]) * (1.f / kC);
    __syncthreads();
    float t0 = act ? d1 * rsqrtf(v1 + 1e-5f) * ng[t] + nb[t] : 0.f;
    s = wave_sum(t0);
    if (act && (t & 63) == 0) red[t >> 6] = s;
    __syncthreads();
    float m2 = (red[0] + red[1]) * (1.f / kC);
    __syncthreads();
    float d2 = t0 - m2;
    ss = wave_sum(act ? d2 * d2 : 0.f);
    if (act && (t & 63) == 0) red[t >> 6] = ss;
    __syncthreads();
    float v2 = (red[0] + red[1]) * (1.f / kC);
    if (act) s1[t] = d2 * rsqrtf(v2 + 1e-5f) * tfng[i * kC + t] + tfnb[i * kC + t];
    __syncthreads();
    if (act) {
      float a0 = 0.f;
      const float* wr = inw + (size_t)i * 384 * kC + (size_t)(256 + t) * kC;
      for (int c = 0; c < 128; ++c) a0 += s1[c] * wr[c];
      s2[t] = inb[i * 384 + 256 + t] + a0;
    }
    __syncthreads();
    if (act) {
      float a0 = 0.f;
      const float* wr2 = tow + (size_t)i * kC * kC + (size_t)t * kC;
      for (int c = 0; c < 128; ++c) a0 += s2[c] * wr2[c];
      mout[rel * kC + t] = tob[i * kC + t] + a0;
    }
  }
}

// ---------------- k_qoff: qproj ([0,512)) + offsets ([512,2560)) ----------------
__global__ void k_qoff(const float* __restrict__ lnq1, const float* __restrict__ lnq2,
                       const float* __restrict__ qw, const float* __restrict__ o1w,
                       const float* __restrict__ o1b, const float* __restrict__ o2w,
                       __hip_bfloat16* __restrict__ qout, float* __restrict__ vgs) {
  int bx = blockIdx.x;
  if (bx < 512) {
    int bg = bx >> 4, r0 = (bx & 15) * 64;
    int str = bg >> 4, b = (bg >> 3) & 1, g = bg & 7;
    int rl = threadIdx.x & 63, dq = threadIdx.x >> 6;
    const float* lnq = str ? lnq2 : lnq1;
    const float* xr = lnq + ((size_t)(b * kN + r0 + rl)) * kC + g * 16;
    float4 x0 = *(const float4*)(xr + 0);
    float4 x1 = *(const float4*)(xr + 4);
    float4 x2 = *(const float4*)(xr + 8);
    float4 x3 = *(const float4*)(xr + 12);
    const float* wqb = qw + (size_t)str * 8192 + (size_t)g * 1024;
    __hip_bfloat16* qrow = qout + ((size_t)bg * 1024 + r0 + rl) * 64 + dq * 16;
#pragma unroll 4
    for (int dd = 0; dd < 16; ++dd) {
      int d = dq * 16 + dd;
      const float* wq = wqb + d * 16;
      float4 w0 = *(const float4*)(wq + 0);
      float4 w1 = *(const float4*)(wq + 4);
      float4 w2 = *(const float4*)(wq + 8);
      float4 w3 = *(const float4*)(wq + 12);
      float q = x0.x * w0.x + x0.y * w0.y + x0.z * w0.z + x0.w * w0.w
              + x1.x * w1.x + x1.y * w1.y + x1.z * w1.z + x1.w * w1.w
              + x2.x * w2.x + x2.y * w2.y + x2.z * w2.z + x2.w * w2.w
              + x3.x * w3.x + x3.y * w3.y + x3.z * w3.z + x3.w * w3.w;
      qrow[dd] = __float2bfloat16(q);
    }
  } else {
    int bxo = bx - 512;
    int w = threadIdx.x >> 6, lane = threadIdx.x & 63;
    int bg = bxo >> 6, j = ((bxo & 63) << 2) + w;
    int str = bg >> 4, b = (bg >> 3) & 1, g = bg & 7;
    const float* lnq = str ? lnq2 : lnq1;
    __shared__ float xr[4][96];
    int base = j * 4 - 1;
#pragma unroll
    for (int rep = 0; rep < 2; ++rep) {
      int idx = lane + rep * 64;
      if (idx < 96) {
        int r = idx >> 4, c = idx & 15, n = base + r;
        xr[w][idx] = (n >= 0 && n < kN)
                         ? lnq[((size_t)(b * kN + n)) * kC + g * 16 + c] : 0.f;
      }
    }
    const float* wq = qw + (size_t)str * 8192 + (size_t)(g * kDH + lane) * 16;
    float acc = o1b[str * 64 + lane];
#pragma unroll
    for (int k2 = 0; k2 < 6; ++k2) {
      float qv = 0.f;
#pragma unroll
      for (int c = 0; c < 16; ++c) qv += xr[w][k2 * 16 + c] * wq[c];
      acc += qv * o1w[str * 384 + lane * 6 + k2];
    }
    float ge = 0.5f * acc * (1.f + erff(acc * 0.70710678118654752440f));
    float s = wave_sum(ge * o2w[str * 64 + lane]);
    if (lane == 0)
      vgs[bg * kND + j] = 2.f * ((float)j + tanhf(s) * 4.0f) / 255.f - 1.f;
  }
}

// ---------------- grid_sample + k/v projections ----------------
__global__ void k_sample_kv(const float* __restrict__ lnkv, const float* __restrict__ vgs,
                            const float* __restrict__ kw, const float* __restrict__ vw,
                            __hip_bfloat16* __restrict__ kout,
                            __hip_bfloat16* __restrict__ vtout) {
  int w = threadIdx.x >> 6, lane = threadIdx.x & 63;
  int bg = blockIdx.x >> 6, j = ((blockIdx.x & 63) << 2) + w;
  int str = bg >> 4, b = (bg >> 3) & 1, g = bg & 7;
  __shared__ float sc[4][16];
  if (lane < 16) {
    float gr = vgs[bg * kND + j];
    float x = ((gr + 1.f) * 1024.f - 1.f) * 0.5f;
    float x0f = floorf(x);
    float w1 = x - x0f;
    int x0 = (int)x0f, x1 = x0 + 1;
    const float* src = lnkv + (size_t)b * kN * kC + g * 16 + lane;
    float v0 = (x0 >= 0 && x0 < 1024) ? src[(size_t)x0 * kC] : 0.f;
    float v1 = (x1 >= 0 && x1 < 1024) ? src[(size_t)x1 * kC] : 0.f;
    sc[w][lane] = v0 * (1.f - w1) + v1 * w1;
  }
  const float* kwr = kw + (size_t)str * 8192 + (size_t)(g * kDH + lane) * 16;
  const float* vwr = vw + (size_t)str * 8192 + (size_t)(g * kDH + lane) * 16;
  float ka = 0.f, va = 0.f;
#pragma unroll
  for (int c = 0; c < 16; ++c) { ka += sc[w][c] * kwr[c]; va += sc[w][c] * vwr[c]; }
  kout[((size_t)bg * 256 + j) * 64 + lane] = __float2bfloat16(ka);      // K[j][d]
  vtout[((size_t)bg * 64 + lane) * 256 + j] = __float2bfloat16(va);     // Vt[d][j]
}

// ---------------- MFMA flash attention: block = (bg, 64-row tile) ----------------
__global__ void __launch_bounds__(256, 2)
k_attn(const __hip_bfloat16* __restrict__ q_g, const __hip_bfloat16* __restrict__ k_g,
       const __hip_bfloat16* __restrict__ vt_g, const float* __restrict__ vgs,
       const float* __restrict__ tab, float* __restrict__ aout,
       __hip_bfloat16* __restrict__ attout) {
  int bg = blockIdx.x >> 4, tile = blockIdx.x & 15;
  int str = bg >> 4;
  int i0 = tile * 64;
  int t = threadIdx.x;
  int w = t >> 6, l = t & 63;
  int lr = l & 15, lg = l >> 4;

  __shared__ __align__(16) __hip_bfloat16 Qs[64 * 72];   // Q tile, then f32 CPB table
  __shared__ __align__(16) __hip_bfloat16 Ss[64 * 72];
  __shared__ __align__(16) __hip_bfloat16 Ps[64 * 264];

  const float* tabs = tab + str * (kNT + 1);

  // stage Q tile (wave-local rows), load fragments, then repurpose Qs as table
  {
    int r = t >> 2, c0 = (t & 3) * 16;
    const __hip_bfloat16* src = q_g + ((size_t)bg * 1024 + i0 + r) * 64 + c0;
    *(float4*)&Qs[r * 72 + c0]     = *(const float4*)src;
    *(float4*)&Qs[r * 72 + c0 + 8] = *(const float4*)(src + 8);
  }
  short8 a0 = *(const short8*)&Qs[(w * 16 + lr) * 72 + lg * 8];
  short8 a1 = *(const short8*)&Qs[(w * 16 + lr) * 72 + 32 + lg * 8];
  __syncthreads();  // all waves' Q-fragment reads complete before overwrite
  float* tabL = (float*)Qs;  // 2049 f32 = 8196 B <= 9216 B
  for (int e = t; e <= kNT; e += 256) tabL[e] = tabs[e];
  // (published by the first barrier of the jc-loop below)

  floatx4 acc[16];
#pragma unroll
  for (int f = 0; f < 16; ++f) acc[f] = {0.f, 0.f, 0.f, 0.f};

#pragma unroll
  for (int jc = 0; jc < 4; ++jc) {
    __syncthreads();
    {
      int r = t >> 2, c0 = (t & 3) * 16;
      const __hip_bfloat16* src = k_g + ((size_t)bg * 256 + jc * 64 + r) * 64 + c0;
      *(float4*)&Ss[r * 72 + c0]     = *(const float4*)src;
      *(float4*)&Ss[r * 72 + c0 + 8] = *(const float4*)(src + 8);
    }
    __syncthreads();
#pragma unroll
    for (int ct = 0; ct < 4; ++ct) {
      short8 b0 = *(const short8*)&Ss[(ct * 16 + lr) * 72 + lg * 8];
      short8 b1 = *(const short8*)&Ss[(ct * 16 + lr) * 72 + 32 + lg * 8];
      acc[jc * 4 + ct] =
          __builtin_amdgcn_mfma_f32_16x16x32_bf16(a0, b0, acc[jc * 4 + ct], 0, 0, 0);
      acc[jc * 4 + ct] =
          __builtin_amdgcn_mfma_f32_16x16x32_bf16(a1, b1, acc[jc * 4 + ct], 0, 0, 0);
    }
  }

  float vgl[16];
#pragma unroll
  for (int f = 0; f < 16; ++f) vgl[f] = vgs[bg * 256 + f * 16 + lr];
  float* aoutb = aout + (size_t)str * 4194304 + (size_t)(bg & 15) * 262144;
#pragma unroll
  for (int reg = 0; reg < 4; ++reg) {
    int row = w * 16 + lg * 4 + reg;
    int i = i0 + row;
    float seq = 2.f * (float)i / 1023.f - 1.f;
    float sv[16];
#pragma unroll
    for (int f = 0; f < 16; ++f)
      sv[f] = acc[f][reg] * 0.125f + cpb_lds(tabL, seq, vgl[f]);
    float m = sv[0];
#pragma unroll
    for (int f = 1; f < 16; ++f) m = fmaxf(m, sv[f]);
    m = fmaxf(m, __shfl_xor(m, 1, 64));
    m = fmaxf(m, __shfl_xor(m, 2, 64));
    m = fmaxf(m, __shfl_xor(m, 4, 64));
    m = fmaxf(m, __shfl_xor(m, 8, 64));
    float ev[16], sum = 0.f;
#pragma unroll
    for (int f = 0; f < 16; ++f) { ev[f] = expf(sv[f] - m); sum += ev[f]; }
    sum += __shfl_xor(sum, 1, 64);
    sum += __shfl_xor(sum, 2, 64);
    sum += __shfl_xor(sum, 4, 64);
    sum += __shfl_xor(sum, 8, 64);
    float inv = 1.f / sum;
    float* arow = aoutb + (size_t)i * 256;
#pragma unroll
    for (int f = 0; f < 16; ++f) {
      float p = ev[f] * inv;
      arow[f * 16 + lr] = p;
      Ps[row * 264 + f * 16 + lr] = __float2bfloat16(p);
    }
  }

  floatx4 oacc[4];
#pragma unroll
  for (int dt = 0; dt < 4; ++dt) oacc[dt] = {0.f, 0.f, 0.f, 0.f};
#pragma unroll
  for (int jc = 0; jc < 4; ++jc) {
    __syncthreads();
    {
      int r = t >> 2, c0 = (t & 3) * 16;
      const __hip_bfloat16* src = vt_g + ((size_t)bg * 64 + r) * 256 + jc * 64 + c0;
      *(float4*)&Ss[r * 72 + c0]     = *(const float4*)src;
      *(float4*)&Ss[r * 72 + c0 + 8] = *(const float4*)(src + 8);
    }
    __syncthreads();
    short8 pa0 = *(const short8*)&Ps[(w * 16 + lr) * 264 + jc * 64 + lg * 8];
    short8 pa1 = *(const short8*)&Ps[(w * 16 + lr) * 264 + jc * 64 + 32 + lg * 8];
#pragma unroll
    for (int dt = 0; dt < 4; ++dt) {
      short8 b0 = *(const short8*)&Ss[(dt * 16 + lr) * 72 + lg * 8];
      short8 b1 = *(const short8*)&Ss[(dt * 16 + lr) * 72 + 32 + lg * 8];
      oacc[dt] = __builtin_amdgcn_mfma_f32_16x16x32_bf16(pa0, b0, oacc[dt], 0, 0, 0);
      oacc[dt] = __builtin_amdgcn_mfma_f32_16x16x32_bf16(pa1, b1, oacc[dt], 0, 0, 0);
    }
  }
  {
    int b = (bg >> 3) & 1, g = bg & 7;
    __hip_bfloat16* ab = attout + ((size_t)(str * 2 + b) * 1024) * 512 + (size_t)g * 64;
#pragma unroll
    for (int dt = 0; dt < 4; ++dt)
#pragma unroll
      for (int reg = 0; reg < 4; ++reg) {
        int row = w * 16 + lg * 4 + reg;
        ab[(size_t)(i0 + row) * 512 + dt * 16 + lr] = __float2bfloat16(oacc[dt][reg]);
      }
  }
}

// ---------------- MFMA oproj + residual + fuse + meanz (merged) ----------------
// Block = 16 tokens (concat space), 4 waves, 128 blocks.
__global__ void __launch_bounds__(256, 2)
k_oproj_fuse(const __hip_bfloat16* __restrict__ aog, const __hip_bfloat16* __restrict__ owb,
             const float* __restrict__ ob,
             const float* __restrict__ x1_0, const float* __restrict__ x1_1,
             const __hip_bfloat16* __restrict__ fwb, const float* __restrict__ fb,
             const float* __restrict__ ng, const float* __restrict__ nb,
             const float* __restrict__ tfng, const float* __restrict__ tfnb,
             const float* __restrict__ mout, float* __restrict__ partial) {
  int tok0 = blockIdx.x * 16;
  int t = threadIdx.x;
  int w = t >> 6, l = t & 63;
  int lr = l & 15, lg = l >> 4;
  int nt0 = w * 2;

  __shared__ __align__(16) unsigned char smem[16 * 280 * 2];  // xos bf16 8960B / fs f32 8448B
  __shared__ float red[4][128];
  __hip_bfloat16* xos = (__hip_bfloat16*)smem;
  float* fs = (float*)smem;

  // phase 1: oproj MFMA per stream -> xos bf16 [16][280]
  for (int s = 0; s < 2; ++s) {
    const __hip_bfloat16* arow = aog + ((size_t)(s * 2048 + tok0 + lr)) * 512 + lg * 8;
    const __hip_bfloat16* wb0 = owb + (size_t)s * 65536 + (size_t)((nt0 + 0) * 16 + lr) * 512 + lg * 8;
    const __hip_bfloat16* wb1 = owb + (size_t)s * 65536 + (size_t)((nt0 + 1) * 16 + lr) * 512 + lg * 8;
    floatx4 acc0 = {0.f, 0.f, 0.f, 0.f}, acc1 = {0.f, 0.f, 0.f, 0.f};
#pragma unroll
    for (int ks = 0; ks < 16; ++ks) {
      short8 a  = *(const short8*)(arow + ks * 32);
      short8 b0 = *(const short8*)(wb0 + ks * 32);
      short8 b1 = *(const short8*)(wb1 + ks * 32);
      acc0 = __builtin_amdgcn_mfma_f32_16x16x32_bf16(a, b0, acc0, 0, 0, 0);
      acc1 = __builtin_amdgcn_mfma_f32_16x16x32_bf16(a, b1, acc1, 0, 0, 0);
    }
    const float* x1 = s ? x1_1 : x1_0;
    float bias0 = ob[s * 128 + nt0 * 16 + lr];
    float bias1 = ob[s * 128 + (nt0 + 1) * 16 + lr];
#pragma unroll
    for (int reg = 0; reg < 4; ++reg) {
      int row = lg * 4 + reg;
      size_t xi = (size_t)(tok0 + row) * 128;
      xos[row * 280 + s * 128 + nt0 * 16 + lr] =
          __float2bfloat16(acc0[reg] + x1[xi + nt0 * 16 + lr] + bias0);
      xos[row * 280 + s * 128 + (nt0 + 1) * 16 + lr] =
          __float2bfloat16(acc1[reg] + x1[xi + (nt0 + 1) * 16 + lr] + bias1);
    }
  }
  __syncthreads();

  // phase 2: fuse MFMA
  floatx4 f0 = {0.f, 0.f, 0.f, 0.f}, f1 = {0.f, 0.f, 0.f, 0.f};
  const __hip_bfloat16* fb0 = fwb + (size_t)((nt0 + 0) * 16 + lr) * 256 + lg * 8;
  const __hip_bfloat16* fb1 = fwb + (size_t)((nt0 + 1) * 16 + lr) * 256 + lg * 8;
#pragma unroll
  for (int ks = 0; ks < 8; ++ks) {
    short8 a  = *(const short8*)&xos[lr * 280 + ks * 32 + lg * 8];
    short8 b0 = *(const short8*)(fb0 + ks * 32);
    short8 b1 = *(const short8*)(fb1 + ks * 32);
    f0 = __builtin_amdgcn_mfma_f32_16x16x32_bf16(a, b0, f0, 0, 0, 0);
    f1 = __builtin_amdgcn_mfma_f32_16x16x32_bf16(a, b1, f1, 0, 0, 0);
  }
  __syncthreads();  // all xos reads done before fs overwrite

  // phase 3: fused f32 -> fs[16][132] (aliases xos)
  {
    float fbias0 = fb[nt0 * 16 + lr], fbias1 = fb[(nt0 + 1) * 16 + lr];
#pragma unroll
    for (int reg = 0; reg < 4; ++reg) {
      int row = lg * 4 + reg;
      fs[row * 132 + w * 32 + lr]      = f0[reg] + fbias0;
      fs[row * 132 + w * 32 + 16 + lr] = f1[reg] + fbias1;
    }
  }
  __syncthreads();

  // phase 4: double-LN + mout for i=0,1; wave per token (4 rounds), partial sums
  int b = tok0 >> 10, chunk = (tok0 & 1023) >> 4;
  float g1a = ng[l], b1a = nb[l], g1b = ng[l + 64], b1b = nb[l + 64];
  float mo0a = mout[b * 128 + l], mo0b = mout[b * 128 + l + 64];
  float mo1a = mout[(2 + b) * 128 + l], mo1b = mout[(2 + b) * 128 + l + 64];
  float g20a = tfng[l], b20a = tfnb[l], g20b = tfng[l + 64], b20b = tfnb[l + 64];
  float g21a = tfng[128 + l], b21a = tfnb[128 + l];
  float g21b = tfng[192 + l], b21b = tfnb[192 + l];
  float acc0a = 0.f, acc0b = 0.f, acc1a = 0.f, acc1b = 0.f;
#pragma unroll
  for (int it = 0; it < 4; ++it) {
    int tok = it * 4 + w;
    float xa = fs[tok * 132 + l], xb = fs[tok * 132 + l + 64];
    float m1 = wave_sum(xa + xb) * (1.f / kC);
    float da = xa - m1, db = xb - m1;
    float v1 = wave_sum(da * da + db * db) * (1.f / kC);
    float r1 = rsqrtf(v1 + 1e-5f);
    float ba = da * r1 * g1a + b1a, bb = db * r1 * g1b + b1b;
    // i = 0
    {
      float za = ba + mo0a, zb = bb + mo0b;
      float m2 = wave_sum(za + zb) * (1.f / kC);
      float ea = za - m2, eb = zb - m2;
      float v2 = wave_sum(ea * ea + eb * eb) * (1.f / kC);
      float r2 = rsqrtf(v2 + 1e-5f);
      acc0a += ea * r2 * g20a + b20a;
      acc0b += eb * r2 * g20b + b20b;
    }
    // i = 1
    {
      float za = ba + mo1a, zb = bb + mo1b;
      float m2 = wave_sum(za + zb) * (1.f / kC);
      float ea = za - m2, eb = zb - m2;
      float v2 = wave_sum(ea * ea + eb * eb) * (1.f / kC);
      float r2 = rsqrtf(v2 + 1e-5f);
      acc1a += ea * r2 * g21a + b21a;
      acc1b += eb * r2 * g21b + b21b;
    }
  }
  red[w][l] = acc0a; red[w][l + 64] = acc0b;
  __syncthreads();
  if (w == 0) {
    float* pr = partial + ((size_t)(b)*64 + chunk) * kC;
    pr[l]      = red[0][l] + red[1][l] + red[2][l] + red[3][l];
    pr[l + 64] = red[0][l + 64] + red[1][l + 64] + red[2][l + 64] + red[3][l + 64];
  }
  __syncthreads();
  red[w][l] = acc1a; red[w][l + 64] = acc1b;
  __syncthreads();
  if (w == 0) {
    float* pr = partial + ((size_t)(2 + b) * 64 + chunk) * kC;
    pr[l]      = red[0][l] + red[1][l] + red[2][l] + red[3][l];
    pr[l + 64] = red[0][l + 64] + red[1][l + 64] + red[2][l + 64] + red[3][l + 64];
  }
}

__global__ void k_final(const float* __restrict__ partial, const float* __restrict__ pw,
                        const float* __restrict__ pb, float* __restrict__ out) {
  int ib = blockIdx.x;
  int i = ib >> 1, t = threadIdx.x;
  int c = t & 127, half = t >> 7;
  float a = 0.f;
  for (int ch = half * 32; ch < half * 32 + 32; ++ch)
    a += partial[((size_t)ib * 64 + ch) * kC + c];
  __shared__ float s[256];
  s[half * 128 + c] = a;
  __syncthreads();
  if (t < 128) s[t] = (s[t] + s[128 + t]) * (1.f / (float)kN);
  __syncthreads();
  if (t < 128) {
    float a0 = 0.f;
    const float* wr = pw + (size_t)i * kC * kC + (size_t)t * kC;
    for (int cc = 0; cc < 128; ++cc) a0 += s[cc] * wr[cc];
    out[ib * 128 + t] = tanhf(pb[i * kC + t] + a0);
  }
}

extern "C" void kernel_launch(void* const* d_in, const int* in_sizes, int n_in,
                              void* d_out, int out_size, void* d_ws, size_t ws_size,
                              hipStream_t stream) {
  const float* x1_0   = (const float*)d_in[0];
  const float* x1_1   = (const float*)d_in[1];
  const float* x2     = (const float*)d_in[2];
  const float* norm_g = (const float*)d_in[3];
  const float* norm_b = (const float*)d_in[4];
  const float* d_qw   = (const float*)d_in[5];
  const float* d_kw   = (const float*)d_in[6];
  const float* d_vw   = (const float*)d_in[7];
  const float* d_ow   = (const float*)d_in[8];
  const float* d_ob   = (const float*)d_in[9];
  const float* d_o1w  = (const float*)d_in[10];
  const float* d_o1b  = (const float*)d_in[11];
  const float* d_o2w  = (const float*)d_in[12];
  const float* c_w1   = (const float*)d_in[13];
  const float* c_b1   = (const float*)d_in[14];
  const float* c_w2   = (const float*)d_in[15];
  const float* c_b2   = (const float*)d_in[16];
  const float* c_w3   = (const float*)d_in[17];
  const float* c_b3   = (const float*)d_in[18];
  const float* fus_w  = (const float*)d_in[19];
  const float* fus_b  = (const float*)d_in[20];
  const float* tf_ng  = (const float*)d_in[21];
  const float* tf_nb  = (const float*)d_in[22];
  const float* tf_inw = (const float*)d_in[23];
  const float* tf_inb = (const float*)d_in[24];
  const float* tf_ow  = (const float*)d_in[25];
  const float* tf_ob  = (const float*)d_in[26];
  const float* tf_pw  = (const float*)d_in[27];
  const float* tf_pb  = (const float*)d_in[28];

  float* ws = (float*)d_ws;
  float* out = (float*)d_out;
  float* lnkv = ws + W_LNKV;
  float* lnq1 = ws + W_LNQ1; float* lnq2 = ws + W_LNQ2;
  __hip_bfloat16* qb  = (__hip_bfloat16*)(ws + W_Q);
  __hip_bfloat16* kb  = (__hip_bfloat16*)(ws + W_K);
  __hip_bfloat16* vtb = (__hip_bfloat16*)(ws + W_VT);
  float* vgsw = ws + W_VGS;
  __hip_bfloat16* aob = (__hip_bfloat16*)(ws + W_AO);
  float* tab = ws + W_TAB;
  float* moutp = ws + W_MOUT; float* partp = ws + W_PART;
  __hip_bfloat16* owb = (__hip_bfloat16*)(ws + W_OWB);
  __hip_bfloat16* fwb = (__hip_bfloat16*)(ws + W_FWB);

  // output: f1(256) | f2(256) | a1(2*8*1024*256) | a2(same), all f32
  float* aoutb = out + 512;

  k_prep<<<2198, 256, 0, stream>>>(d_ow, fus_w, owb, fwb,
                                   x1_0, x1_1, x2, lnq1, lnq2, lnkv, norm_g, norm_b,
                                   c_w1, c_b1, c_w2, c_b2, c_w3, c_b3, tab,
                                   tf_ng, tf_nb, tf_inw, tf_inb, tf_ow, tf_ob, moutp);
  k_qoff<<<2560, 256, 0, stream>>>(lnq1, lnq2, d_qw, d_o1w, d_o1b, d_o2w, qb, vgsw);
  k_sample_kv<<<2048, 256, 0, stream>>>(lnkv, vgsw, d_kw, d_vw, kb, vtb);
  k_attn<<<512, 256, 0, stream>>>(qb, kb, vtb, vgsw, tab, aoutb, aob);
  k_oproj_fuse<<<128, 256, 0, stream>>>(aob, owb, d_ob, x1_0, x1_1, fwb, fus_b,
                                        norm_g, norm_b, tf_ng, tf_nb, moutp, partp);
  k_final<<<4, 256, 0, stream>>>(partp, tf_pw, tf_pb, out);

  (void)in_sizes; (void)n_in; (void)out_size; (void)ws_size;
}

// Round 13
// 83.292 us; speedup vs baseline: 3.3636x; 1.0639x over previous
//
#include <hip/hip_runtime.h>
#include <hip/hip_bf16.h>

// UniTeacherEncoder v13: k_attn restructured to single-shot K/V staging.
// v12 post-mortem: LDS CPB table changed nothing -> block SERIAL latency is the
// limiter (all 512 blocks co-resident; 18 barriers, 9 global-staging waits).
// v13: stage K whole (32KB) and Vt whole (33KB); 3 barriers total; V loads
// issued to registers BEFORE softmax (latency hides under it); __expf.
// Fragment convention HW-verified (v10..v12 pass):
//   A: row=lane&15, k=(lane>>4)*8+i ; B: col=lane&15, k=(lane>>4)*8+i
//   C/D: col=lane&15, row=(lane>>4)*4+reg
// __launch_bounds__(256,2) on hot kernels (only spill-free allocator config).

namespace {

constexpr int kN  = 1024;
constexpr int kC  = 128;
constexpr int kG  = 8;
constexpr int kDH = 64;
constexpr int kND = 256;

constexpr int   kNT    = 2048;      // CPB table intervals (PWL -> err ~5e-8)
constexpr float kRLO   = -2.0625f;  // rel in [-2.032, 2.032] guaranteed (|off|<=4)
constexpr float kRSPAN = 4.125f;

// workspace layout (float offsets)
constexpr size_t W_LNKV = 0;          // 2048 x 128 f32
constexpr size_t W_LNQ1 = 262144;
constexpr size_t W_LNQ2 = 524288;
constexpr size_t W_Q    = 786432;     // bf16 [32 bg][1024 r][64 d] row-major
constexpr size_t W_K    = 1835008;    // bf16 [32 bg][256 j][64 d] row-major
constexpr size_t W_VT   = 2097152;    // bf16 [32 bg][64 d][256 j] (transposed V)
constexpr size_t W_VGS  = 2359296;    // f32 [32][256]
constexpr size_t W_AO   = 2367488;    // bf16 [2 str][2048 tok][512 c]
constexpr size_t W_TAB  = 5251072;    // f32 2 x 2049
constexpr size_t W_MOUT = 5283844;    // 4 x 128
constexpr size_t W_PART = 5284356;    // 4 x 64 x 128
constexpr size_t W_OWB  = 5317124;    // bf16 2x128x512
constexpr size_t W_FWB  = 5382660;    // bf16 128x256

} // namespace

typedef __attribute__((ext_vector_type(8))) short short8;
typedef __attribute__((ext_vector_type(4))) float floatx4;

__device__ __forceinline__ float wave_sum(float v) {
#pragma unroll
  for (int o = 32; o > 0; o >>= 1) v += __shfl_xor(v, o, 64);
  return v;
}
__device__ __forceinline__ float cpb_bias(const float* __restrict__ tabs,
                                          float seq, float vg) {
  float rel = seq - vg;
  float ft = (rel - kRLO) * ((float)kNT / kRSPAN);
  ft = fminf(fmaxf(ft, 0.f), (float)kNT - 0.001f);
  int ix = (int)ft;
  float fw = ft - (float)ix;
  return tabs[ix] * (1.f - fw) + tabs[ix + 1] * fw;
}

// ---------------- k_prep: weight bf16 cvt + LN x3 + CPB table + mout ----------------
__global__ void k_prep(const float* __restrict__ ow, const float* __restrict__ fw,
                       __hip_bfloat16* __restrict__ owb, __hip_bfloat16* __restrict__ fwb,
                       const float* __restrict__ x1_0, const float* __restrict__ x1_1,
                       const float* __restrict__ x2, float* __restrict__ lnq1,
                       float* __restrict__ lnq2, float* __restrict__ lnkv,
                       const float* __restrict__ ng, const float* __restrict__ nb,
                       const float* __restrict__ cw1, const float* __restrict__ cb1,
                       const float* __restrict__ cw2, const float* __restrict__ cb2,
                       const float* __restrict__ cw3, const float* __restrict__ cb3,
                       float* __restrict__ tab,
                       const float* __restrict__ tfng, const float* __restrict__ tfnb,
                       const float* __restrict__ inw, const float* __restrict__ inb,
                       const float* __restrict__ tow, const float* __restrict__ tob,
                       float* __restrict__ mout) {
  int bx = blockIdx.x;
  int t = threadIdx.x;
  if (bx < 640) {
    int id = bx * 256 + t;
    if (id < 131072) owb[id] = __float2bfloat16(ow[id]);
    else fwb[id - 131072] = __float2bfloat16(fw[id - 131072]);
  } else if (bx < 2176) {
    int w = t >> 6, lane = t & 63;
    int gr = (bx - 640) * 4 + w;
    int sel = gr >> 11, row = gr & 2047;
    const float* in = (sel == 0) ? x1_0 : (sel == 1) ? x1_1 : x2;
    float* out = (sel == 0) ? lnq1 : (sel == 1) ? lnq2 : lnkv;
    const float* xr = in + (size_t)row * kC;
    float xa = xr[lane], xb = xr[lane + 64];
    float m = wave_sum(xa + xb) * (1.f / kC);
    float da = xa - m, db = xb - m;
    float v = wave_sum(da * da + db * db) * (1.f / kC);
    float r = rsqrtf(v + 1e-5f);
    float* orow = out + (size_t)row * kC;
    orow[lane]      = da * r * ng[lane] + nb[lane];
    orow[lane + 64] = db * r * ng[lane + 64] + nb[lane + 64];
  } else if (bx < 2194) {
    int rel = bx - 2176;
    int idx = rel / 9, bb = rel - idx * 9;
    int tt = bb * 256 + t;
    if (tt <= kNT) {
      float rel_ = kRLO + (kRSPAN / (float)kNT) * (float)tt;
      float u = (rel_ >= 0.f ? 1.f : -1.f) * log1pf(fabsf(rel_));
      const float* W1 = cw1 + idx * 32; const float* B1 = cb1 + idx * 32;
      const float* W2 = cw2 + idx * 1024; const float* B2 = cb2 + idx * 32;
      const float* W3 = cw3 + idx * 32; const float* B3 = cb3 + idx;
      float h1[32];
#pragma unroll
      for (int m = 0; m < 32; ++m) h1[m] = fmaxf(0.f, u * W1[m] + B1[m]);
      float o = B3[0];
      for (int m = 0; m < 32; ++m) {
        float a = B2[m];
#pragma unroll
        for (int k = 0; k < 32; ++k) a += h1[k] * W2[k * 32 + m];
        o += fmaxf(a, 0.f) * W3[m];
      }
      tab[(size_t)idx * (kNT + 1) + tt] = o;
    }
  } else {
    int rel = bx - 2194;
    int i = rel >> 1, b = rel & 1;
    bool act = t < 128;
    __shared__ float red[2];
    __shared__ float s1[128];
    __shared__ float s2[128];
    const float* xs = (i ? x1_1 : x1_0) + (size_t)b * kN * kC;
    float x = act ? xs[t] : 0.f;
    float s = wave_sum(x);
    if (act && (t & 63) == 0) red[t >> 6] = s;
    __syncthreads();
    float m1 = (red[0] + red[1]) * (1.f / kC);
    __syncthreads();
    float d1 = x - m1;
    float ss = wave_sum(act ? d1 * d1 : 0.f);
    if (act && (t & 63) == 0) red[t >> 6] = ss;
    __syncthreads();
    float v1 = (red[0] + red[1]) * (1.f / kC);
    __syncthreads();
    float t0 = act ? d1 * rsqrtf(v1 + 1e-5f) * ng[t] + nb[t] : 0.f;
    s = wave_sum(t0);
    if (act && (t & 63) == 0) red[t >> 6] = s;
    __syncthreads();
    float m2 = (red[0] + red[1]) * (1.f / kC);
    __syncthreads();
    float d2 = t0 - m2;
    ss = wave_sum(act ? d2 * d2 : 0.f);
    if (act && (t & 63) == 0) red[t >> 6] = ss;
    __syncthreads();
    float v2 = (red[0] + red[1]) * (1.f / kC);
    if (act) s1[t] = d2 * rsqrtf(v2 + 1e-5f) * tfng[i * kC + t] + tfnb[i * kC + t];
    __syncthreads();
    if (act) {
      float a0 = 0.f;
      const float* wr = inw + (size_t)i * 384 * kC + (size_t)(256 + t) * kC;
      for (int c = 0; c < 128; ++c) a0 += s1[c] * wr[c];
      s2[t] = inb[i * 384 + 256 + t] + a0;
    }
    __syncthreads();
    if (act) {
      float a0 = 0.f;
      const float* wr2 = tow + (size_t)i * kC * kC + (size_t)t * kC;
      for (int c = 0; c < 128; ++c) a0 += s2[c] * wr2[c];
      mout[rel * kC + t] = tob[i * kC + t] + a0;
    }
  }
}

// ---------------- k_qoff: qproj ([0,512)) + offsets ([512,2560)) ----------------
__global__ void k_qoff(const float* __restrict__ lnq1, const float* __restrict__ lnq2,
                       const float* __restrict__ qw, const float* __restrict__ o1w,
                       const float* __restrict__ o1b, const float* __restrict__ o2w,
                       __hip_bfloat16* __restrict__ qout, float* __restrict__ vgs) {
  int bx = blockIdx.x;
  if (bx < 512) {
    int bg = bx >> 4, r0 = (bx & 15) * 64;
    int str = bg >> 4, b = (bg >> 3) & 1, g = bg & 7;
    int rl = threadIdx.x & 63, dq = threadIdx.x >> 6;
    const float* lnq = str ? lnq2 : lnq1;
    const float* xr = lnq + ((size_t)(b * kN + r0 + rl)) * kC + g * 16;
    float4 x0 = *(const float4*)(xr + 0);
    float4 x1 = *(const float4*)(xr + 4);
    float4 x2 = *(const float4*)(xr + 8);
    float4 x3 = *(const float4*)(xr + 12);
    const float* wqb = qw + (size_t)str * 8192 + (size_t)g * 1024;
    __hip_bfloat16* qrow = qout + ((size_t)bg * 1024 + r0 + rl) * 64 + dq * 16;
#pragma unroll 4
    for (int dd = 0; dd < 16; ++dd) {
      int d = dq * 16 + dd;
      const float* wq = wqb + d * 16;
      float4 w0 = *(const float4*)(wq + 0);
      float4 w1 = *(const float4*)(wq + 4);
      float4 w2 = *(const float4*)(wq + 8);
      float4 w3 = *(const float4*)(wq + 12);
      float q = x0.x * w0.x + x0.y * w0.y + x0.z * w0.z + x0.w * w0.w
              + x1.x * w1.x + x1.y * w1.y + x1.z * w1.z + x1.w * w1.w
              + x2.x * w2.x + x2.y * w2.y + x2.z * w2.z + x2.w * w2.w
              + x3.x * w3.x + x3.y * w3.y + x3.z * w3.z + x3.w * w3.w;
      qrow[dd] = __float2bfloat16(q);
    }
  } else {
    int bxo = bx - 512;
    int w = threadIdx.x >> 6, lane = threadIdx.x & 63;
    int bg = bxo >> 6, j = ((bxo & 63) << 2) + w;
    int str = bg >> 4, b = (bg >> 3) & 1, g = bg & 7;
    const float* lnq = str ? lnq2 : lnq1;
    __shared__ float xr[4][96];
    int base = j * 4 - 1;
#pragma unroll
    for (int rep = 0; rep < 2; ++rep) {
      int idx = lane + rep * 64;
      if (idx < 96) {
        int r = idx >> 4, c = idx & 15, n = base + r;
        xr[w][idx] = (n >= 0 && n < kN)
                         ? lnq[((size_t)(b * kN + n)) * kC + g * 16 + c] : 0.f;
      }
    }
    const float* wq = qw + (size_t)str * 8192 + (size_t)(g * kDH + lane) * 16;
    float acc = o1b[str * 64 + lane];
#pragma unroll
    for (int k2 = 0; k2 < 6; ++k2) {
      float qv = 0.f;
#pragma unroll
      for (int c = 0; c < 16; ++c) qv += xr[w][k2 * 16 + c] * wq[c];
      acc += qv * o1w[str * 384 + lane * 6 + k2];
    }
    float ge = 0.5f * acc * (1.f + erff(acc * 0.70710678118654752440f));
    float s = wave_sum(ge * o2w[str * 64 + lane]);
    if (lane == 0)
      vgs[bg * kND + j] = 2.f * ((float)j + tanhf(s) * 4.0f) / 255.f - 1.f;
  }
}

// ---------------- grid_sample + k/v projections ----------------
__global__ void k_sample_kv(const float* __restrict__ lnkv, const float* __restrict__ vgs,
                            const float* __restrict__ kw, const float* __restrict__ vw,
                            __hip_bfloat16* __restrict__ kout,
                            __hip_bfloat16* __restrict__ vtout) {
  int w = threadIdx.x >> 6, lane = threadIdx.x & 63;
  int bg = blockIdx.x >> 6, j = ((blockIdx.x & 63) << 2) + w;
  int str = bg >> 4, b = (bg >> 3) & 1, g = bg & 7;
  __shared__ float sc[4][16];
  if (lane < 16) {
    float gr = vgs[bg * kND + j];
    float x = ((gr + 1.f) * 1024.f - 1.f) * 0.5f;
    float x0f = floorf(x);
    float w1 = x - x0f;
    int x0 = (int)x0f, x1 = x0 + 1;
    const float* src = lnkv + (size_t)b * kN * kC + g * 16 + lane;
    float v0 = (x0 >= 0 && x0 < 1024) ? src[(size_t)x0 * kC] : 0.f;
    float v1 = (x1 >= 0 && x1 < 1024) ? src[(size_t)x1 * kC] : 0.f;
    sc[w][lane] = v0 * (1.f - w1) + v1 * w1;
  }
  const float* kwr = kw + (size_t)str * 8192 + (size_t)(g * kDH + lane) * 16;
  const float* vwr = vw + (size_t)str * 8192 + (size_t)(g * kDH + lane) * 16;
  float ka = 0.f, va = 0.f;
#pragma unroll
  for (int c = 0; c < 16; ++c) { ka += sc[w][c] * kwr[c]; va += sc[w][c] * vwr[c]; }
  kout[((size_t)bg * 256 + j) * 64 + lane] = __float2bfloat16(ka);      // K[j][d]
  vtout[((size_t)bg * 64 + lane) * 256 + j] = __float2bfloat16(va);     // Vt[d][j]
}

// ---------------- MFMA flash attention, single-shot staging ----------------
// Block = (bg, 64-row tile), 512 blocks, 4 waves. LDS 79.9 KB -> 2 blocks/CU.
// Phases: {Q+K stage, bar} -> 32 QK MFMA -> bar -> V->regs issued -> softmax
// (overlaps V flight) -> V regs->LDS -> bar -> 32 PV MFMA -> stores.
__global__ void __launch_bounds__(256, 2)
k_attn(const __hip_bfloat16* __restrict__ q_g, const __hip_bfloat16* __restrict__ k_g,
       const __hip_bfloat16* __restrict__ vt_g, const float* __restrict__ vgs,
       const float* __restrict__ tab, float* __restrict__ aout,
       __hip_bfloat16* __restrict__ attout) {
  int bg = blockIdx.x >> 4, tile = blockIdx.x & 15;
  int str = bg >> 4;
  int i0 = tile * 64;
  int t = threadIdx.x;
  int w = t >> 6, l = t & 63;
  int lr = l & 15, lg = l >> 4;

  __shared__ __align__(16) __hip_bfloat16 Qs[64 * 72];    // 9216 B
  __shared__ __align__(16) __hip_bfloat16 KVs[256 * 72];  // 36864 B (K whole / Vt [64][264])
  __shared__ __align__(16) __hip_bfloat16 Ps[64 * 264];   // 33792 B

  const float* tabs = tab + str * (kNT + 1);

  // ---- stage Q (8 KB) + all K (32 KB), coalesced 1KB/instr ----
  {
    const __hip_bfloat16* qflat = q_g + ((size_t)bg * 1024 + i0) * 64;
#pragma unroll
    for (int i2 = 0; i2 < 2; ++i2) {
      int e = i2 * 2048 + t * 8;
      int r = e >> 6, c = e & 63;
      *(float4*)&Qs[r * 72 + c] = *(const float4*)(qflat + e);
    }
    const __hip_bfloat16* kflat = k_g + (size_t)bg * 256 * 64;
#pragma unroll
    for (int i2 = 0; i2 < 8; ++i2) {
      int e = i2 * 2048 + t * 8;
      int r = e >> 6, c = e & 63;
      *(float4*)&KVs[r * 72 + c] = *(const float4*)(kflat + e);
    }
  }
  __syncthreads();

  short8 a0 = *(const short8*)&Qs[(w * 16 + lr) * 72 + lg * 8];
  short8 a1 = *(const short8*)&Qs[(w * 16 + lr) * 72 + 32 + lg * 8];

  // ---- QK^T: 16 col-tiles x 2 MFMA, no barriers ----
  floatx4 acc[16];
#pragma unroll
  for (int f = 0; f < 16; ++f) acc[f] = {0.f, 0.f, 0.f, 0.f};
#pragma unroll
  for (int ct = 0; ct < 16; ++ct) {
    short8 b0 = *(const short8*)&KVs[(ct * 16 + lr) * 72 + lg * 8];
    short8 b1 = *(const short8*)&KVs[(ct * 16 + lr) * 72 + 32 + lg * 8];
    acc[ct] = __builtin_amdgcn_mfma_f32_16x16x32_bf16(a0, b0, acc[ct], 0, 0, 0);
    acc[ct] = __builtin_amdgcn_mfma_f32_16x16x32_bf16(a1, b1, acc[ct], 0, 0, 0);
  }
  __syncthreads();  // all waves done reading K from KVs

  // ---- issue V loads to registers (latency hides under softmax) ----
  float4 vr0, vr1, vr2, vr3, vr4, vr5, vr6, vr7;
  {
    const __hip_bfloat16* vflat = vt_g + (size_t)bg * 64 * 256;
    vr0 = *(const float4*)(vflat + 0 * 2048 + t * 8);
    vr1 = *(const float4*)(vflat + 1 * 2048 + t * 8);
    vr2 = *(const float4*)(vflat + 2 * 2048 + t * 8);
    vr3 = *(const float4*)(vflat + 3 * 2048 + t * 8);
    vr4 = *(const float4*)(vflat + 4 * 2048 + t * 8);
    vr5 = *(const float4*)(vflat + 5 * 2048 + t * 8);
    vr6 = *(const float4*)(vflat + 6 * 2048 + t * 8);
    vr7 = *(const float4*)(vflat + 7 * 2048 + t * 8);
  }

  // ---- bias + softmax (fast exp); write attn f32 + P bf16 ----
  float vgl[16];
#pragma unroll
  for (int f = 0; f < 16; ++f) vgl[f] = vgs[bg * 256 + f * 16 + lr];
  float* aoutb = aout + (size_t)str * 4194304 + (size_t)(bg & 15) * 262144;
#pragma unroll
  for (int reg = 0; reg < 4; ++reg) {
    int row = w * 16 + lg * 4 + reg;
    int i = i0 + row;
    float seq = 2.f * (float)i / 1023.f - 1.f;
    float sv[16];
#pragma unroll
    for (int f = 0; f < 16; ++f)
      sv[f] = acc[f][reg] * 0.125f + cpb_bias(tabs, seq, vgl[f]);
    float m = sv[0];
#pragma unroll
    for (int f = 1; f < 16; ++f) m = fmaxf(m, sv[f]);
    m = fmaxf(m, __shfl_xor(m, 1, 64));
    m = fmaxf(m, __shfl_xor(m, 2, 64));
    m = fmaxf(m, __shfl_xor(m, 4, 64));
    m = fmaxf(m, __shfl_xor(m, 8, 64));
    float ev[16], sum = 0.f;
#pragma unroll
    for (int f = 0; f < 16; ++f) { ev[f] = __expf(sv[f] - m); sum += ev[f]; }
    sum += __shfl_xor(sum, 1, 64);
    sum += __shfl_xor(sum, 2, 64);
    sum += __shfl_xor(sum, 4, 64);
    sum += __shfl_xor(sum, 8, 64);
    float inv = 1.f / sum;
    float* arow = aoutb + (size_t)i * 256;
#pragma unroll
    for (int f = 0; f < 16; ++f) {
      float p = ev[f] * inv;
      arow[f * 16 + lr] = p;
      Ps[row * 264 + f * 16 + lr] = __float2bfloat16(p);
    }
  }

  // ---- V regs -> LDS as Vt [64][264], barrier, PV ----
  {
    int e0 = t * 8;
#pragma unroll
    for (int i2 = 0; i2 < 8; ++i2) {
      int e = i2 * 2048 + e0;
      int r = e >> 8, c = e & 255;
      float4 v = (i2 == 0) ? vr0 : (i2 == 1) ? vr1 : (i2 == 2) ? vr2 :
                 (i2 == 3) ? vr3 : (i2 == 4) ? vr4 : (i2 == 5) ? vr5 :
                 (i2 == 6) ? vr6 : vr7;
      *(float4*)&KVs[r * 264 + c] = v;
    }
  }
  __syncthreads();

  floatx4 oacc[4];
#pragma unroll
  for (int dt = 0; dt < 4; ++dt) oacc[dt] = {0.f, 0.f, 0.f, 0.f};
#pragma unroll
  for (int ks = 0; ks < 8; ++ks) {
    short8 pa = *(const short8*)&Ps[(w * 16 + lr) * 264 + ks * 32 + lg * 8];
#pragma unroll
    for (int dt = 0; dt < 4; ++dt) {
      short8 b = *(const short8*)&KVs[(dt * 16 + lr) * 264 + ks * 32 + lg * 8];
      oacc[dt] = __builtin_amdgcn_mfma_f32_16x16x32_bf16(pa, b, oacc[dt], 0, 0, 0);
    }
  }
  {
    int b = (bg >> 3) & 1, g = bg & 7;
    __hip_bfloat16* ab = attout + ((size_t)(str * 2 + b) * 1024) * 512 + (size_t)g * 64;
#pragma unroll
    for (int dt = 0; dt < 4; ++dt)
#pragma unroll
      for (int reg = 0; reg < 4; ++reg) {
        int row = w * 16 + lg * 4 + reg;
        ab[(size_t)(i0 + row) * 512 + dt * 16 + lr] = __float2bfloat16(oacc[dt][reg]);
      }
  }
}

// ---------------- MFMA oproj + residual + fuse + meanz (merged) ----------------
__global__ void __launch_bounds__(256, 2)
k_oproj_fuse(const __hip_bfloat16* __restrict__ aog, const __hip_bfloat16* __restrict__ owb,
             const float* __restrict__ ob,
             const float* __restrict__ x1_0, const float* __restrict__ x1_1,
             const __hip_bfloat16* __restrict__ fwb, const float* __restrict__ fb,
             const float* __restrict__ ng, const float* __restrict__ nb,
             const float* __restrict__ tfng, const float* __restrict__ tfnb,
             const float* __restrict__ mout, float* __restrict__ partial) {
  int tok0 = blockIdx.x * 16;
  int t = threadIdx.x;
  int w = t >> 6, l = t & 63;
  int lr = l & 15, lg = l >> 4;
  int nt0 = w * 2;

  __shared__ __align__(16) unsigned char smem[16 * 280 * 2];
  __shared__ float red[4][128];
  __hip_bfloat16* xos = (__hip_bfloat16*)smem;
  float* fs = (float*)smem;

  for (int s = 0; s < 2; ++s) {
    const __hip_bfloat16* arow = aog + ((size_t)(s * 2048 + tok0 + lr)) * 512 + lg * 8;
    const __hip_bfloat16* wb0 = owb + (size_t)s * 65536 + (size_t)((nt0 + 0) * 16 + lr) * 512 + lg * 8;
    const __hip_bfloat16* wb1 = owb + (size_t)s * 65536 + (size_t)((nt0 + 1) * 16 + lr) * 512 + lg * 8;
    floatx4 acc0 = {0.f, 0.f, 0.f, 0.f}, acc1 = {0.f, 0.f, 0.f, 0.f};
#pragma unroll
    for (int ks = 0; ks < 16; ++ks) {
      short8 a  = *(const short8*)(arow + ks * 32);
      short8 b0 = *(const short8*)(wb0 + ks * 32);
      short8 b1 = *(const short8*)(wb1 + ks * 32);
      acc0 = __builtin_amdgcn_mfma_f32_16x16x32_bf16(a, b0, acc0, 0, 0, 0);
      acc1 = __builtin_amdgcn_mfma_f32_16x16x32_bf16(a, b1, acc1, 0, 0, 0);
    }
    const float* x1 = s ? x1_1 : x1_0;
    float bias0 = ob[s * 128 + nt0 * 16 + lr];
    float bias1 = ob[s * 128 + (nt0 + 1) * 16 + lr];
#pragma unroll
    for (int reg = 0; reg < 4; ++reg) {
      int row = lg * 4 + reg;
      size_t xi = (size_t)(tok0 + row) * 128;
      xos[row * 280 + s * 128 + nt0 * 16 + lr] =
          __float2bfloat16(acc0[reg] + x1[xi + nt0 * 16 + lr] + bias0);
      xos[row * 280 + s * 128 + (nt0 + 1) * 16 + lr] =
          __float2bfloat16(acc1[reg] + x1[xi + (nt0 + 1) * 16 + lr] + bias1);
    }
  }
  __syncthreads();

  floatx4 f0 = {0.f, 0.f, 0.f, 0.f}, f1 = {0.f, 0.f, 0.f, 0.f};
  const __hip_bfloat16* fb0 = fwb + (size_t)((nt0 + 0) * 16 + lr) * 256 + lg * 8;
  const __hip_bfloat16* fb1 = fwb + (size_t)((nt0 + 1) * 16 + lr) * 256 + lg * 8;
#pragma unroll
  for (int ks = 0; ks < 8; ++ks) {
    short8 a  = *(const short8*)&xos[lr * 280 + ks * 32 + lg * 8];
    short8 b0 = *(const short8*)(fb0 + ks * 32);
    short8 b1 = *(const short8*)(fb1 + ks * 32);
    f0 = __builtin_amdgcn_mfma_f32_16x16x32_bf16(a, b0, f0, 0, 0, 0);
    f1 = __builtin_amdgcn_mfma_f32_16x16x32_bf16(a, b1, f1, 0, 0, 0);
  }
  __syncthreads();

  {
    float fbias0 = fb[nt0 * 16 + lr], fbias1 = fb[(nt0 + 1) * 16 + lr];
#pragma unroll
    for (int reg = 0; reg < 4; ++reg) {
      int row = lg * 4 + reg;
      fs[row * 132 + w * 32 + lr]      = f0[reg] + fbias0;
      fs[row * 132 + w * 32 + 16 + lr] = f1[reg] + fbias1;
    }
  }
  __syncthreads();

  int b = tok0 >> 10, chunk = (tok0 & 1023) >> 4;
  float g1a = ng[l], b1a = nb[l], g1b = ng[l + 64], b1b = nb[l + 64];
  float mo0a = mout[b * 128 + l], mo0b = mout[b * 128 + l + 64];
  float mo1a = mout[(2 + b) * 128 + l], mo1b = mout[(2 + b) * 128 + l + 64];
  float g20a = tfng[l], b20a = tfnb[l], g20b = tfng[l + 64], b20b = tfnb[l + 64];
  float g21a = tfng[128 + l], b21a = tfnb[128 + l];
  float g21b = tfng[192 + l], b21b = tfnb[192 + l];
  float acc0a = 0.f, acc0b = 0.f, acc1a = 0.f, acc1b = 0.f;
#pragma unroll
  for (int it = 0; it < 4; ++it) {
    int tok = it * 4 + w;
    float xa = fs[tok * 132 + l], xb = fs[tok * 132 + l + 64];
    float m1 = wave_sum(xa + xb) * (1.f / kC);
    float da = xa - m1, db = xb - m1;
    float v1 = wave_sum(da * da + db * db) * (1.f / kC);
    float r1 = rsqrtf(v1 + 1e-5f);
    float ba = da * r1 * g1a + b1a, bb = db * r1 * g1b + b1b;
    {
      float za = ba + mo0a, zb = bb + mo0b;
      float m2 = wave_sum(za + zb) * (1.f / kC);
      float ea = za - m2, eb = zb - m2;
      float v2 = wave_sum(ea * ea + eb * eb) * (1.f / kC);
      float r2 = rsqrtf(v2 + 1e-5f);
      acc0a += ea * r2 * g20a + b20a;
      acc0b += eb * r2 * g20b + b20b;
    }
    {
      float za = ba + mo1a, zb = bb + mo1b;
      float m2 = wave_sum(za + zb) * (1.f / kC);
      float ea = za - m2, eb = zb - m2;
      float v2 = wave_sum(ea * ea + eb * eb) * (1.f / kC);
      float r2 = rsqrtf(v2 + 1e-5f);
      acc1a += ea * r2 * g21a + b21a;
      acc1b += eb * r2 * g21b + b21b;
    }
  }
  red[w][l] = acc0a; red[w][l + 64] = acc0b;
  __syncthreads();
  if (w == 0) {
    float* pr = partial + ((size_t)(b)*64 + chunk) * kC;
    pr[l]      = red[0][l] + red[1][l] + red[2][l] + red[3][l];
    pr[l + 64] = red[0][l + 64] + red[1][l + 64] + red[2][l + 64] + red[3][l + 64];
  }
  __syncthreads();
  red[w][l] = acc1a; red[w][l + 64] = acc1b;
  __syncthreads();
  if (w == 0) {
    float* pr = partial + ((size_t)(2 + b) * 64 + chunk) * kC;
    pr[l]      = red[0][l] + red[1][l] + red[2][l] + red[3][l];
    pr[l + 64] = red[0][l + 64] + red[1][l + 64] + red[2][l + 64] + red[3][l + 64];
  }
}

__global__ void k_final(const float* __restrict__ partial, const float* __restrict__ pw,
                        const float* __restrict__ pb, float* __restrict__ out) {
  int ib = blockIdx.x;
  int i = ib >> 1, t = threadIdx.x;
  int c = t & 127, half = t >> 7;
  float a = 0.f;
  for (int ch = half * 32; ch < half * 32 + 32; ++ch)
    a += partial[((size_t)ib * 64 + ch) * kC + c];
  __shared__ float s[256];
  s[half * 128 + c] = a;
  __syncthreads();
  if (t < 128) s[t] = (s[t] + s[128 + t]) * (1.f / (float)kN);
  __syncthreads();
  if (t < 128) {
    float a0 = 0.f;
    const float* wr = pw + (size_t)i * kC * kC + (size_t)t * kC;
    for (int cc = 0; cc < 128; ++cc) a0 += s[cc] * wr[cc];
    out[ib * 128 + t] = tanhf(pb[i * kC + t] + a0);
  }
}

extern "C" void kernel_launch(void* const* d_in, const int* in_sizes, int n_in,
                              void* d_out, int out_size, void* d_ws, size_t ws_size,
                              hipStream_t stream) {
  const float* x1_0   = (const float*)d_in[0];
  const float* x1_1   = (const float*)d_in[1];
  const float* x2     = (const float*)d_in[2];
  const float* norm_g = (const float*)d_in[3];
  const float* norm_b = (const float*)d_in[4];
  const float* d_qw   = (const float*)d_in[5];
  const float* d_kw   = (const float*)d_in[6];
  const float* d_vw   = (const float*)d_in[7];
  const float* d_ow   = (const float*)d_in[8];
  const float* d_ob   = (const float*)d_in[9];
  const float* d_o1w  = (const float*)d_in[10];
  const float* d_o1b  = (const float*)d_in[11];
  const float* d_o2w  = (const float*)d_in[12];
  const float* c_w1   = (const float*)d_in[13];
  const float* c_b1   = (const float*)d_in[14];
  const float* c_w2   = (const float*)d_in[15];
  const float* c_b2   = (const float*)d_in[16];
  const float* c_w3   = (const float*)d_in[17];
  const float* c_b3   = (const float*)d_in[18];
  const float* fus_w  = (const float*)d_in[19];
  const float* fus_b  = (const float*)d_in[20];
  const float* tf_ng  = (const float*)d_in[21];
  const float* tf_nb  = (const float*)d_in[22];
  const float* tf_inw = (const float*)d_in[23];
  const float* tf_inb = (const float*)d_in[24];
  const float* tf_ow  = (const float*)d_in[25];
  const float* tf_ob  = (const float*)d_in[26];
  const float* tf_pw  = (const float*)d_in[27];
  const float* tf_pb  = (const float*)d_in[28];

  float* ws = (float*)d_ws;
  float* out = (float*)d_out;
  float* lnkv = ws + W_LNKV;
  float* lnq1 = ws + W_LNQ1; float* lnq2 = ws + W_LNQ2;
  __hip_bfloat16* qb  = (__hip_bfloat16*)(ws + W_Q);
  __hip_bfloat16* kb  = (__hip_bfloat16*)(ws + W_K);
  __hip_bfloat16* vtb = (__hip_bfloat16*)(ws + W_VT);
  float* vgsw = ws + W_VGS;
  __hip_bfloat16* aob = (__hip_bfloat16*)(ws + W_AO);
  float* tab = ws + W_TAB;
  float* moutp = ws + W_MOUT; float* partp = ws + W_PART;
  __hip_bfloat16* owb = (__hip_bfloat16*)(ws + W_OWB);
  __hip_bfloat16* fwb = (__hip_bfloat16*)(ws + W_FWB);

  // output: f1(256) | f2(256) | a1(2*8*1024*256) | a2(same), all f32
  float* aoutb = out + 512;

  k_prep<<<2198, 256, 0, stream>>>(d_ow, fus_w, owb, fwb,
                                   x1_0, x1_1, x2, lnq1, lnq2, lnkv, norm_g, norm_b,
                                   c_w1, c_b1, c_w2, c_b2, c_w3, c_b3, tab,
                                   tf_ng, tf_nb, tf_inw, tf_inb, tf_ow, tf_ob, moutp);
  k_qoff<<<2560, 256, 0, stream>>>(lnq1, lnq2, d_qw, d_o1w, d_o1b, d_o2w, qb, vgsw);
  k_sample_kv<<<2048, 256, 0, stream>>>(lnkv, vgsw, d_kw, d_vw, kb, vtb);
  k_attn<<<512, 256, 0, stream>>>(qb, kb, vtb, vgsw, tab, aoutb, aob);
  k_oproj_fuse<<<128, 256, 0, stream>>>(aob, owb, d_ob, x1_0, x1_1, fwb, fus_b,
                                        norm_g, norm_b, tf_ng, tf_nb, moutp, partp);
  k_final<<<4, 256, 0, stream>>>(partp, tf_pw, tf_pb, out);

  (void)in_sizes; (void)n_in; (void)out_size; (void)ws_size;
}